// Round 6
// baseline (415.438 us; speedup 1.0000x reference)
//
#include <hip/hip_runtime.h>
#include <math.h>

#define HH 128
#define WW 128
#define HWSZ (HH * WW)
#define BB 2
#define COUT 128

typedef __bf16 bf16x8 __attribute__((ext_vector_type(8)));
typedef float f32x4 __attribute__((ext_vector_type(4)));
typedef float f32x2 __attribute__((ext_vector_type(2)));
typedef short s16x8 __attribute__((ext_vector_type(8)));
typedef short s16x4 __attribute__((ext_vector_type(4)));
typedef unsigned short u16x4 __attribute__((ext_vector_type(4)));
typedef unsigned short u16x8 __attribute__((ext_vector_type(8)));

__device__ __forceinline__ short tobf(float f) {
  union { float f; unsigned u; } v; v.f = f;
  unsigned r = v.u + 0x7fffu + ((v.u >> 16) & 1u);  // RNE
  return (short)(r >> 16);
}
__device__ __forceinline__ float asf(unsigned u) {
  union { unsigned u; float f; } v; v.u = u;
  return v.f;
}
__device__ __forceinline__ f32x2 up2(unsigned u) {   // 2 bf16 -> 2 f32
  f32x2 r; r[0] = asf(u << 16); r[1] = asf(u & 0xffff0000u); return r;
}
__device__ __forceinline__ unsigned pack2bf(f32x2 v) {
  union { float f; unsigned u; } x, y; x.f = v[0]; y.f = v[1];
  unsigned lo = (x.u + 0x7fffu + ((x.u >> 16) & 1u)) >> 16;
  unsigned hi = (y.u + 0x7fffu + ((y.u >> 16) & 1u)) & 0xffff0000u;
  return lo | hi;
}

// ---------------------------------------------------------------------------
// Merged prep. Segments (flat idx):
//  [0, PA0)    wbf1: 128x576, dc1_w*inv1, n-major remap Cin=64, row-major
//  [PA0, PA1)  wbf2 conv: 128x1152 (stride 1216), dc2_w*inv2, remap Cin=128
//  [PA1, PA2)  wbf2 id: 128x64 at col 1152, id_w*inv3
//  [PA2, PA3)  woff1: MFMA-fragment order, rows pad 32 (o<18 else 0)
//  [PA3, PA4)  woff2: same
//  [PA4, PA5)  cb1[128], cb2[128]
// Fragment order: idx = ((col>>5)*2 + (o>>4))*512 + ((col>>3)&3)*128
//                       + (o&15)*8 + (col&7)   (col = n-major column)
// ---------------------------------------------------------------------------
#define PA0 73728
#define PA1 221184
#define PA2 229376
#define PA3 247808
#define PA4 284672
#define PA5 284928
__global__ __launch_bounds__(256) void prep_all_kernel(
    const float* __restrict__ dc1_w, const float* __restrict__ dc2_w,
    const float* __restrict__ id_w, const float* __restrict__ dc1_offw,
    const float* __restrict__ dc2_offw,
    const float* g1, const float* b1, const float* m1, const float* v1,
    const float* g2, const float* b2, const float* m2, const float* v2,
    const float* g3, const float* b3, const float* m3, const float* v3,
    const float* idb,
    short* __restrict__ wbf1, short* __restrict__ wbf2,
    short* __restrict__ woff1, short* __restrict__ woff2,
    float* __restrict__ cb1, float* __restrict__ cb2) {
  int idx = blockIdx.x * 256 + threadIdx.x;
  if (idx < PA0) {
    int o = idx / 576, k = idx - o * 576;
    float inv = g1[o] / sqrtf(v1[o] + 1e-5f);
    int col = (k % 9) * 64 + k / 9;
    wbf1[o * 576 + col] = tobf(dc1_w[(size_t)o * 576 + k] * inv);
  } else if (idx < PA1) {
    int j = idx - PA0;
    int o = j / 1152, k = j - o * 1152;
    float inv = g2[o] / sqrtf(v2[o] + 1e-5f);
    int col = (k % 9) * 128 + k / 9;
    wbf2[o * 1216 + col] = tobf(dc2_w[(size_t)o * 1152 + k] * inv);
  } else if (idx < PA2) {
    int j = idx - PA1;
    int o = j >> 6, k = j & 63;
    float inv = g3[o] / sqrtf(v3[o] + 1e-5f);
    wbf2[o * 1216 + 1152 + k] = tobf(id_w[(size_t)o * 64 + k] * inv);
  } else if (idx < PA3) {
    int j = idx - PA2;
    int o = j / 576, k = j - o * 576;         // o 0..31
    int col = (k % 9) * 64 + k / 9;
    int di = ((col >> 5) * 2 + (o >> 4)) * 512 + ((col >> 3) & 3) * 128
           + (o & 15) * 8 + (col & 7);
    woff1[di] = (o < 18) ? tobf(dc1_offw[(size_t)o * 576 + k]) : (short)0;
  } else if (idx < PA4) {
    int j = idx - PA3;
    int o = j / 1152, k = j - o * 1152;
    int col = (k % 9) * 128 + k / 9;
    int di = ((col >> 5) * 2 + (o >> 4)) * 512 + ((col >> 3) & 3) * 128
           + (o & 15) * 8 + (col & 7);
    woff2[di] = (o < 18) ? tobf(dc2_offw[(size_t)o * 1152 + k]) : (short)0;
  } else if (idx < PA5) {
    int j = idx - PA4;
    if (j < 128) {
      float inv = g1[j] / sqrtf(v1[j] + 1e-5f);
      cb1[j] = b1[j] - m1[j] * inv;
    } else {
      int o = j - 128;
      float inv2_ = g2[o] / sqrtf(v2[o] + 1e-5f);
      float inv3_ = g3[o] / sqrtf(v3[o] + 1e-5f);
      cb2[o] = (b2[o] - m2[o] * inv2_) + idb[o] * inv3_ + (b3[o] - m3[o] * inv3_);
    }
  }
}

// ---------------------------------------------------------------------------
// x (B,64,H,W) fp32 NCHW -> xnhwc (B,H,W,64) bf16
// ---------------------------------------------------------------------------
__global__ __launch_bounds__(256) void xcast_kernel(const float* __restrict__ x,
                                                    unsigned short* __restrict__ xn) {
  __shared__ short lds[64 * 72];
  int tid = threadIdx.x;
  int gp0 = blockIdx.x * 64;
  int b = gp0 >> 14;
  int pl0 = gp0 & 16383;
  int p = tid & 63;
  int cb = (tid >> 6) * 16;
#pragma unroll
  for (int i = 0; i < 16; i++) {
    int c = cb + i;
    lds[p * 72 + c] = tobf(x[((size_t)(b * 64 + c)) * HWSZ + pl0 + p]);
  }
  __syncthreads();
  int pw = tid >> 2, cseg = (tid & 3) * 16;
  u16x8 a = *(const u16x8*)&lds[pw * 72 + cseg];
  u16x8 b8 = *(const u16x8*)&lds[pw * 72 + cseg + 8];
  *(u16x8*)&xn[(size_t)(gp0 + pw) * 64 + cseg] = a;
  *(u16x8*)&xn[(size_t)(gp0 + pw) * 64 + cseg + 8] = b8;
}

// ---------------------------------------------------------------------------
// Offset conv, barrier-free K-loop. Block: 64 px x 32 M (only 18 valid),
// 512 thr = 8 waves = 4 px-groups (16 px) x 2 K-halves.
// A-fragments direct from fragment-ordered global weights (L2-resident);
// B-fragments direct NHWC 16B loads (regular 3x3 grid). One LDS reduce.
// ---------------------------------------------------------------------------
__global__ __launch_bounds__(512, 4) void offconv_mfma_kernel(
    const unsigned short* __restrict__ in, const short* __restrict__ woff,
    const float* __restrict__ offb, float* __restrict__ off, int cshift) {
  __shared__ float redf[4 * 64 * 8];
  const int tid = threadIdx.x;
  const int lane = tid & 63, wv = tid >> 6;
  const int pxg = wv & 3, kh = wv >> 2;
  const int pb = ((blockIdx.x & 7) << 6) | (blockIdx.x >> 3);  // XCD swizzle
  const int pix0 = pb << 6;
  const int x0 = pix0 & 127, y = (pix0 >> 7) & 127, b = pix0 >> 14;
  const int Cin = 1 << cshift;
  const int HK = (9 << cshift) >> 1;
  const int NCh = HK >> 5;
  const unsigned short* inb = in + (size_t)b * HWSZ * Cin;
  const int l15 = lane & 15, quad = lane >> 4;
  const int px = x0 + pxg * 16 + l15;

  f32x4 acc[2];
  acc[0] = (f32x4){0.f, 0.f, 0.f, 0.f};
  acc[1] = (f32x4){0.f, 0.f, 0.f, 0.f};

  for (int i = 0; i < NCh; i++) {
    int k0 = kh * HK + i * 32;
    int n = k0 >> cshift;
    int c0 = (k0 & (Cin - 1)) + quad * 8;
    int yy = y + n / 3 - 1;
    int xx = px + n % 3 - 1;
    bf16x8 bv = {};
    if (((unsigned)yy < (unsigned)HH) && ((unsigned)xx < (unsigned)WW))
      bv = *(const bf16x8*)&inb[((size_t)yy * WW + xx) * Cin + c0];
    int fbase = (k0 >> 5) * 1024 + lane * 8;
    bf16x8 a0 = *(const bf16x8*)&woff[fbase];
    bf16x8 a1 = *(const bf16x8*)&woff[fbase + 512];
    acc[0] = __builtin_amdgcn_mfma_f32_16x16x32_bf16(a0, bv, acc[0], 0, 0, 0);
    acc[1] = __builtin_amdgcn_mfma_f32_16x16x32_bf16(a1, bv, acc[1], 0, 0, 0);
  }
  if (kh == 1) {
    *(f32x4*)&redf[(pxg * 64 + lane) * 8] = acc[0];
    *(f32x4*)&redf[(pxg * 64 + lane) * 8 + 4] = acc[1];
  }
  __syncthreads();
  if (kh == 0) {
    acc[0] += *(const f32x4*)&redf[(pxg * 64 + lane) * 8];
    acc[1] += *(const f32x4*)&redf[(pxg * 64 + lane) * 8 + 4];
#pragma unroll
    for (int ot = 0; ot < 2; ot++) {
#pragma unroll
      for (int r = 0; r < 4; r++) {
        int o = ot * 16 + quad * 4 + r;
        if (o < 18)
          off[(size_t)(b * 18 + o) * HWSZ + y * WW + px] = acc[ot][r] + offb[o];
      }
    }
  }
}

// ---------------------------------------------------------------------------
// Deformable conv im2col MFMA GEMM. Block: 128 px (one row) x 128 out,
// 512 thr = 8 waves = 4 px-quads (32 px) x 2 out-halves (64 out).
// Per 32-k chunk: 8 MFMA/wave, 1 barrier; depth-2 register pipeline
// (loads for chunk N+2 issued at iter N -> commits never wait on vmcnt).
// mode 0: h1 NHWC bf16 (LDS transpose); mode 1: d_out NCHW fp32.
// ---------------------------------------------------------------------------
__global__ __launch_bounds__(512, 2) void deform_mfma_kernel(
    const unsigned short* __restrict__ in, const float* __restrict__ off,
    const short* __restrict__ wbf, const float* __restrict__ cbv,
    const unsigned short* __restrict__ xid, float* __restrict__ outf,
    unsigned short* __restrict__ outb, int cshift, int KCONV, int KTOT, int mode) {
  __shared__ __align__(16) char smem[59392];
  u16x4* dsw = (u16x4*)smem;                    // [1152] 4 bf16 tap weights
  int2* dsa = (int2*)(smem + 9216);             // [1152] {base, dy<<16|dx}
  short* wlds = (short*)(smem + 18432);         // 2 x 128x40
  short* vlds = (short*)(smem + 38912);         // 2 x 128x40
  short* trans = (short*)smem;                  // 128 x 136 (overlay)

  const int tid = threadIdx.x;
  const int lane = tid & 63, wv = tid >> 6;
  const int pb = ((blockIdx.x & 7) << 5) | (blockIdx.x >> 3);  // XCD swizzle
  const int y = pb & 127, b = pb >> 7;          // block = one image row
  const int Cin = 1 << cshift;
  const unsigned short* inb = in + (size_t)b * HWSZ * Cin;
  const int ps = tid >> 2, cq = tid & 3;        // sampling: px, 8-ch group
  const int l15 = lane & 15, quad = lane >> 4;
  const int pxq = wv & 3, oh = wv >> 2;         // wave tile: 32px x 64out

  // ---- bilinear descriptors: 9 kernel points x 128 pixels ----
  for (int t = tid; t < 9 * 128; t += 512) {
    int n = t >> 7, pp = t & 127;
    float offy = off[(size_t)(b * 18 + n) * HWSZ + y * WW + pp];
    float offx = off[(size_t)(b * 18 + 9 + n) * HWSZ + y * WW + pp];
    float py = offy + (float)(n / 3 - 1) + (float)(y + 1);
    float px = offx + (float)(n % 3 - 1) + (float)(pp + 1);
    py = fminf(fmaxf(py, 0.f), 129.f);
    px = fminf(fmaxf(px, 0.f), 129.f);
    float fy = floorf(py), fx = floorf(px);
    float qy1 = fminf(fy + 1.f, 129.f), qx1 = fminf(fx + 1.f, 129.f);
    float ty0 = 1.f + fy - py, ty1 = 1.f - (qy1 - py);
    float tx0 = 1.f + fx - px, tx1 = 1.f - (qx1 - px);
    int iy0 = (int)fy - 1, ix0 = (int)fx - 1;
    int iy1 = (int)qy1 - 1, ix1 = (int)qx1 - 1;
    if ((unsigned)iy0 >= (unsigned)HH) ty0 = 0.f;
    if ((unsigned)iy1 >= (unsigned)HH) ty1 = 0.f;
    if ((unsigned)ix0 >= (unsigned)WW) tx0 = 0.f;
    if ((unsigned)ix1 >= (unsigned)WW) tx1 = 0.f;
    int by0 = min(max(iy0, 0), HH - 1), by1 = min(max(iy1, 0), HH - 1);
    int bx0 = min(max(ix0, 0), WW - 1), bx1 = min(max(ix1, 0), WW - 1);
    u16x4 w4;
    w4[0] = (unsigned short)tobf(ty0 * tx0);
    w4[1] = (unsigned short)tobf(ty0 * tx1);
    w4[2] = (unsigned short)tobf(ty1 * tx0);
    w4[3] = (unsigned short)tobf(ty1 * tx1);
    dsw[t] = w4;
    dsa[t] = make_int2((by0 * WW + bx0) * Cin,
                       (((by1 - by0) * WW * Cin) << 16) | ((bx1 - bx0) * Cin));
  }

  f32x4 acc[2][4];
#pragma unroll
  for (int i = 0; i < 2; i++)
#pragma unroll
    for (int j = 0; j < 4; j++) acc[i][j] = (f32x4){0.f, 0.f, 0.f, 0.f};

  // depth-2 pipeline registers
  s16x8 wr[2];
  uint4 t00[2], t01[2], t10[2], t11[2];
  u16x4 wq[2];
  int isres[2];

  auto issue = [&](int k0, int s) {
    wr[s] = *(const s16x8*)&wbf[(size_t)ps * KTOT + k0 + cq * 8];
    if (k0 < KCONV) {
      isres[s] = 0;
      int n = k0 >> cshift;
      int c0 = (k0 & (Cin - 1)) + cq * 8;
      int d = (n << 7) + ps;
      wq[s] = dsw[d];
      int2 ai = dsa[d];
      int dx = ai.y & 0xffff, dy = ai.y >> 16;
      const unsigned short* ptr = inb + ai.x + c0;
      t00[s] = *(const uint4*)(ptr);
      t01[s] = *(const uint4*)(ptr + dx);
      t10[s] = *(const uint4*)(ptr + dy);
      t11[s] = *(const uint4*)(ptr + dx + dy);
    } else {
      isres[s] = 1;
      int c = k0 - KCONV + cq * 8;
      t00[s] = *(const uint4*)&xid[((size_t)(b * HWSZ) + y * WW + ps) * 64 + c];
    }
  };
  auto commit = [&](int buf, int s) {
    uint4 pk;
    if (!isres[s]) {
      float w0 = asf((unsigned)wq[s][0] << 16), w1 = asf((unsigned)wq[s][1] << 16);
      float w2 = asf((unsigned)wq[s][2] << 16), w3 = asf((unsigned)wq[s][3] << 16);
      f32x2 v0 = up2(t00[s].x) * w0 + up2(t01[s].x) * w1
               + up2(t10[s].x) * w2 + up2(t11[s].x) * w3;
      f32x2 v1 = up2(t00[s].y) * w0 + up2(t01[s].y) * w1
               + up2(t10[s].y) * w2 + up2(t11[s].y) * w3;
      f32x2 v2 = up2(t00[s].z) * w0 + up2(t01[s].z) * w1
               + up2(t10[s].z) * w2 + up2(t11[s].z) * w3;
      f32x2 v3 = up2(t00[s].w) * w0 + up2(t01[s].w) * w1
               + up2(t10[s].w) * w2 + up2(t11[s].w) * w3;
      pk.x = pack2bf(v0); pk.y = pack2bf(v1); pk.z = pack2bf(v2); pk.w = pack2bf(v3);
    } else {
      pk = t00[s];
    }
    *(s16x8*)&wlds[buf * 5120 + ps * 40 + cq * 8] = wr[s];
    *(uint4*)&vlds[buf * 5120 + ps * 40 + cq * 8] = pk;
  };

  __syncthreads();            // descriptors ready
  const int NC = KTOT >> 5;
  issue(0, 0);
  commit(0, 0);
  if (NC > 1) issue(32, 1);
  __syncthreads();

  for (int ch = 0; ch < NC; ch++) {
    int cur = ch & 1;
    if (ch + 2 < NC) issue((ch + 2) << 5, ch & 1);
    bf16x8 bf0 = *(const bf16x8*)&vlds[cur * 5120 + (pxq * 32 + l15) * 40 + quad * 8];
    bf16x8 bf1 = *(const bf16x8*)&vlds[cur * 5120 + (pxq * 32 + 16 + l15) * 40 + quad * 8];
#pragma unroll
    for (int ot = 0; ot < 4; ot++) {
      bf16x8 afr = *(const bf16x8*)&wlds[cur * 5120 + (oh * 64 + ot * 16 + l15) * 40 + quad * 8];
      acc[0][ot] = __builtin_amdgcn_mfma_f32_16x16x32_bf16(afr, bf0, acc[0][ot], 0, 0, 0);
      acc[1][ot] = __builtin_amdgcn_mfma_f32_16x16x32_bf16(afr, bf1, acc[1][ot], 0, 0, 0);
    }
    if (ch + 1 < NC) commit(cur ^ 1, (ch + 1) & 1);
    __syncthreads();
  }

  if (mode == 1) {
#pragma unroll
    for (int pxi = 0; pxi < 2; pxi++) {
      int px_ = pxq * 32 + pxi * 16 + l15;
#pragma unroll
      for (int ot = 0; ot < 4; ot++) {
#pragma unroll
        for (int r = 0; r < 4; r++) {
          int o = oh * 64 + ot * 16 + quad * 4 + r;
          outf[(size_t)(b * COUT + o) * HWSZ + y * WW + px_] =
              fmaxf(acc[pxi][ot][r] + cbv[o], 0.f);
        }
      }
    }
  } else {
    // h1 NHWC bf16 via LDS transpose (overlay)
#pragma unroll
    for (int pxi = 0; pxi < 2; pxi++) {
      int px_ = pxq * 32 + pxi * 16 + l15;
#pragma unroll
      for (int ot = 0; ot < 4; ot++) {
        s16x4 t4;
#pragma unroll
        for (int r = 0; r < 4; r++) {
          int o = oh * 64 + ot * 16 + quad * 4 + r;
          t4[r] = tobf(fmaxf(acc[pxi][ot][r] + cbv[o], 0.f));
        }
        *(s16x4*)&trans[px_ * 136 + oh * 64 + ot * 16 + quad * 4] = t4;
      }
    }
    __syncthreads();
    int pw = tid >> 2, cs = (tid & 3) * 32;
    size_t gb = ((size_t)(b * HWSZ) + y * WW + pw) * 128 + cs;
#pragma unroll
    for (int i = 0; i < 4; i++) {
      u16x8 v8 = *(const u16x8*)&trans[pw * 136 + cs + i * 8];
      *(u16x8*)&outb[gb + i * 8] = v8;
    }
  }
}

// ---------------------------------------------------------------------------
extern "C" void kernel_launch(void* const* d_in, const int* in_sizes, int n_in,
                              void* d_out, int out_size, void* d_ws, size_t ws_size,
                              hipStream_t stream) {
  const float* x        = (const float*)d_in[0];
  const float* dc1_offw = (const float*)d_in[1];
  const float* dc1_offb = (const float*)d_in[2];
  const float* dc1_w    = (const float*)d_in[3];
  const float* bn1_g    = (const float*)d_in[4];
  const float* bn1_b    = (const float*)d_in[5];
  const float* bn1_m    = (const float*)d_in[6];
  const float* bn1_v    = (const float*)d_in[7];
  const float* dc2_offw = (const float*)d_in[8];
  const float* dc2_offb = (const float*)d_in[9];
  const float* dc2_w    = (const float*)d_in[10];
  const float* bn2_g    = (const float*)d_in[11];
  const float* bn2_b    = (const float*)d_in[12];
  const float* bn2_m    = (const float*)d_in[13];
  const float* bn2_v    = (const float*)d_in[14];
  const float* id_w     = (const float*)d_in[15];
  const float* id_b     = (const float*)d_in[16];
  const float* bn3_g    = (const float*)d_in[17];
  const float* bn3_b    = (const float*)d_in[18];
  const float* bn3_m    = (const float*)d_in[19];
  const float* bn3_v    = (const float*)d_in[20];

  float* wsf = (float*)d_ws;
  float* off1 = wsf;                                   // 2*18*16384 f
  float* off2 = off1 + (size_t)BB * 18 * HWSZ;
  float* cb1  = off2 + (size_t)BB * 18 * HWSZ;
  float* cb2  = cb1 + 128;
  unsigned short* xbf = (unsigned short*)(cb2 + 128);  // NHWC (B,H,W,64)
  unsigned short* h1  = xbf + (size_t)BB * HWSZ * 64;  // NHWC (B,H,W,128)
  short* wbf1  = (short*)(h1 + (size_t)BB * HWSZ * COUT);  // 128 x 576
  short* wbf2  = wbf1 + (size_t)128 * 576;             // 128 x 1216
  short* woff1 = wbf2 + (size_t)128 * 1216;            // frag-order 18*1024
  short* woff2 = woff1 + (size_t)18 * 1024;            // frag-order 36*1024

  const int K1 = 576, K2 = 1152, KT2 = 1216;

  hipLaunchKernelGGL(prep_all_kernel, dim3((PA5 + 255) / 256), dim3(256), 0, stream,
                     dc1_w, dc2_w, id_w, dc1_offw, dc2_offw,
                     bn1_g, bn1_b, bn1_m, bn1_v, bn2_g, bn2_b, bn2_m, bn2_v,
                     bn3_g, bn3_b, bn3_m, bn3_v, id_b,
                     wbf1, wbf2, woff1, woff2, cb1, cb2);
  hipLaunchKernelGGL(xcast_kernel, dim3(BB * HWSZ / 64), dim3(256), 0, stream, x, xbf);

  // --- layer 1 ---
  hipLaunchKernelGGL(offconv_mfma_kernel, dim3(512), dim3(512), 0, stream,
                     xbf, woff1, dc1_offb, off1, 6);
  hipLaunchKernelGGL(deform_mfma_kernel, dim3(256), dim3(512), 0, stream,
                     xbf, off1, wbf1, cb1, (const unsigned short*)nullptr,
                     (float*)nullptr, h1, 6, K1, K1, 0);
  // --- layer 2 (identity residual folded into GEMM) ---
  hipLaunchKernelGGL(offconv_mfma_kernel, dim3(512), dim3(512), 0, stream,
                     h1, woff2, dc2_offb, off2, 7);
  hipLaunchKernelGGL(deform_mfma_kernel, dim3(256), dim3(512), 0, stream,
                     h1, off2, wbf2, cb2, xbf, (float*)d_out,
                     (unsigned short*)nullptr, 7, K2, KT2, 1);
}

// Round 7
// 352.441 us; speedup vs baseline: 1.1787x; 1.1787x over previous
//
#include <hip/hip_runtime.h>
#include <math.h>

#define HH 128
#define WW 128
#define HWSZ (HH * WW)
#define BB 2
#define COUT 128

typedef __bf16 bf16x8 __attribute__((ext_vector_type(8)));
typedef float f32x4 __attribute__((ext_vector_type(4)));
typedef float f32x2 __attribute__((ext_vector_type(2)));
typedef short s16x8 __attribute__((ext_vector_type(8)));
typedef short s16x4 __attribute__((ext_vector_type(4)));
typedef unsigned short u16x4 __attribute__((ext_vector_type(4)));
typedef unsigned short u16x8 __attribute__((ext_vector_type(8)));

__device__ __forceinline__ short tobf(float f) {
  union { float f; unsigned u; } v; v.f = f;
  unsigned r = v.u + 0x7fffu + ((v.u >> 16) & 1u);  // RNE
  return (short)(r >> 16);
}
__device__ __forceinline__ float asf(unsigned u) {
  union { unsigned u; float f; } v; v.u = u;
  return v.f;
}
__device__ __forceinline__ f32x2 up2(unsigned u) {   // 2 bf16 -> 2 f32
  f32x2 r; r[0] = asf(u << 16); r[1] = asf(u & 0xffff0000u); return r;
}
__device__ __forceinline__ unsigned pack2bf(f32x2 v) {
  union { float f; unsigned u; } x, y; x.f = v[0]; y.f = v[1];
  unsigned lo = (x.u + 0x7fffu + ((x.u >> 16) & 1u)) >> 16;
  unsigned hi = (y.u + 0x7fffu + ((y.u >> 16) & 1u)) & 0xffff0000u;
  return lo | hi;
}

// ---------------------------------------------------------------------------
// Merged prep (same as round 6).
// ---------------------------------------------------------------------------
#define PA0 73728
#define PA1 221184
#define PA2 229376
#define PA3 247808
#define PA4 284672
#define PA5 284928
__global__ __launch_bounds__(256) void prep_all_kernel(
    const float* __restrict__ dc1_w, const float* __restrict__ dc2_w,
    const float* __restrict__ id_w, const float* __restrict__ dc1_offw,
    const float* __restrict__ dc2_offw,
    const float* g1, const float* b1, const float* m1, const float* v1,
    const float* g2, const float* b2, const float* m2, const float* v2,
    const float* g3, const float* b3, const float* m3, const float* v3,
    const float* idb,
    short* __restrict__ wbf1, short* __restrict__ wbf2,
    short* __restrict__ woff1, short* __restrict__ woff2,
    float* __restrict__ cb1, float* __restrict__ cb2) {
  int idx = blockIdx.x * 256 + threadIdx.x;
  if (idx < PA0) {
    int o = idx / 576, k = idx - o * 576;
    float inv = g1[o] / sqrtf(v1[o] + 1e-5f);
    int col = (k % 9) * 64 + k / 9;
    wbf1[o * 576 + col] = tobf(dc1_w[(size_t)o * 576 + k] * inv);
  } else if (idx < PA1) {
    int j = idx - PA0;
    int o = j / 1152, k = j - o * 1152;
    float inv = g2[o] / sqrtf(v2[o] + 1e-5f);
    int col = (k % 9) * 128 + k / 9;
    wbf2[o * 1216 + col] = tobf(dc2_w[(size_t)o * 1152 + k] * inv);
  } else if (idx < PA2) {
    int j = idx - PA1;
    int o = j >> 6, k = j & 63;
    float inv = g3[o] / sqrtf(v3[o] + 1e-5f);
    wbf2[o * 1216 + 1152 + k] = tobf(id_w[(size_t)o * 64 + k] * inv);
  } else if (idx < PA3) {
    int j = idx - PA2;
    int o = j / 576, k = j - o * 576;
    int col = (k % 9) * 64 + k / 9;
    int di = ((col >> 5) * 2 + (o >> 4)) * 512 + ((col >> 3) & 3) * 128
           + (o & 15) * 8 + (col & 7);
    woff1[di] = (o < 18) ? tobf(dc1_offw[(size_t)o * 576 + k]) : (short)0;
  } else if (idx < PA4) {
    int j = idx - PA3;
    int o = j / 1152, k = j - o * 1152;
    int col = (k % 9) * 128 + k / 9;
    int di = ((col >> 5) * 2 + (o >> 4)) * 512 + ((col >> 3) & 3) * 128
           + (o & 15) * 8 + (col & 7);
    woff2[di] = (o < 18) ? tobf(dc2_offw[(size_t)o * 1152 + k]) : (short)0;
  } else if (idx < PA5) {
    int j = idx - PA4;
    if (j < 128) {
      float inv = g1[j] / sqrtf(v1[j] + 1e-5f);
      cb1[j] = b1[j] - m1[j] * inv;
    } else {
      int o = j - 128;
      float inv2_ = g2[o] / sqrtf(v2[o] + 1e-5f);
      float inv3_ = g3[o] / sqrtf(v3[o] + 1e-5f);
      cb2[o] = (b2[o] - m2[o] * inv2_) + idb[o] * inv3_ + (b3[o] - m3[o] * inv3_);
    }
  }
}

// ---------------------------------------------------------------------------
// x (B,64,H,W) fp32 NCHW -> xnhwc (B,H,W,64) bf16
// ---------------------------------------------------------------------------
__global__ __launch_bounds__(256) void xcast_kernel(const float* __restrict__ x,
                                                    unsigned short* __restrict__ xn) {
  __shared__ short lds[64 * 72];
  int tid = threadIdx.x;
  int gp0 = blockIdx.x * 64;
  int b = gp0 >> 14;
  int pl0 = gp0 & 16383;
  int p = tid & 63;
  int cb = (tid >> 6) * 16;
#pragma unroll
  for (int i = 0; i < 16; i++) {
    int c = cb + i;
    lds[p * 72 + c] = tobf(x[((size_t)(b * 64 + c)) * HWSZ + pl0 + p]);
  }
  __syncthreads();
  int pw = tid >> 2, cseg = (tid & 3) * 16;
  u16x8 a = *(const u16x8*)&lds[pw * 72 + cseg];
  u16x8 b8 = *(const u16x8*)&lds[pw * 72 + cseg + 8];
  *(u16x8*)&xn[(size_t)(gp0 + pw) * 64 + cseg] = a;
  *(u16x8*)&xn[(size_t)(gp0 + pw) * 64 + cseg + 8] = b8;
}

// ---------------------------------------------------------------------------
// Offset conv, barrier-free K-loop (round 6, unchanged).
// ---------------------------------------------------------------------------
__global__ __launch_bounds__(512, 4) void offconv_mfma_kernel(
    const unsigned short* __restrict__ in, const short* __restrict__ woff,
    const float* __restrict__ offb, float* __restrict__ off, int cshift) {
  __shared__ float redf[4 * 64 * 8];
  const int tid = threadIdx.x;
  const int lane = tid & 63, wv = tid >> 6;
  const int pxg = wv & 3, kh = wv >> 2;
  const int pb = ((blockIdx.x & 7) << 6) | (blockIdx.x >> 3);
  const int pix0 = pb << 6;
  const int x0 = pix0 & 127, y = (pix0 >> 7) & 127, b = pix0 >> 14;
  const int Cin = 1 << cshift;
  const int HK = (9 << cshift) >> 1;
  const int NCh = HK >> 5;
  const unsigned short* inb = in + (size_t)b * HWSZ * Cin;
  const int l15 = lane & 15, quad = lane >> 4;
  const int px = x0 + pxg * 16 + l15;

  f32x4 acc[2];
  acc[0] = (f32x4){0.f, 0.f, 0.f, 0.f};
  acc[1] = (f32x4){0.f, 0.f, 0.f, 0.f};

  for (int i = 0; i < NCh; i++) {
    int k0 = kh * HK + i * 32;
    int n = k0 >> cshift;
    int c0 = (k0 & (Cin - 1)) + quad * 8;
    int yy = y + n / 3 - 1;
    int xx = px + n % 3 - 1;
    bf16x8 bv = {};
    if (((unsigned)yy < (unsigned)HH) && ((unsigned)xx < (unsigned)WW))
      bv = *(const bf16x8*)&inb[((size_t)yy * WW + xx) * Cin + c0];
    int fbase = (k0 >> 5) * 1024 + lane * 8;
    bf16x8 a0 = *(const bf16x8*)&woff[fbase];
    bf16x8 a1 = *(const bf16x8*)&woff[fbase + 512];
    acc[0] = __builtin_amdgcn_mfma_f32_16x16x32_bf16(a0, bv, acc[0], 0, 0, 0);
    acc[1] = __builtin_amdgcn_mfma_f32_16x16x32_bf16(a1, bv, acc[1], 0, 0, 0);
  }
  if (kh == 1) {
    *(f32x4*)&redf[(pxg * 64 + lane) * 8] = acc[0];
    *(f32x4*)&redf[(pxg * 64 + lane) * 8 + 4] = acc[1];
  }
  __syncthreads();
  if (kh == 0) {
    acc[0] += *(const f32x4*)&redf[(pxg * 64 + lane) * 8];
    acc[1] += *(const f32x4*)&redf[(pxg * 64 + lane) * 8 + 4];
#pragma unroll
    for (int ot = 0; ot < 2; ot++) {
#pragma unroll
      for (int r = 0; r < 4; r++) {
        int o = ot * 16 + quad * 4 + r;
        if (o < 18)
          off[(size_t)(b * 18 + o) * HWSZ + y * WW + px] = acc[ot][r] + offb[o];
      }
    }
  }
}

// ---------------------------------------------------------------------------
// Deformable conv im2col MFMA GEMM. Block: 64 px x 128 out, 256 thr =
// 4 waves (wave tile 32px x 64out -> 8 MFMA/wave/chunk, 1 barrier/chunk).
// STATIC depth-2 register pipeline: two named Slot structs, loop unrolled
// by 2 -- every slot reference is compile-time (no scratch spill).
// Grid 512 -> 2 blocks/CU (cross-block barrier hiding).
// mode 0: h1 NHWC bf16; mode 1: d_out NCHW fp32.
// ---------------------------------------------------------------------------
struct Slot {
  s16x8 w0, w1;
  uint4 t00, t01, t10, t11;
  u16x4 wq;
  int res;
};

__global__ __launch_bounds__(256, 2) void deform_mfma_kernel(
    const unsigned short* __restrict__ in, const float* __restrict__ off,
    const short* __restrict__ wbf, const float* __restrict__ cbv,
    const unsigned short* __restrict__ xid, float* __restrict__ outf,
    unsigned short* __restrict__ outb, int cshift, int KCONV, int KTOT, int mode) {
  __shared__ __align__(16) char smem[39936];
  u16x4* dsw = (u16x4*)smem;                    // [576] 4 bf16 tap weights
  int2* dsa = (int2*)(smem + 4608);             // [576] {base, dy<<16|dx}
  short* wlds = (short*)(smem + 9216);          // 2 x 128x40
  short* vlds = (short*)(smem + 29696);         // 2 x 64x40
  short* trans = (short*)smem;                  // 64 x 136 (epilogue overlay)

  const int tid = threadIdx.x;
  const int lane = tid & 63, wv = tid >> 6;
  const int pb = ((blockIdx.x & 7) << 6) | (blockIdx.x >> 3);  // XCD swizzle
  const int pix0 = pb << 6;
  const int x0 = pix0 & 127, y = (pix0 >> 7) & 127, b = pix0 >> 14;
  const int Cin = 1 << cshift;
  const unsigned short* inb = in + (size_t)b * HWSZ * Cin;
  const int ps = tid >> 2, cq = tid & 3;        // sampling: px, 8-ch group
  const int l15 = lane & 15, quad = lane >> 4;
  const int pxh = wv & 1, oh = wv >> 1;         // wave tile: 32px x 64out
  const int wrow = tid >> 1, wcol = (tid & 1) * 16;

  // ---- bilinear descriptors: 9 kernel points x 64 pixels ----
  for (int t = tid; t < 576; t += 256) {
    int n = t >> 6, pp = t & 63;
    float offy = off[(size_t)(b * 18 + n) * HWSZ + y * WW + x0 + pp];
    float offx = off[(size_t)(b * 18 + 9 + n) * HWSZ + y * WW + x0 + pp];
    float py = offy + (float)(n / 3 - 1) + (float)(y + 1);
    float px = offx + (float)(n % 3 - 1) + (float)(x0 + pp + 1);
    py = fminf(fmaxf(py, 0.f), 129.f);
    px = fminf(fmaxf(px, 0.f), 129.f);
    float fy = floorf(py), fx = floorf(px);
    float qy1 = fminf(fy + 1.f, 129.f), qx1 = fminf(fx + 1.f, 129.f);
    float ty0 = 1.f + fy - py, ty1 = 1.f - (qy1 - py);
    float tx0 = 1.f + fx - px, tx1 = 1.f - (qx1 - px);
    int iy0 = (int)fy - 1, ix0 = (int)fx - 1;
    int iy1 = (int)qy1 - 1, ix1 = (int)qx1 - 1;
    if ((unsigned)iy0 >= (unsigned)HH) ty0 = 0.f;
    if ((unsigned)iy1 >= (unsigned)HH) ty1 = 0.f;
    if ((unsigned)ix0 >= (unsigned)WW) tx0 = 0.f;
    if ((unsigned)ix1 >= (unsigned)WW) tx1 = 0.f;
    int by0 = min(max(iy0, 0), HH - 1), by1 = min(max(iy1, 0), HH - 1);
    int bx0 = min(max(ix0, 0), WW - 1), bx1 = min(max(ix1, 0), WW - 1);
    u16x4 w4;
    w4[0] = (unsigned short)tobf(ty0 * tx0);
    w4[1] = (unsigned short)tobf(ty0 * tx1);
    w4[2] = (unsigned short)tobf(ty1 * tx0);
    w4[3] = (unsigned short)tobf(ty1 * tx1);
    dsw[t] = w4;
    dsa[t] = make_int2((by0 * WW + bx0) * Cin,
                       (((by1 - by0) * WW * Cin) << 16) | ((bx1 - bx0) * Cin));
  }

  f32x4 acc0[4], acc1[4];
#pragma unroll
  for (int j = 0; j < 4; j++) {
    acc0[j] = (f32x4){0.f, 0.f, 0.f, 0.f};
    acc1[j] = (f32x4){0.f, 0.f, 0.f, 0.f};
  }

  Slot A, B;
  auto issue = [&](Slot& S, int k0) {
    S.w0 = *(const s16x8*)&wbf[(size_t)wrow * KTOT + k0 + wcol];
    S.w1 = *(const s16x8*)&wbf[(size_t)wrow * KTOT + k0 + wcol + 8];
    if (k0 < KCONV) {
      S.res = 0;
      int n = k0 >> cshift;
      int c0 = (k0 & (Cin - 1)) + cq * 8;
      int d = (n << 6) + ps;
      S.wq = dsw[d];
      int2 ai = dsa[d];
      int dx = ai.y & 0xffff, dy = ai.y >> 16;
      const unsigned short* ptr = inb + ai.x + c0;
      S.t00 = *(const uint4*)(ptr);
      S.t01 = *(const uint4*)(ptr + dx);
      S.t10 = *(const uint4*)(ptr + dy);
      S.t11 = *(const uint4*)(ptr + dx + dy);
    } else {
      S.res = 1;
      int c = k0 - KCONV + cq * 8;
      S.t00 = *(const uint4*)&xid[((size_t)(b * HWSZ) + y * WW + x0 + ps) * 64 + c];
    }
  };
  auto commit = [&](Slot& S, int buf) {
    uint4 pk;
    if (!S.res) {
      float w0 = asf((unsigned)S.wq[0] << 16), w1 = asf((unsigned)S.wq[1] << 16);
      float w2 = asf((unsigned)S.wq[2] << 16), w3 = asf((unsigned)S.wq[3] << 16);
      f32x2 v0 = up2(S.t00.x) * w0 + up2(S.t01.x) * w1
               + up2(S.t10.x) * w2 + up2(S.t11.x) * w3;
      f32x2 v1 = up2(S.t00.y) * w0 + up2(S.t01.y) * w1
               + up2(S.t10.y) * w2 + up2(S.t11.y) * w3;
      f32x2 v2 = up2(S.t00.z) * w0 + up2(S.t01.z) * w1
               + up2(S.t10.z) * w2 + up2(S.t11.z) * w3;
      f32x2 v3 = up2(S.t00.w) * w0 + up2(S.t01.w) * w1
               + up2(S.t10.w) * w2 + up2(S.t11.w) * w3;
      pk.x = pack2bf(v0); pk.y = pack2bf(v1); pk.z = pack2bf(v2); pk.w = pack2bf(v3);
    } else {
      pk = S.t00;
    }
    *(s16x8*)&wlds[buf * 5120 + wrow * 40 + wcol] = S.w0;
    *(s16x8*)&wlds[buf * 5120 + wrow * 40 + wcol + 8] = S.w1;
    *(uint4*)&vlds[buf * 2560 + ps * 40 + cq * 8] = pk;
  };
  auto step = [&](int buf) {
    bf16x8 bf0 = *(const bf16x8*)&vlds[buf * 2560 + (pxh * 32 + l15) * 40 + quad * 8];
    bf16x8 bf1 = *(const bf16x8*)&vlds[buf * 2560 + (pxh * 32 + 16 + l15) * 40 + quad * 8];
#pragma unroll
    for (int ot = 0; ot < 4; ot++) {
      bf16x8 afr = *(const bf16x8*)&wlds[buf * 5120 + (oh * 64 + ot * 16 + l15) * 40 + quad * 8];
      acc0[ot] = __builtin_amdgcn_mfma_f32_16x16x32_bf16(afr, bf0, acc0[ot], 0, 0, 0);
      acc1[ot] = __builtin_amdgcn_mfma_f32_16x16x32_bf16(afr, bf1, acc1[ot], 0, 0, 0);
    }
  };

  __syncthreads();            // descriptors ready
  const int NC = KTOT >> 5;   // 18 or 38 (even)
  issue(A, 0);
  commit(A, 0);
  issue(B, 32);
  __syncthreads();

  for (int ch = 0; ch < NC; ch += 2) {
    if (ch + 2 < NC) issue(A, (ch + 2) << 5);
    step(0);
    commit(B, 1);
    __syncthreads();
    if (ch + 3 < NC) issue(B, (ch + 3) << 5);
    step(1);
    if (ch + 2 < NC) commit(A, 0);
    __syncthreads();
  }

  if (mode == 1) {
#pragma unroll
    for (int pxi = 0; pxi < 2; pxi++) {
      int px_ = x0 + pxh * 32 + pxi * 16 + l15;
#pragma unroll
      for (int ot = 0; ot < 4; ot++) {
        f32x4 a4 = pxi ? acc1[ot] : acc0[ot];
#pragma unroll
        for (int r = 0; r < 4; r++) {
          int o = oh * 64 + ot * 16 + quad * 4 + r;
          outf[(size_t)(b * COUT + o) * HWSZ + y * WW + px_] =
              fmaxf(a4[r] + cbv[o], 0.f);
        }
      }
    }
  } else {
    // h1 NHWC bf16 via LDS transpose (overlay on descriptor region)
#pragma unroll
    for (int pxi = 0; pxi < 2; pxi++) {
      int pl = pxh * 32 + pxi * 16 + l15;
#pragma unroll
      for (int ot = 0; ot < 4; ot++) {
        f32x4 a4 = pxi ? acc1[ot] : acc0[ot];
        s16x4 t4;
#pragma unroll
        for (int r = 0; r < 4; r++) {
          int o = oh * 64 + ot * 16 + quad * 4 + r;
          t4[r] = tobf(fmaxf(a4[r] + cbv[o], 0.f));
        }
        *(s16x4*)&trans[pl * 136 + oh * 64 + ot * 16 + quad * 4] = t4;
      }
    }
    __syncthreads();
    int pw = tid >> 2, cs = (tid & 3) * 32;
    size_t gb = ((size_t)(b * HWSZ) + y * WW + x0 + pw) * 128 + cs;
#pragma unroll
    for (int i = 0; i < 4; i++) {
      u16x8 v8 = *(const u16x8*)&trans[pw * 136 + cs + i * 8];
      *(u16x8*)&outb[gb + i * 8] = v8;
    }
  }
}

// ---------------------------------------------------------------------------
extern "C" void kernel_launch(void* const* d_in, const int* in_sizes, int n_in,
                              void* d_out, int out_size, void* d_ws, size_t ws_size,
                              hipStream_t stream) {
  const float* x        = (const float*)d_in[0];
  const float* dc1_offw = (const float*)d_in[1];
  const float* dc1_offb = (const float*)d_in[2];
  const float* dc1_w    = (const float*)d_in[3];
  const float* bn1_g    = (const float*)d_in[4];
  const float* bn1_b    = (const float*)d_in[5];
  const float* bn1_m    = (const float*)d_in[6];
  const float* bn1_v    = (const float*)d_in[7];
  const float* dc2_offw = (const float*)d_in[8];
  const float* dc2_offb = (const float*)d_in[9];
  const float* dc2_w    = (const float*)d_in[10];
  const float* bn2_g    = (const float*)d_in[11];
  const float* bn2_b    = (const float*)d_in[12];
  const float* bn2_m    = (const float*)d_in[13];
  const float* bn2_v    = (const float*)d_in[14];
  const float* id_w     = (const float*)d_in[15];
  const float* id_b     = (const float*)d_in[16];
  const float* bn3_g    = (const float*)d_in[17];
  const float* bn3_b    = (const float*)d_in[18];
  const float* bn3_m    = (const float*)d_in[19];
  const float* bn3_v    = (const float*)d_in[20];

  float* wsf = (float*)d_ws;
  float* off1 = wsf;                                   // 2*18*16384 f
  float* off2 = off1 + (size_t)BB * 18 * HWSZ;
  float* cb1  = off2 + (size_t)BB * 18 * HWSZ;
  float* cb2  = cb1 + 128;
  unsigned short* xbf = (unsigned short*)(cb2 + 128);  // NHWC (B,H,W,64)
  unsigned short* h1  = xbf + (size_t)BB * HWSZ * 64;  // NHWC (B,H,W,128)
  short* wbf1  = (short*)(h1 + (size_t)BB * HWSZ * COUT);  // 128 x 576
  short* wbf2  = wbf1 + (size_t)128 * 576;             // 128 x 1216
  short* woff1 = wbf2 + (size_t)128 * 1216;            // frag-order 18*1024
  short* woff2 = woff1 + (size_t)18 * 1024;            // frag-order 36*1024

  const int K1 = 576, K2 = 1152, KT2 = 1216;

  hipLaunchKernelGGL(prep_all_kernel, dim3((PA5 + 255) / 256), dim3(256), 0, stream,
                     dc1_w, dc2_w, id_w, dc1_offw, dc2_offw,
                     bn1_g, bn1_b, bn1_m, bn1_v, bn2_g, bn2_b, bn2_m, bn2_v,
                     bn3_g, bn3_b, bn3_m, bn3_v, id_b,
                     wbf1, wbf2, woff1, woff2, cb1, cb2);
  hipLaunchKernelGGL(xcast_kernel, dim3(BB * HWSZ / 64), dim3(256), 0, stream, x, xbf);

  // --- layer 1 ---
  hipLaunchKernelGGL(offconv_mfma_kernel, dim3(512), dim3(512), 0, stream,
                     xbf, woff1, dc1_offb, off1, 6);
  hipLaunchKernelGGL(deform_mfma_kernel, dim3(512), dim3(256), 0, stream,
                     xbf, off1, wbf1, cb1, (const unsigned short*)nullptr,
                     (float*)nullptr, h1, 6, K1, K1, 0);
  // --- layer 2 (identity residual folded into GEMM) ---
  hipLaunchKernelGGL(offconv_mfma_kernel, dim3(512), dim3(512), 0, stream,
                     h1, woff2, dc2_offb, off2, 7);
  hipLaunchKernelGGL(deform_mfma_kernel, dim3(512), dim3(256), 0, stream,
                     h1, off2, wbf2, cb2, xbf, (float*)d_out,
                     (unsigned short*)nullptr, 7, K2, KT2, 1);
}

// Round 8
// 224.804 us; speedup vs baseline: 1.8480x; 1.5678x over previous
//
#include <hip/hip_runtime.h>
#include <math.h>

#define HH 128
#define WW 128
#define HWSZ (HH * WW)
#define BB 2
#define COUT 128

typedef __bf16 bf16x8 __attribute__((ext_vector_type(8)));
typedef float f32x4 __attribute__((ext_vector_type(4)));
typedef float f32x2 __attribute__((ext_vector_type(2)));
typedef short s16x8 __attribute__((ext_vector_type(8)));
typedef short s16x4 __attribute__((ext_vector_type(4)));
typedef unsigned short u16x4 __attribute__((ext_vector_type(4)));
typedef unsigned short u16x8 __attribute__((ext_vector_type(8)));

__device__ __forceinline__ short tobf(float f) {
  union { float f; unsigned u; } v; v.f = f;
  unsigned r = v.u + 0x7fffu + ((v.u >> 16) & 1u);  // RNE
  return (short)(r >> 16);
}
__device__ __forceinline__ float asf(unsigned u) {
  union { unsigned u; float f; } v; v.u = u;
  return v.f;
}
__device__ __forceinline__ f32x2 up2(unsigned u) {   // 2 bf16 -> 2 f32
  f32x2 r; r[0] = asf(u << 16); r[1] = asf(u & 0xffff0000u); return r;
}
__device__ __forceinline__ unsigned pack2bf(f32x2 v) {
  union { float f; unsigned u; } x, y; x.f = v[0]; y.f = v[1];
  unsigned lo = (x.u + 0x7fffu + ((x.u >> 16) & 1u)) >> 16;
  unsigned hi = (y.u + 0x7fffu + ((y.u >> 16) & 1u)) & 0xffff0000u;
  return lo | hi;
}

// ---------------------------------------------------------------------------
// Merged prep (unchanged from round 6/7).
// ---------------------------------------------------------------------------
#define PA0 73728
#define PA1 221184
#define PA2 229376
#define PA3 247808
#define PA4 284672
#define PA5 284928
__global__ __launch_bounds__(256) void prep_all_kernel(
    const float* __restrict__ dc1_w, const float* __restrict__ dc2_w,
    const float* __restrict__ id_w, const float* __restrict__ dc1_offw,
    const float* __restrict__ dc2_offw,
    const float* g1, const float* b1, const float* m1, const float* v1,
    const float* g2, const float* b2, const float* m2, const float* v2,
    const float* g3, const float* b3, const float* m3, const float* v3,
    const float* idb,
    short* __restrict__ wbf1, short* __restrict__ wbf2,
    short* __restrict__ woff1, short* __restrict__ woff2,
    float* __restrict__ cb1, float* __restrict__ cb2) {
  int idx = blockIdx.x * 256 + threadIdx.x;
  if (idx < PA0) {
    int o = idx / 576, k = idx - o * 576;
    float inv = g1[o] / sqrtf(v1[o] + 1e-5f);
    int col = (k % 9) * 64 + k / 9;
    wbf1[o * 576 + col] = tobf(dc1_w[(size_t)o * 576 + k] * inv);
  } else if (idx < PA1) {
    int j = idx - PA0;
    int o = j / 1152, k = j - o * 1152;
    float inv = g2[o] / sqrtf(v2[o] + 1e-5f);
    int col = (k % 9) * 128 + k / 9;
    wbf2[o * 1216 + col] = tobf(dc2_w[(size_t)o * 1152 + k] * inv);
  } else if (idx < PA2) {
    int j = idx - PA1;
    int o = j >> 6, k = j & 63;
    float inv = g3[o] / sqrtf(v3[o] + 1e-5f);
    wbf2[o * 1216 + 1152 + k] = tobf(id_w[(size_t)o * 64 + k] * inv);
  } else if (idx < PA3) {
    int j = idx - PA2;
    int o = j / 576, k = j - o * 576;
    int col = (k % 9) * 64 + k / 9;
    int di = ((col >> 5) * 2 + (o >> 4)) * 512 + ((col >> 3) & 3) * 128
           + (o & 15) * 8 + (col & 7);
    woff1[di] = (o < 18) ? tobf(dc1_offw[(size_t)o * 576 + k]) : (short)0;
  } else if (idx < PA4) {
    int j = idx - PA3;
    int o = j / 1152, k = j - o * 1152;
    int col = (k % 9) * 128 + k / 9;
    int di = ((col >> 5) * 2 + (o >> 4)) * 512 + ((col >> 3) & 3) * 128
           + (o & 15) * 8 + (col & 7);
    woff2[di] = (o < 18) ? tobf(dc2_offw[(size_t)o * 1152 + k]) : (short)0;
  } else if (idx < PA5) {
    int j = idx - PA4;
    if (j < 128) {
      float inv = g1[j] / sqrtf(v1[j] + 1e-5f);
      cb1[j] = b1[j] - m1[j] * inv;
    } else {
      int o = j - 128;
      float inv2_ = g2[o] / sqrtf(v2[o] + 1e-5f);
      float inv3_ = g3[o] / sqrtf(v3[o] + 1e-5f);
      cb2[o] = (b2[o] - m2[o] * inv2_) + idb[o] * inv3_ + (b3[o] - m3[o] * inv3_);
    }
  }
}

// ---------------------------------------------------------------------------
// x (B,64,H,W) fp32 NCHW -> xnhwc (B,H,W,64) bf16
// ---------------------------------------------------------------------------
__global__ __launch_bounds__(256) void xcast_kernel(const float* __restrict__ x,
                                                    unsigned short* __restrict__ xn) {
  __shared__ short lds[64 * 72];
  int tid = threadIdx.x;
  int gp0 = blockIdx.x * 64;
  int b = gp0 >> 14;
  int pl0 = gp0 & 16383;
  int p = tid & 63;
  int cb = (tid >> 6) * 16;
#pragma unroll
  for (int i = 0; i < 16; i++) {
    int c = cb + i;
    lds[p * 72 + c] = tobf(x[((size_t)(b * 64 + c)) * HWSZ + pl0 + p]);
  }
  __syncthreads();
  int pw = tid >> 2, cseg = (tid & 3) * 16;
  u16x8 a = *(const u16x8*)&lds[pw * 72 + cseg];
  u16x8 b8 = *(const u16x8*)&lds[pw * 72 + cseg + 8];
  *(u16x8*)&xn[(size_t)(gp0 + pw) * 64 + cseg] = a;
  *(u16x8*)&xn[(size_t)(gp0 + pw) * 64 + cseg + 8] = b8;
}

// ---------------------------------------------------------------------------
// Offset conv, barrier-free K-loop (unchanged from round 6/7).
// ---------------------------------------------------------------------------
__global__ __launch_bounds__(512, 4) void offconv_mfma_kernel(
    const unsigned short* __restrict__ in, const short* __restrict__ woff,
    const float* __restrict__ offb, float* __restrict__ off, int cshift) {
  __shared__ float redf[4 * 64 * 8];
  const int tid = threadIdx.x;
  const int lane = tid & 63, wv = tid >> 6;
  const int pxg = wv & 3, kh = wv >> 2;
  const int pb = ((blockIdx.x & 7) << 6) | (blockIdx.x >> 3);
  const int pix0 = pb << 6;
  const int x0 = pix0 & 127, y = (pix0 >> 7) & 127, b = pix0 >> 14;
  const int Cin = 1 << cshift;
  const int HK = (9 << cshift) >> 1;
  const int NCh = HK >> 5;
  const unsigned short* inb = in + (size_t)b * HWSZ * Cin;
  const int l15 = lane & 15, quad = lane >> 4;
  const int px = x0 + pxg * 16 + l15;

  f32x4 acc[2];
  acc[0] = (f32x4){0.f, 0.f, 0.f, 0.f};
  acc[1] = (f32x4){0.f, 0.f, 0.f, 0.f};

  for (int i = 0; i < NCh; i++) {
    int k0 = kh * HK + i * 32;
    int n = k0 >> cshift;
    int c0 = (k0 & (Cin - 1)) + quad * 8;
    int yy = y + n / 3 - 1;
    int xx = px + n % 3 - 1;
    bf16x8 bv = {};
    if (((unsigned)yy < (unsigned)HH) && ((unsigned)xx < (unsigned)WW))
      bv = *(const bf16x8*)&inb[((size_t)yy * WW + xx) * Cin + c0];
    int fbase = (k0 >> 5) * 1024 + lane * 8;
    bf16x8 a0 = *(const bf16x8*)&woff[fbase];
    bf16x8 a1 = *(const bf16x8*)&woff[fbase + 512];
    acc[0] = __builtin_amdgcn_mfma_f32_16x16x32_bf16(a0, bv, acc[0], 0, 0, 0);
    acc[1] = __builtin_amdgcn_mfma_f32_16x16x32_bf16(a1, bv, acc[1], 0, 0, 0);
  }
  if (kh == 1) {
    *(f32x4*)&redf[(pxg * 64 + lane) * 8] = acc[0];
    *(f32x4*)&redf[(pxg * 64 + lane) * 8 + 4] = acc[1];
  }
  __syncthreads();
  if (kh == 0) {
    acc[0] += *(const f32x4*)&redf[(pxg * 64 + lane) * 8];
    acc[1] += *(const f32x4*)&redf[(pxg * 64 + lane) * 8 + 4];
#pragma unroll
    for (int ot = 0; ot < 2; ot++) {
#pragma unroll
      for (int r = 0; r < 4; r++) {
        int o = ot * 16 + quad * 4 + r;
        if (o < 18)
          off[(size_t)(b * 18 + o) * HWSZ + y * WW + px] = acc[ot][r] + offb[o];
      }
    }
  }
}

// ---------------------------------------------------------------------------
// Deformable conv im2col MFMA GEMM. Block: 64 px x 128 out, 256 thr =
// 4 waves (wave tile 32px x 64out -> 8 MFMA/wave/chunk, 1 barrier/chunk).
// Depth-1 pipeline in NAMED SCALAR registers (round-5 codegen pattern that
// provably avoids scratch: lambdas take only ints, always_inline).
// Grid 512 -> 2 blocks/CU. mode 0: h1 NHWC bf16; mode 1: d_out NCHW fp32.
// ---------------------------------------------------------------------------
__global__ __launch_bounds__(256, 2) void deform_mfma_kernel(
    const unsigned short* __restrict__ in, const float* __restrict__ off,
    const short* __restrict__ wbf, const float* __restrict__ cbv,
    const unsigned short* __restrict__ xid, float* __restrict__ outf,
    unsigned short* __restrict__ outb, int cshift, int KCONV, int KTOT, int mode) {
  __shared__ __align__(16) char smem[39936];
  u16x4* dsw = (u16x4*)smem;                    // [576] 4 bf16 tap weights
  int2* dsa = (int2*)(smem + 4608);             // [576] {base, dy<<16|dx}
  short* wlds = (short*)(smem + 9216);          // 2 x 128x40
  short* vlds = (short*)(smem + 29696);         // 2 x 64x40
  short* trans = (short*)smem;                  // 64 x 136 (epilogue overlay)

  const int tid = threadIdx.x;
  const int lane = tid & 63, wv = tid >> 6;
  const int pb = ((blockIdx.x & 7) << 6) | (blockIdx.x >> 3);  // XCD swizzle
  const int pix0 = pb << 6;
  const int x0 = pix0 & 127, y = (pix0 >> 7) & 127, b = pix0 >> 14;
  const int Cin = 1 << cshift;
  const unsigned short* inb = in + (size_t)b * HWSZ * Cin;
  const int ps = tid >> 2, cq = tid & 3;        // sampling: px, 8-ch group
  const int l15 = lane & 15, quad = lane >> 4;
  const int pxh = wv & 1, oh = wv >> 1;         // wave tile: 32px x 64out
  const int wrow = tid >> 1, wcol = (tid & 1) * 16;

  // ---- bilinear descriptors: 9 kernel points x 64 pixels ----
  for (int t = tid; t < 576; t += 256) {
    int n = t >> 6, pp = t & 63;
    float offy = off[(size_t)(b * 18 + n) * HWSZ + y * WW + x0 + pp];
    float offx = off[(size_t)(b * 18 + 9 + n) * HWSZ + y * WW + x0 + pp];
    float py = offy + (float)(n / 3 - 1) + (float)(y + 1);
    float px = offx + (float)(n % 3 - 1) + (float)(x0 + pp + 1);
    py = fminf(fmaxf(py, 0.f), 129.f);
    px = fminf(fmaxf(px, 0.f), 129.f);
    float fy = floorf(py), fx = floorf(px);
    float qy1 = fminf(fy + 1.f, 129.f), qx1 = fminf(fx + 1.f, 129.f);
    float ty0 = 1.f + fy - py, ty1 = 1.f - (qy1 - py);
    float tx0 = 1.f + fx - px, tx1 = 1.f - (qx1 - px);
    int iy0 = (int)fy - 1, ix0 = (int)fx - 1;
    int iy1 = (int)qy1 - 1, ix1 = (int)qx1 - 1;
    if ((unsigned)iy0 >= (unsigned)HH) ty0 = 0.f;
    if ((unsigned)iy1 >= (unsigned)HH) ty1 = 0.f;
    if ((unsigned)ix0 >= (unsigned)WW) tx0 = 0.f;
    if ((unsigned)ix1 >= (unsigned)WW) tx1 = 0.f;
    int by0 = min(max(iy0, 0), HH - 1), by1 = min(max(iy1, 0), HH - 1);
    int bx0 = min(max(ix0, 0), WW - 1), bx1 = min(max(ix1, 0), WW - 1);
    u16x4 w4;
    w4[0] = (unsigned short)tobf(ty0 * tx0);
    w4[1] = (unsigned short)tobf(ty0 * tx1);
    w4[2] = (unsigned short)tobf(ty1 * tx0);
    w4[3] = (unsigned short)tobf(ty1 * tx1);
    dsw[t] = w4;
    dsa[t] = make_int2((by0 * WW + bx0) * Cin,
                       (((by1 - by0) * WW * Cin) << 16) | ((bx1 - bx0) * Cin));
  }

  f32x4 acc0[4], acc1[4];
#pragma unroll
  for (int j = 0; j < 4; j++) {
    acc0[j] = (f32x4){0.f, 0.f, 0.f, 0.f};
    acc1[j] = (f32x4){0.f, 0.f, 0.f, 0.f};
  }

  // depth-1 pipeline state: NAMED scalar/vector registers only
  s16x8 wr0, wr1;
  uint4 q00, q01, q10, q11;
  u16x4 wq4 = {0, 0, 0, 0};
  int resf = 0;

  auto issue = [&](int k0) __attribute__((always_inline)) {
    wr0 = *(const s16x8*)&wbf[(size_t)wrow * KTOT + k0 + wcol];
    wr1 = *(const s16x8*)&wbf[(size_t)wrow * KTOT + k0 + wcol + 8];
    if (k0 < KCONV) {
      resf = 0;
      int n = k0 >> cshift;
      int c0 = (k0 & (Cin - 1)) + cq * 8;
      int d = (n << 6) + ps;
      wq4 = dsw[d];
      int2 ai = dsa[d];
      int dx = ai.y & 0xffff, dy = ai.y >> 16;
      const unsigned short* ptr = inb + ai.x + c0;
      q00 = *(const uint4*)(ptr);
      q01 = *(const uint4*)(ptr + dx);
      q10 = *(const uint4*)(ptr + dy);
      q11 = *(const uint4*)(ptr + dx + dy);
    } else {
      resf = 1;
      int c = k0 - KCONV + cq * 8;
      q00 = *(const uint4*)&xid[((size_t)(b * HWSZ) + y * WW + x0 + ps) * 64 + c];
    }
  };
  auto commit = [&](int buf) __attribute__((always_inline)) {
    uint4 pk;
    if (!resf) {
      float w0 = asf((unsigned)wq4[0] << 16), w1 = asf((unsigned)wq4[1] << 16);
      float w2 = asf((unsigned)wq4[2] << 16), w3 = asf((unsigned)wq4[3] << 16);
      f32x2 v0 = up2(q00.x) * w0 + up2(q01.x) * w1 + up2(q10.x) * w2 + up2(q11.x) * w3;
      f32x2 v1 = up2(q00.y) * w0 + up2(q01.y) * w1 + up2(q10.y) * w2 + up2(q11.y) * w3;
      f32x2 v2 = up2(q00.z) * w0 + up2(q01.z) * w1 + up2(q10.z) * w2 + up2(q11.z) * w3;
      f32x2 v3 = up2(q00.w) * w0 + up2(q01.w) * w1 + up2(q10.w) * w2 + up2(q11.w) * w3;
      pk.x = pack2bf(v0); pk.y = pack2bf(v1); pk.z = pack2bf(v2); pk.w = pack2bf(v3);
    } else {
      pk = q00;
    }
    *(s16x8*)&wlds[buf * 5120 + wrow * 40 + wcol] = wr0;
    *(s16x8*)&wlds[buf * 5120 + wrow * 40 + wcol + 8] = wr1;
    *(uint4*)&vlds[buf * 2560 + ps * 40 + cq * 8] = pk;
  };
  auto step = [&](int buf) __attribute__((always_inline)) {
    bf16x8 bf0 = *(const bf16x8*)&vlds[buf * 2560 + (pxh * 32 + l15) * 40 + quad * 8];
    bf16x8 bf1 = *(const bf16x8*)&vlds[buf * 2560 + (pxh * 32 + 16 + l15) * 40 + quad * 8];
#pragma unroll
    for (int ot = 0; ot < 4; ot++) {
      bf16x8 afr = *(const bf16x8*)&wlds[buf * 5120 + (oh * 64 + ot * 16 + l15) * 40 + quad * 8];
      acc0[ot] = __builtin_amdgcn_mfma_f32_16x16x32_bf16(afr, bf0, acc0[ot], 0, 0, 0);
      acc1[ot] = __builtin_amdgcn_mfma_f32_16x16x32_bf16(afr, bf1, acc1[ot], 0, 0, 0);
    }
  };

  __syncthreads();            // descriptors ready
  const int NC = KTOT >> 5;
  issue(0);
  commit(0);
  __syncthreads();
  for (int ch = 0; ch < NC; ch++) {
    int cur = ch & 1;
    bool has = (ch + 1) < NC;
    if (has) issue((ch + 1) << 5);
    step(cur);
    if (has) commit(cur ^ 1);
    __syncthreads();
  }

  if (mode == 1) {
#pragma unroll
    for (int pxi = 0; pxi < 2; pxi++) {
      int px_ = x0 + pxh * 32 + pxi * 16 + l15;
#pragma unroll
      for (int ot = 0; ot < 4; ot++) {
        f32x4 a4 = pxi ? acc1[ot] : acc0[ot];
#pragma unroll
        for (int r = 0; r < 4; r++) {
          int o = oh * 64 + ot * 16 + quad * 4 + r;
          outf[(size_t)(b * COUT + o) * HWSZ + y * WW + px_] =
              fmaxf(a4[r] + cbv[o], 0.f);
        }
      }
    }
  } else {
    // h1 NHWC bf16 via LDS transpose (overlay on descriptor region)
#pragma unroll
    for (int pxi = 0; pxi < 2; pxi++) {
      int pl = pxh * 32 + pxi * 16 + l15;
#pragma unroll
      for (int ot = 0; ot < 4; ot++) {
        f32x4 a4 = pxi ? acc1[ot] : acc0[ot];
        s16x4 t4;
#pragma unroll
        for (int r = 0; r < 4; r++) {
          int o = oh * 64 + ot * 16 + quad * 4 + r;
          t4[r] = tobf(fmaxf(a4[r] + cbv[o], 0.f));
        }
        *(s16x4*)&trans[pl * 136 + oh * 64 + ot * 16 + quad * 4] = t4;
      }
    }
    __syncthreads();
    int pw = tid >> 2, cs = (tid & 3) * 32;
    size_t gb = ((size_t)(b * HWSZ) + y * WW + x0 + pw) * 128 + cs;
#pragma unroll
    for (int i = 0; i < 4; i++) {
      u16x8 v8 = *(const u16x8*)&trans[pw * 136 + cs + i * 8];
      *(u16x8*)&outb[gb + i * 8] = v8;
    }
  }
}

// ---------------------------------------------------------------------------
extern "C" void kernel_launch(void* const* d_in, const int* in_sizes, int n_in,
                              void* d_out, int out_size, void* d_ws, size_t ws_size,
                              hipStream_t stream) {
  const float* x        = (const float*)d_in[0];
  const float* dc1_offw = (const float*)d_in[1];
  const float* dc1_offb = (const float*)d_in[2];
  const float* dc1_w    = (const float*)d_in[3];
  const float* bn1_g    = (const float*)d_in[4];
  const float* bn1_b    = (const float*)d_in[5];
  const float* bn1_m    = (const float*)d_in[6];
  const float* bn1_v    = (const float*)d_in[7];
  const float* dc2_offw = (const float*)d_in[8];
  const float* dc2_offb = (const float*)d_in[9];
  const float* dc2_w    = (const float*)d_in[10];
  const float* bn2_g    = (const float*)d_in[11];
  const float* bn2_b    = (const float*)d_in[12];
  const float* bn2_m    = (const float*)d_in[13];
  const float* bn2_v    = (const float*)d_in[14];
  const float* id_w     = (const float*)d_in[15];
  const float* id_b     = (const float*)d_in[16];
  const float* bn3_g    = (const float*)d_in[17];
  const float* bn3_b    = (const float*)d_in[18];
  const float* bn3_m    = (const float*)d_in[19];
  const float* bn3_v    = (const float*)d_in[20];

  float* wsf = (float*)d_ws;
  float* off1 = wsf;                                   // 2*18*16384 f
  float* off2 = off1 + (size_t)BB * 18 * HWSZ;
  float* cb1  = off2 + (size_t)BB * 18 * HWSZ;
  float* cb2  = cb1 + 128;
  unsigned short* xbf = (unsigned short*)(cb2 + 128);  // NHWC (B,H,W,64)
  unsigned short* h1  = xbf + (size_t)BB * HWSZ * 64;  // NHWC (B,H,W,128)
  short* wbf1  = (short*)(h1 + (size_t)BB * HWSZ * COUT);  // 128 x 576
  short* wbf2  = wbf1 + (size_t)128 * 576;             // 128 x 1216
  short* woff1 = wbf2 + (size_t)128 * 1216;            // frag-order 18*1024
  short* woff2 = woff1 + (size_t)18 * 1024;            // frag-order 36*1024

  const int K1 = 576, K2 = 1152, KT2 = 1216;

  hipLaunchKernelGGL(prep_all_kernel, dim3((PA5 + 255) / 256), dim3(256), 0, stream,
                     dc1_w, dc2_w, id_w, dc1_offw, dc2_offw,
                     bn1_g, bn1_b, bn1_m, bn1_v, bn2_g, bn2_b, bn2_m, bn2_v,
                     bn3_g, bn3_b, bn3_m, bn3_v, id_b,
                     wbf1, wbf2, woff1, woff2, cb1, cb2);
  hipLaunchKernelGGL(xcast_kernel, dim3(BB * HWSZ / 64), dim3(256), 0, stream, x, xbf);

  // --- layer 1 ---
  hipLaunchKernelGGL(offconv_mfma_kernel, dim3(512), dim3(512), 0, stream,
                     xbf, woff1, dc1_offb, off1, 6);
  hipLaunchKernelGGL(deform_mfma_kernel, dim3(512), dim3(256), 0, stream,
                     xbf, off1, wbf1, cb1, (const unsigned short*)nullptr,
                     (float*)nullptr, h1, 6, K1, K1, 0);
  // --- layer 2 (identity residual folded into GEMM) ---
  hipLaunchKernelGGL(offconv_mfma_kernel, dim3(512), dim3(512), 0, stream,
                     h1, woff2, dc2_offb, off2, 7);
  hipLaunchKernelGGL(deform_mfma_kernel, dim3(512), dim3(256), 0, stream,
                     h1, off2, wbf2, cb2, xbf, (float*)d_out,
                     (unsigned short*)nullptr, 7, K2, KT2, 1);
}

// Round 9
// 193.751 us; speedup vs baseline: 2.1442x; 1.1603x over previous
//
#include <hip/hip_runtime.h>
#include <math.h>

#define HH 128
#define WW 128
#define HWSZ (HH * WW)
#define BB 2
#define COUT 128

typedef __bf16 bf16x8 __attribute__((ext_vector_type(8)));
typedef float f32x4 __attribute__((ext_vector_type(4)));
typedef float f32x2 __attribute__((ext_vector_type(2)));
typedef short s16x8 __attribute__((ext_vector_type(8)));
typedef short s16x4 __attribute__((ext_vector_type(4)));
typedef unsigned short u16x4 __attribute__((ext_vector_type(4)));
typedef unsigned short u16x8 __attribute__((ext_vector_type(8)));

__device__ __forceinline__ short tobf(float f) {
  union { float f; unsigned u; } v; v.f = f;
  unsigned r = v.u + 0x7fffu + ((v.u >> 16) & 1u);  // RNE
  return (short)(r >> 16);
}
__device__ __forceinline__ float asf(unsigned u) {
  union { unsigned u; float f; } v; v.u = u;
  return v.f;
}
__device__ __forceinline__ f32x2 up2(unsigned u) {   // 2 bf16 -> 2 f32
  f32x2 r; r[0] = asf(u << 16); r[1] = asf(u & 0xffff0000u); return r;
}
__device__ __forceinline__ unsigned pack2bf(f32x2 v) {
  union { float f; unsigned u; } x, y; x.f = v[0]; y.f = v[1];
  unsigned lo = (x.u + 0x7fffu + ((x.u >> 16) & 1u)) >> 16;
  unsigned hi = (y.u + 0x7fffu + ((y.u >> 16) & 1u)) & 0xffff0000u;
  return lo | hi;
}

// ---------------------------------------------------------------------------
// Merged prep. wbf1/wbf2 now in MFMA A-FRAGMENT order (direct per-wave global
// loads in the deform kernel, no LDS staging):
//   col = n-major column; kc = col>>5; oh = o>>6; ot = (o>>4)&3
//   lane = (o&15) | (((col>>3)&3)<<4); idx = ((kc*2+oh)*4+ot)*512 + lane*8 + (col&7)
// woff1/woff2 keep their own fragment order (unchanged).
// ---------------------------------------------------------------------------
#define PA0 73728
#define PA1 221184
#define PA2 229376
#define PA3 247808
#define PA4 284672
#define PA5 284928
__global__ __launch_bounds__(256) void prep_all_kernel(
    const float* __restrict__ dc1_w, const float* __restrict__ dc2_w,
    const float* __restrict__ id_w, const float* __restrict__ dc1_offw,
    const float* __restrict__ dc2_offw,
    const float* g1, const float* b1, const float* m1, const float* v1,
    const float* g2, const float* b2, const float* m2, const float* v2,
    const float* g3, const float* b3, const float* m3, const float* v3,
    const float* idb,
    short* __restrict__ wbf1, short* __restrict__ wbf2,
    short* __restrict__ woff1, short* __restrict__ woff2,
    float* __restrict__ cb1, float* __restrict__ cb2) {
  int idx = blockIdx.x * 256 + threadIdx.x;
  if (idx < PA0) {
    int o = idx / 576, k = idx - o * 576;
    float inv = g1[o] / sqrtf(v1[o] + 1e-5f);
    int col = (k % 9) * 64 + k / 9;
    int di = (((col >> 5) * 2 + (o >> 6)) * 4 + ((o >> 4) & 3)) * 512
           + (((o & 15) | (((col >> 3) & 3) << 4)) * 8) + (col & 7);
    wbf1[di] = tobf(dc1_w[(size_t)o * 576 + k] * inv);
  } else if (idx < PA1) {
    int j = idx - PA0;
    int o = j / 1152, k = j - o * 1152;
    float inv = g2[o] / sqrtf(v2[o] + 1e-5f);
    int col = (k % 9) * 128 + k / 9;
    int di = (((col >> 5) * 2 + (o >> 6)) * 4 + ((o >> 4) & 3)) * 512
           + (((o & 15) | (((col >> 3) & 3) << 4)) * 8) + (col & 7);
    wbf2[di] = tobf(dc2_w[(size_t)o * 1152 + k] * inv);
  } else if (idx < PA2) {
    int j = idx - PA1;
    int o = j >> 6, k = j & 63;
    float inv = g3[o] / sqrtf(v3[o] + 1e-5f);
    int col = 1152 + k;
    int di = (((col >> 5) * 2 + (o >> 6)) * 4 + ((o >> 4) & 3)) * 512
           + (((o & 15) | (((col >> 3) & 3) << 4)) * 8) + (col & 7);
    wbf2[di] = tobf(id_w[(size_t)o * 64 + k] * inv);
  } else if (idx < PA3) {
    int j = idx - PA2;
    int o = j / 576, k = j - o * 576;
    int col = (k % 9) * 64 + k / 9;
    int di = ((col >> 5) * 2 + (o >> 4)) * 512 + ((col >> 3) & 3) * 128
           + (o & 15) * 8 + (col & 7);
    woff1[di] = (o < 18) ? tobf(dc1_offw[(size_t)o * 576 + k]) : (short)0;
  } else if (idx < PA4) {
    int j = idx - PA3;
    int o = j / 1152, k = j - o * 1152;
    int col = (k % 9) * 128 + k / 9;
    int di = ((col >> 5) * 2 + (o >> 4)) * 512 + ((col >> 3) & 3) * 128
           + (o & 15) * 8 + (col & 7);
    woff2[di] = (o < 18) ? tobf(dc2_offw[(size_t)o * 1152 + k]) : (short)0;
  } else if (idx < PA5) {
    int j = idx - PA4;
    if (j < 128) {
      float inv = g1[j] / sqrtf(v1[j] + 1e-5f);
      cb1[j] = b1[j] - m1[j] * inv;
    } else {
      int o = j - 128;
      float inv2_ = g2[o] / sqrtf(v2[o] + 1e-5f);
      float inv3_ = g3[o] / sqrtf(v3[o] + 1e-5f);
      cb2[o] = (b2[o] - m2[o] * inv2_) + idb[o] * inv3_ + (b3[o] - m3[o] * inv3_);
    }
  }
}

// ---------------------------------------------------------------------------
// x (B,64,H,W) fp32 NCHW -> xnhwc (B,H,W,64) bf16
// ---------------------------------------------------------------------------
__global__ __launch_bounds__(256) void xcast_kernel(const float* __restrict__ x,
                                                    unsigned short* __restrict__ xn) {
  __shared__ short lds[64 * 72];
  int tid = threadIdx.x;
  int gp0 = blockIdx.x * 64;
  int b = gp0 >> 14;
  int pl0 = gp0 & 16383;
  int p = tid & 63;
  int cb = (tid >> 6) * 16;
#pragma unroll
  for (int i = 0; i < 16; i++) {
    int c = cb + i;
    lds[p * 72 + c] = tobf(x[((size_t)(b * 64 + c)) * HWSZ + pl0 + p]);
  }
  __syncthreads();
  int pw = tid >> 2, cseg = (tid & 3) * 16;
  u16x8 a = *(const u16x8*)&lds[pw * 72 + cseg];
  u16x8 b8 = *(const u16x8*)&lds[pw * 72 + cseg + 8];
  *(u16x8*)&xn[(size_t)(gp0 + pw) * 64 + cseg] = a;
  *(u16x8*)&xn[(size_t)(gp0 + pw) * 64 + cseg + 8] = b8;
}

// ---------------------------------------------------------------------------
// Offset conv, barrier-free K-loop (unchanged).
// ---------------------------------------------------------------------------
__global__ __launch_bounds__(512, 4) void offconv_mfma_kernel(
    const unsigned short* __restrict__ in, const short* __restrict__ woff,
    const float* __restrict__ offb, float* __restrict__ off, int cshift) {
  __shared__ float redf[4 * 64 * 8];
  const int tid = threadIdx.x;
  const int lane = tid & 63, wv = tid >> 6;
  const int pxg = wv & 3, kh = wv >> 2;
  const int pb = ((blockIdx.x & 7) << 6) | (blockIdx.x >> 3);
  const int pix0 = pb << 6;
  const int x0 = pix0 & 127, y = (pix0 >> 7) & 127, b = pix0 >> 14;
  const int Cin = 1 << cshift;
  const int HK = (9 << cshift) >> 1;
  const int NCh = HK >> 5;
  const unsigned short* inb = in + (size_t)b * HWSZ * Cin;
  const int l15 = lane & 15, quad = lane >> 4;
  const int px = x0 + pxg * 16 + l15;

  f32x4 acc[2];
  acc[0] = (f32x4){0.f, 0.f, 0.f, 0.f};
  acc[1] = (f32x4){0.f, 0.f, 0.f, 0.f};

  for (int i = 0; i < NCh; i++) {
    int k0 = kh * HK + i * 32;
    int n = k0 >> cshift;
    int c0 = (k0 & (Cin - 1)) + quad * 8;
    int yy = y + n / 3 - 1;
    int xx = px + n % 3 - 1;
    bf16x8 bv = {};
    if (((unsigned)yy < (unsigned)HH) && ((unsigned)xx < (unsigned)WW))
      bv = *(const bf16x8*)&inb[((size_t)yy * WW + xx) * Cin + c0];
    int fbase = (k0 >> 5) * 1024 + lane * 8;
    bf16x8 a0 = *(const bf16x8*)&woff[fbase];
    bf16x8 a1 = *(const bf16x8*)&woff[fbase + 512];
    acc[0] = __builtin_amdgcn_mfma_f32_16x16x32_bf16(a0, bv, acc[0], 0, 0, 0);
    acc[1] = __builtin_amdgcn_mfma_f32_16x16x32_bf16(a1, bv, acc[1], 0, 0, 0);
  }
  if (kh == 1) {
    *(f32x4*)&redf[(pxg * 64 + lane) * 8] = acc[0];
    *(f32x4*)&redf[(pxg * 64 + lane) * 8 + 4] = acc[1];
  }
  __syncthreads();
  if (kh == 0) {
    acc[0] += *(const f32x4*)&redf[(pxg * 64 + lane) * 8];
    acc[1] += *(const f32x4*)&redf[(pxg * 64 + lane) * 8 + 4];
#pragma unroll
    for (int ot = 0; ot < 2; ot++) {
#pragma unroll
      for (int r = 0; r < 4; r++) {
        int o = ot * 16 + quad * 4 + r;
        if (o < 18)
          off[(size_t)(b * 18 + o) * HWSZ + y * WW + px] = acc[ot][r] + offb[o];
      }
    }
  }
}

// ---------------------------------------------------------------------------
// Deformable conv, BARRIER-FREE K-loop.
// Block: 64 px x 128 out, 512 thr = 8 waves = 4 px-groups x 2 out-halves.
// Wave = 16px x 64out, fully independent in the K-loop:
//  - A-fragments loaded directly from fragment-ordered global weights
//    (shared via L1 across the 4 px-group waves of the CU).
//  - B-fragment: lane (px=l>>2, cq=l&3) samples 8 channels; intra-wave
//    transpose to MFMA layout via 4x ds_bpermute (no LDS mem, no barrier).
//  - Residual columns (layer 2) flow through the same path, blend skipped.
// LDS: only bilinear descriptors (9.2 KB) + epilogue transpose overlay.
// ---------------------------------------------------------------------------
template <int CSH, int KCONV, int KTOT, int MODE>
__global__ __launch_bounds__(512, 4) void deform_mfma_kernel(
    const unsigned short* __restrict__ in, const float* __restrict__ off,
    const short* __restrict__ wbf, const float* __restrict__ cbv,
    const unsigned short* __restrict__ xid, float* __restrict__ outf,
    unsigned short* __restrict__ outb) {
  __shared__ __align__(16) char smem[17408];
  uint4* dsu = (uint4*)smem;                    // [576] {w01,w23,base,dy|dx}
  short* trans = (short*)smem;                  // 64 x 136 (epilogue overlay)

  const int tid = threadIdx.x;
  const int lane = tid & 63, wv = tid >> 6;
  const int pb = ((blockIdx.x & 7) << 6) | (blockIdx.x >> 3);  // XCD swizzle
  const int pix0 = pb << 6;
  const int x0 = pix0 & 127, y = (pix0 >> 7) & 127, b = pix0 >> 14;
  const int Cin = 1 << CSH;
  const unsigned short* inb = in + (size_t)b * HWSZ * Cin;
  const int l15 = lane & 15, quad = lane >> 4;
  const int pxg = wv & 3, oh = wv >> 2;         // wave tile: 16px x 64out
  const int dp = pxg * 16 + (lane >> 2);        // sampling pixel (block-local)
  const int cq = lane & 3;                      // sampling channel group
  const int baddr = (((lane & 15) << 2) | (lane >> 4)) << 2;  // bpermute src*4

  // ---- bilinear descriptors: 9 kernel points x 64 pixels ----
  for (int t = tid; t < 576; t += 512) {
    int n = t >> 6, pp = t & 63;
    float offy = off[(size_t)(b * 18 + n) * HWSZ + y * WW + x0 + pp];
    float offx = off[(size_t)(b * 18 + 9 + n) * HWSZ + y * WW + x0 + pp];
    float py = offy + (float)(n / 3 - 1) + (float)(y + 1);
    float px = offx + (float)(n % 3 - 1) + (float)(x0 + pp + 1);
    py = fminf(fmaxf(py, 0.f), 129.f);
    px = fminf(fmaxf(px, 0.f), 129.f);
    float fy = floorf(py), fx = floorf(px);
    float qy1 = fminf(fy + 1.f, 129.f), qx1 = fminf(fx + 1.f, 129.f);
    float ty0 = 1.f + fy - py, ty1 = 1.f - (qy1 - py);
    float tx0 = 1.f + fx - px, tx1 = 1.f - (qx1 - px);
    int iy0 = (int)fy - 1, ix0 = (int)fx - 1;
    int iy1 = (int)qy1 - 1, ix1 = (int)qx1 - 1;
    if ((unsigned)iy0 >= (unsigned)HH) ty0 = 0.f;
    if ((unsigned)iy1 >= (unsigned)HH) ty1 = 0.f;
    if ((unsigned)ix0 >= (unsigned)WW) tx0 = 0.f;
    if ((unsigned)ix1 >= (unsigned)WW) tx1 = 0.f;
    int by0 = min(max(iy0, 0), HH - 1), by1 = min(max(iy1, 0), HH - 1);
    int bx0 = min(max(ix0, 0), WW - 1), bx1 = min(max(ix1, 0), WW - 1);
    unsigned w01 = (unsigned)(unsigned short)tobf(ty0 * tx0)
                 | ((unsigned)(unsigned short)tobf(ty0 * tx1) << 16);
    unsigned w23 = (unsigned)(unsigned short)tobf(ty1 * tx0)
                 | ((unsigned)(unsigned short)tobf(ty1 * tx1) << 16);
    uint4 d4;
    d4.x = w01; d4.y = w23;
    d4.z = (unsigned)((by0 * WW + bx0) * Cin);
    d4.w = (unsigned)((((by1 - by0) * WW * Cin) << 16) | ((bx1 - bx0) * Cin));
    dsu[t] = d4;
  }

  f32x4 acc[4];
#pragma unroll
  for (int j = 0; j < 4; j++) acc[j] = (f32x4){0.f, 0.f, 0.f, 0.f};

  __syncthreads();            // descriptors ready (only barrier before loop)

  const short* wfb = wbf + (size_t)oh * 2048 + lane * 8;
  constexpr int NC = KTOT >> 5;

#pragma unroll 2
  for (int kc = 0; kc < NC; kc++) {
    int k0 = kc << 5;
    // A-fragments: direct global loads, fragment order
    const short* wf = wfb + kc * 4096;
    bf16x8 a0 = *(const bf16x8*)(wf);
    bf16x8 a1 = *(const bf16x8*)(wf + 512);
    bf16x8 a2 = *(const bf16x8*)(wf + 1024);
    bf16x8 a3 = *(const bf16x8*)(wf + 1536);
    // B-sample (8 channels for pixel dp)
    uint4 pk;
    if (k0 < KCONV) {
      int n = k0 >> CSH;
      int c0 = (k0 & (Cin - 1)) + cq * 8;
      uint4 d4 = dsu[(n << 6) + dp];
      int dx = (int)(d4.w & 0xffffu);
      int dy = (int)d4.w >> 16;
      const unsigned short* ptr = inb + (int)d4.z + c0;
      uint4 q00 = *(const uint4*)(ptr);
      uint4 q01 = *(const uint4*)(ptr + dx);
      uint4 q10 = *(const uint4*)(ptr + dy);
      uint4 q11 = *(const uint4*)(ptr + dx + dy);
      float w0 = asf(d4.x << 16), w1 = asf(d4.x & 0xffff0000u);
      float w2 = asf(d4.y << 16), w3 = asf(d4.y & 0xffff0000u);
      f32x2 v0 = up2(q00.x) * w0 + up2(q01.x) * w1 + up2(q10.x) * w2 + up2(q11.x) * w3;
      f32x2 v1 = up2(q00.y) * w0 + up2(q01.y) * w1 + up2(q10.y) * w2 + up2(q11.y) * w3;
      f32x2 v2 = up2(q00.z) * w0 + up2(q01.z) * w1 + up2(q10.z) * w2 + up2(q11.z) * w3;
      f32x2 v3 = up2(q00.w) * w0 + up2(q01.w) * w1 + up2(q10.w) * w2 + up2(q11.w) * w3;
      pk.x = pack2bf(v0); pk.y = pack2bf(v1); pk.z = pack2bf(v2); pk.w = pack2bf(v3);
    } else {
      int c = (k0 - KCONV) + cq * 8;
      pk = *(const uint4*)&xid[((size_t)(b * HWSZ) + y * WW + x0 + dp) * 64 + c];
    }
    // intra-wave transpose: sampling layout -> MFMA B-fragment layout
    union { int i[4]; bf16x8 v; } bu;
    bu.i[0] = __builtin_amdgcn_ds_bpermute(baddr, (int)pk.x);
    bu.i[1] = __builtin_amdgcn_ds_bpermute(baddr, (int)pk.y);
    bu.i[2] = __builtin_amdgcn_ds_bpermute(baddr, (int)pk.z);
    bu.i[3] = __builtin_amdgcn_ds_bpermute(baddr, (int)pk.w);
    bf16x8 bfr = bu.v;
    acc[0] = __builtin_amdgcn_mfma_f32_16x16x32_bf16(a0, bfr, acc[0], 0, 0, 0);
    acc[1] = __builtin_amdgcn_mfma_f32_16x16x32_bf16(a1, bfr, acc[1], 0, 0, 0);
    acc[2] = __builtin_amdgcn_mfma_f32_16x16x32_bf16(a2, bfr, acc[2], 0, 0, 0);
    acc[3] = __builtin_amdgcn_mfma_f32_16x16x32_bf16(a3, bfr, acc[3], 0, 0, 0);
  }

  if (MODE == 1) {
#pragma unroll
    for (int ot = 0; ot < 4; ot++) {
#pragma unroll
      for (int r = 0; r < 4; r++) {
        int o = oh * 64 + ot * 16 + quad * 4 + r;
        outf[(size_t)(b * COUT + o) * HWSZ + y * WW + x0 + pxg * 16 + l15] =
            fmaxf(acc[ot][r] + cbv[o], 0.f);
      }
    }
  } else {
    // h1 NHWC bf16 via LDS transpose (overlay on descriptor region)
    __syncthreads();   // all waves done reading descriptors
    int pl = pxg * 16 + l15;
#pragma unroll
    for (int ot = 0; ot < 4; ot++) {
      s16x4 t4;
#pragma unroll
      for (int r = 0; r < 4; r++) {
        int o = oh * 64 + ot * 16 + quad * 4 + r;
        t4[r] = tobf(fmaxf(acc[ot][r] + cbv[o], 0.f));
      }
      *(s16x4*)&trans[pl * 136 + oh * 64 + ot * 16 + quad * 4] = t4;
    }
    __syncthreads();
    int pw = tid >> 3, cs = (tid & 7) * 16;
    u16x8 va = *(const u16x8*)&trans[pw * 136 + cs];
    u16x8 vb = *(const u16x8*)&trans[pw * 136 + cs + 8];
    size_t gb = ((size_t)(b * HWSZ) + y * WW + x0 + pw) * 128 + cs;
    *(u16x8*)&outb[gb] = va;
    *(u16x8*)&outb[gb + 8] = vb;
  }
}

// ---------------------------------------------------------------------------
extern "C" void kernel_launch(void* const* d_in, const int* in_sizes, int n_in,
                              void* d_out, int out_size, void* d_ws, size_t ws_size,
                              hipStream_t stream) {
  const float* x        = (const float*)d_in[0];
  const float* dc1_offw = (const float*)d_in[1];
  const float* dc1_offb = (const float*)d_in[2];
  const float* dc1_w    = (const float*)d_in[3];
  const float* bn1_g    = (const float*)d_in[4];
  const float* bn1_b    = (const float*)d_in[5];
  const float* bn1_m    = (const float*)d_in[6];
  const float* bn1_v    = (const float*)d_in[7];
  const float* dc2_offw = (const float*)d_in[8];
  const float* dc2_offb = (const float*)d_in[9];
  const float* dc2_w    = (const float*)d_in[10];
  const float* bn2_g    = (const float*)d_in[11];
  const float* bn2_b    = (const float*)d_in[12];
  const float* bn2_m    = (const float*)d_in[13];
  const float* bn2_v    = (const float*)d_in[14];
  const float* id_w     = (const float*)d_in[15];
  const float* id_b     = (const float*)d_in[16];
  const float* bn3_g    = (const float*)d_in[17];
  const float* bn3_b    = (const float*)d_in[18];
  const float* bn3_m    = (const float*)d_in[19];
  const float* bn3_v    = (const float*)d_in[20];

  float* wsf = (float*)d_ws;
  float* off1 = wsf;                                   // 2*18*16384 f
  float* off2 = off1 + (size_t)BB * 18 * HWSZ;
  float* cb1  = off2 + (size_t)BB * 18 * HWSZ;
  float* cb2  = cb1 + 128;
  unsigned short* xbf = (unsigned short*)(cb2 + 128);  // NHWC (B,H,W,64)
  unsigned short* h1  = xbf + (size_t)BB * HWSZ * 64;  // NHWC (B,H,W,128)
  short* wbf1  = (short*)(h1 + (size_t)BB * HWSZ * COUT);  // frag 128x576
  short* wbf2  = wbf1 + (size_t)128 * 576;             // frag 128x1216
  short* woff1 = wbf2 + (size_t)128 * 1216;            // frag-order 18*1024
  short* woff2 = woff1 + (size_t)18 * 1024;            // frag-order 36*1024

  hipLaunchKernelGGL(prep_all_kernel, dim3((PA5 + 255) / 256), dim3(256), 0, stream,
                     dc1_w, dc2_w, id_w, dc1_offw, dc2_offw,
                     bn1_g, bn1_b, bn1_m, bn1_v, bn2_g, bn2_b, bn2_m, bn2_v,
                     bn3_g, bn3_b, bn3_m, bn3_v, id_b,
                     wbf1, wbf2, woff1, woff2, cb1, cb2);
  hipLaunchKernelGGL(xcast_kernel, dim3(BB * HWSZ / 64), dim3(256), 0, stream, x, xbf);

  // --- layer 1 ---
  hipLaunchKernelGGL(offconv_mfma_kernel, dim3(512), dim3(512), 0, stream,
                     xbf, woff1, dc1_offb, off1, 6);
  hipLaunchKernelGGL((deform_mfma_kernel<6, 576, 576, 0>), dim3(512), dim3(512), 0, stream,
                     xbf, off1, wbf1, cb1, (const unsigned short*)nullptr,
                     (float*)nullptr, h1);
  // --- layer 2 (identity residual folded into GEMM) ---
  hipLaunchKernelGGL(offconv_mfma_kernel, dim3(512), dim3(512), 0, stream,
                     h1, woff2, dc2_offb, off2, 7);
  hipLaunchKernelGGL((deform_mfma_kernel<7, 1152, 1216, 1>), dim3(512), dim3(512), 0, stream,
                     h1, off2, wbf2, cb2, xbf, (float*)d_out,
                     (unsigned short*)nullptr);
}

// Round 10
// 187.529 us; speedup vs baseline: 2.2153x; 1.0332x over previous
//
#include <hip/hip_runtime.h>
#include <math.h>

#define HH 128
#define WW 128
#define HWSZ (HH * WW)
#define BB 2
#define COUT 128

typedef __bf16 bf16x8 __attribute__((ext_vector_type(8)));
typedef float f32x4 __attribute__((ext_vector_type(4)));
typedef float f32x2 __attribute__((ext_vector_type(2)));
typedef short s16x8 __attribute__((ext_vector_type(8)));
typedef short s16x4 __attribute__((ext_vector_type(4)));
typedef unsigned short u16x4 __attribute__((ext_vector_type(4)));
typedef unsigned short u16x8 __attribute__((ext_vector_type(8)));

__device__ __forceinline__ short tobf(float f) {
  union { float f; unsigned u; } v; v.f = f;
  unsigned r = v.u + 0x7fffu + ((v.u >> 16) & 1u);  // RNE
  return (short)(r >> 16);
}
__device__ __forceinline__ float asf(unsigned u) {
  union { unsigned u; float f; } v; v.u = u;
  return v.f;
}
__device__ __forceinline__ f32x2 up2(unsigned u) {   // 2 bf16 -> 2 f32
  f32x2 r; r[0] = asf(u << 16); r[1] = asf(u & 0xffff0000u); return r;
}
// truncating pack of 2 f32 -> 2 bf16 in ONE v_perm_b32 (vs ~9 ops for RNE)
__device__ __forceinline__ unsigned trunc2bf(f32x2 v) {
  union { float f; unsigned u; } a, b;
  a.f = v[0]; b.f = v[1];
  return __builtin_amdgcn_perm(b.u, a.u, 0x07060302u);
}

// ---------------------------------------------------------------------------
// Merged prep (identical to round 9: wbf in MFMA A-fragment order).
// ---------------------------------------------------------------------------
#define PA0 73728
#define PA1 221184
#define PA2 229376
#define PA3 247808
#define PA4 284672
#define PA5 284928
__global__ __launch_bounds__(256) void prep_all_kernel(
    const float* __restrict__ dc1_w, const float* __restrict__ dc2_w,
    const float* __restrict__ id_w, const float* __restrict__ dc1_offw,
    const float* __restrict__ dc2_offw,
    const float* g1, const float* b1, const float* m1, const float* v1,
    const float* g2, const float* b2, const float* m2, const float* v2,
    const float* g3, const float* b3, const float* m3, const float* v3,
    const float* idb,
    short* __restrict__ wbf1, short* __restrict__ wbf2,
    short* __restrict__ woff1, short* __restrict__ woff2,
    float* __restrict__ cb1, float* __restrict__ cb2) {
  int idx = blockIdx.x * 256 + threadIdx.x;
  if (idx < PA0) {
    int o = idx / 576, k = idx - o * 576;
    float inv = g1[o] / sqrtf(v1[o] + 1e-5f);
    int col = (k % 9) * 64 + k / 9;
    int di = (((col >> 5) * 2 + (o >> 6)) * 4 + ((o >> 4) & 3)) * 512
           + (((o & 15) | (((col >> 3) & 3) << 4)) * 8) + (col & 7);
    wbf1[di] = tobf(dc1_w[(size_t)o * 576 + k] * inv);
  } else if (idx < PA1) {
    int j = idx - PA0;
    int o = j / 1152, k = j - o * 1152;
    float inv = g2[o] / sqrtf(v2[o] + 1e-5f);
    int col = (k % 9) * 128 + k / 9;
    int di = (((col >> 5) * 2 + (o >> 6)) * 4 + ((o >> 4) & 3)) * 512
           + (((o & 15) | (((col >> 3) & 3) << 4)) * 8) + (col & 7);
    wbf2[di] = tobf(dc2_w[(size_t)o * 1152 + k] * inv);
  } else if (idx < PA2) {
    int j = idx - PA1;
    int o = j >> 6, k = j & 63;
    float inv = g3[o] / sqrtf(v3[o] + 1e-5f);
    int col = 1152 + k;
    int di = (((col >> 5) * 2 + (o >> 6)) * 4 + ((o >> 4) & 3)) * 512
           + (((o & 15) | (((col >> 3) & 3) << 4)) * 8) + (col & 7);
    wbf2[di] = tobf(id_w[(size_t)o * 64 + k] * inv);
  } else if (idx < PA3) {
    int j = idx - PA2;
    int o = j / 576, k = j - o * 576;
    int col = (k % 9) * 64 + k / 9;
    int di = ((col >> 5) * 2 + (o >> 4)) * 512 + ((col >> 3) & 3) * 128
           + (o & 15) * 8 + (col & 7);
    woff1[di] = (o < 18) ? tobf(dc1_offw[(size_t)o * 576 + k]) : (short)0;
  } else if (idx < PA4) {
    int j = idx - PA3;
    int o = j / 1152, k = j - o * 1152;
    int col = (k % 9) * 128 + k / 9;
    int di = ((col >> 5) * 2 + (o >> 4)) * 512 + ((col >> 3) & 3) * 128
           + (o & 15) * 8 + (col & 7);
    woff2[di] = (o < 18) ? tobf(dc2_offw[(size_t)o * 1152 + k]) : (short)0;
  } else if (idx < PA5) {
    int j = idx - PA4;
    if (j < 128) {
      float inv = g1[j] / sqrtf(v1[j] + 1e-5f);
      cb1[j] = b1[j] - m1[j] * inv;
    } else {
      int o = j - 128;
      float inv2_ = g2[o] / sqrtf(v2[o] + 1e-5f);
      float inv3_ = g3[o] / sqrtf(v3[o] + 1e-5f);
      cb2[o] = (b2[o] - m2[o] * inv2_) + idb[o] * inv3_ + (b3[o] - m3[o] * inv3_);
    }
  }
}

// ---------------------------------------------------------------------------
// x (B,64,H,W) fp32 NCHW -> xnhwc (B,H,W,64) bf16
// ---------------------------------------------------------------------------
__global__ __launch_bounds__(256) void xcast_kernel(const float* __restrict__ x,
                                                    unsigned short* __restrict__ xn) {
  __shared__ short lds[64 * 72];
  int tid = threadIdx.x;
  int gp0 = blockIdx.x * 64;
  int b = gp0 >> 14;
  int pl0 = gp0 & 16383;
  int p = tid & 63;
  int cb = (tid >> 6) * 16;
#pragma unroll
  for (int i = 0; i < 16; i++) {
    int c = cb + i;
    lds[p * 72 + c] = tobf(x[((size_t)(b * 64 + c)) * HWSZ + pl0 + p]);
  }
  __syncthreads();
  int pw = tid >> 2, cseg = (tid & 3) * 16;
  u16x8 a = *(const u16x8*)&lds[pw * 72 + cseg];
  u16x8 b8 = *(const u16x8*)&lds[pw * 72 + cseg + 8];
  *(u16x8*)&xn[(size_t)(gp0 + pw) * 64 + cseg] = a;
  *(u16x8*)&xn[(size_t)(gp0 + pw) * 64 + cseg + 8] = b8;
}

// ---------------------------------------------------------------------------
// Offset conv, barrier-free K-loop (unchanged from round 9).
// ---------------------------------------------------------------------------
__global__ __launch_bounds__(512, 4) void offconv_mfma_kernel(
    const unsigned short* __restrict__ in, const short* __restrict__ woff,
    const float* __restrict__ offb, float* __restrict__ off, int cshift) {
  __shared__ float redf[4 * 64 * 8];
  const int tid = threadIdx.x;
  const int lane = tid & 63, wv = tid >> 6;
  const int pxg = wv & 3, kh = wv >> 2;
  const int pb = ((blockIdx.x & 7) << 6) | (blockIdx.x >> 3);
  const int pix0 = pb << 6;
  const int x0 = pix0 & 127, y = (pix0 >> 7) & 127, b = pix0 >> 14;
  const int Cin = 1 << cshift;
  const int HK = (9 << cshift) >> 1;
  const int NCh = HK >> 5;
  const unsigned short* inb = in + (size_t)b * HWSZ * Cin;
  const int l15 = lane & 15, quad = lane >> 4;
  const int px = x0 + pxg * 16 + l15;

  f32x4 acc[2];
  acc[0] = (f32x4){0.f, 0.f, 0.f, 0.f};
  acc[1] = (f32x4){0.f, 0.f, 0.f, 0.f};

  for (int i = 0; i < NCh; i++) {
    int k0 = kh * HK + i * 32;
    int n = k0 >> cshift;
    int c0 = (k0 & (Cin - 1)) + quad * 8;
    int yy = y + n / 3 - 1;
    int xx = px + n % 3 - 1;
    bf16x8 bv = {};
    if (((unsigned)yy < (unsigned)HH) && ((unsigned)xx < (unsigned)WW))
      bv = *(const bf16x8*)&inb[((size_t)yy * WW + xx) * Cin + c0];
    int fbase = (k0 >> 5) * 1024 + lane * 8;
    bf16x8 a0 = *(const bf16x8*)&woff[fbase];
    bf16x8 a1 = *(const bf16x8*)&woff[fbase + 512];
    acc[0] = __builtin_amdgcn_mfma_f32_16x16x32_bf16(a0, bv, acc[0], 0, 0, 0);
    acc[1] = __builtin_amdgcn_mfma_f32_16x16x32_bf16(a1, bv, acc[1], 0, 0, 0);
  }
  if (kh == 1) {
    *(f32x4*)&redf[(pxg * 64 + lane) * 8] = acc[0];
    *(f32x4*)&redf[(pxg * 64 + lane) * 8 + 4] = acc[1];
  }
  __syncthreads();
  if (kh == 0) {
    acc[0] += *(const f32x4*)&redf[(pxg * 64 + lane) * 8];
    acc[1] += *(const f32x4*)&redf[(pxg * 64 + lane) * 8 + 4];
#pragma unroll
    for (int ot = 0; ot < 2; ot++) {
#pragma unroll
      for (int r = 0; r < 4; r++) {
        int o = ot * 16 + quad * 4 + r;
        if (o < 18)
          off[(size_t)(b * 18 + o) * HWSZ + y * WW + px] = acc[ot][r] + offb[o];
      }
    }
  }
}

// ---------------------------------------------------------------------------
// Deformable conv, barrier-free K-loop, NO duplicated sampling.
// Block: 32 px x 128 out, 256 thr = 4 waves = 2 px-groups x 2 K-halves.
// Wave = 16px x 128out x half-K: 8 MFMA/chunk; each pixel sampled by exactly
// one wave per K-chunk. A-fragments direct from fragment-ordered global
// weights (L1-shared); B via 4 tap loads + packed blend + v_perm truncating
// bf16 pack + 4x ds_bpermute transpose. K-halves reduced via LDS f32 once.
// Grid 1024 -> 4 blocks/CU, 16 waves/CU.
// mode 0: h1 NHWC bf16; mode 1: d_out NCHW fp32.
// ---------------------------------------------------------------------------
template <int CSH, int KCONV, int KTOT, int MODE>
__global__ __launch_bounds__(256, 3) void deform_mfma_kernel(
    const unsigned short* __restrict__ in, const float* __restrict__ off,
    const short* __restrict__ wbf, const float* __restrict__ cbv,
    const unsigned short* __restrict__ xid, float* __restrict__ outf,
    unsigned short* __restrict__ outb) {
  __shared__ __align__(16) char smem[25088];
  uint4* dsu = (uint4*)smem;                    // [288] {w01,w23,base,dy|dx}
  f32x4* redf = (f32x4*)smem;                   // [8][128] K-half reduce
  short* trans = (short*)(smem + 16384);        // 32 x 136 (mode 0)

  const int tid = threadIdx.x;
  const int lane = tid & 63, wv = tid >> 6;
  const int pb = ((blockIdx.x & 7) << 7) | (blockIdx.x >> 3);  // XCD swizzle
  const int pix0 = pb << 5;
  const int x0 = pix0 & 127, y = (pix0 >> 7) & 127, b = pix0 >> 14;
  const int Cin = 1 << CSH;
  const unsigned short* inb = in + (size_t)b * HWSZ * Cin;
  const int l15 = lane & 15, quad = lane >> 4;
  const int pxg = wv & 1, kh = wv >> 1;         // wave: 16px x 128out x halfK
  const int dp = pxg * 16 + (lane >> 2);        // sampled pixel (block-local)
  const int cq = lane & 3;                      // sampled channel group
  const int baddr = (((lane & 15) << 2) | (lane >> 4)) << 2;  // bpermute src*4

  // ---- bilinear descriptors: 9 kernel points x 32 pixels ----
  for (int t = tid; t < 288; t += 256) {
    int n = t >> 5, pp = t & 31;
    float offy = off[(size_t)(b * 18 + n) * HWSZ + y * WW + x0 + pp];
    float offx = off[(size_t)(b * 18 + 9 + n) * HWSZ + y * WW + x0 + pp];
    float py = offy + (float)(n / 3 - 1) + (float)(y + 1);
    float px = offx + (float)(n % 3 - 1) + (float)(x0 + pp + 1);
    py = fminf(fmaxf(py, 0.f), 129.f);
    px = fminf(fmaxf(px, 0.f), 129.f);
    float fy = floorf(py), fx = floorf(px);
    float qy1 = fminf(fy + 1.f, 129.f), qx1 = fminf(fx + 1.f, 129.f);
    float ty0 = 1.f + fy - py, ty1 = 1.f - (qy1 - py);
    float tx0 = 1.f + fx - px, tx1 = 1.f - (qx1 - px);
    int iy0 = (int)fy - 1, ix0 = (int)fx - 1;
    int iy1 = (int)qy1 - 1, ix1 = (int)qx1 - 1;
    if ((unsigned)iy0 >= (unsigned)HH) ty0 = 0.f;
    if ((unsigned)iy1 >= (unsigned)HH) ty1 = 0.f;
    if ((unsigned)ix0 >= (unsigned)WW) tx0 = 0.f;
    if ((unsigned)ix1 >= (unsigned)WW) tx1 = 0.f;
    int by0 = min(max(iy0, 0), HH - 1), by1 = min(max(iy1, 0), HH - 1);
    int bx0 = min(max(ix0, 0), WW - 1), bx1 = min(max(ix1, 0), WW - 1);
    uint4 d4;
    d4.x = (unsigned)(unsigned short)tobf(ty0 * tx0)
         | ((unsigned)(unsigned short)tobf(ty0 * tx1) << 16);
    d4.y = (unsigned)(unsigned short)tobf(ty1 * tx0)
         | ((unsigned)(unsigned short)tobf(ty1 * tx1) << 16);
    d4.z = (unsigned)((by0 * WW + bx0) * Cin);
    d4.w = (unsigned)((((by1 - by0) * WW * Cin) << 16) | ((bx1 - bx0) * Cin));
    dsu[t] = d4;
  }

  f32x4 acc[8];
#pragma unroll
  for (int j = 0; j < 8; j++) acc[j] = (f32x4){0.f, 0.f, 0.f, 0.f};

  __syncthreads();            // descriptors ready

  constexpr int NC = KTOT >> 5;
  constexpr int HC = NC >> 1;
  const short* wfb = wbf + lane * 8;

  for (int i = 0; i < HC; i++) {
    int kc = kh * HC + i;
    int k0 = kc << 5;
    const short* wf = wfb + (size_t)kc * 4096;
    bf16x8 a0 = *(const bf16x8*)(wf);
    bf16x8 a1 = *(const bf16x8*)(wf + 512);
    bf16x8 a2 = *(const bf16x8*)(wf + 1024);
    bf16x8 a3 = *(const bf16x8*)(wf + 1536);
    bf16x8 a4 = *(const bf16x8*)(wf + 2048);
    bf16x8 a5 = *(const bf16x8*)(wf + 2560);
    bf16x8 a6 = *(const bf16x8*)(wf + 3072);
    bf16x8 a7 = *(const bf16x8*)(wf + 3584);
    uint4 pk;
    if (k0 < KCONV) {
      int n = k0 >> CSH;
      int c0 = (k0 & (Cin - 1)) + cq * 8;
      uint4 d4 = dsu[(n << 5) + dp];
      int dx = (int)(d4.w & 0xffffu);
      int dy = (int)d4.w >> 16;
      const unsigned short* ptr = inb + (int)d4.z + c0;
      uint4 q00 = *(const uint4*)(ptr);
      uint4 q01 = *(const uint4*)(ptr + dx);
      uint4 q10 = *(const uint4*)(ptr + dy);
      uint4 q11 = *(const uint4*)(ptr + dx + dy);
      float w0 = asf(d4.x << 16), w1 = asf(d4.x & 0xffff0000u);
      float w2 = asf(d4.y << 16), w3 = asf(d4.y & 0xffff0000u);
      f32x2 v0 = up2(q00.x) * w0 + up2(q01.x) * w1 + up2(q10.x) * w2 + up2(q11.x) * w3;
      f32x2 v1 = up2(q00.y) * w0 + up2(q01.y) * w1 + up2(q10.y) * w2 + up2(q11.y) * w3;
      f32x2 v2 = up2(q00.z) * w0 + up2(q01.z) * w1 + up2(q10.z) * w2 + up2(q11.z) * w3;
      f32x2 v3 = up2(q00.w) * w0 + up2(q01.w) * w1 + up2(q10.w) * w2 + up2(q11.w) * w3;
      pk.x = trunc2bf(v0); pk.y = trunc2bf(v1);
      pk.z = trunc2bf(v2); pk.w = trunc2bf(v3);
    } else {
      int c = (k0 - KCONV) + cq * 8;
      pk = *(const uint4*)&xid[((size_t)(b * HWSZ) + y * WW + x0 + dp) * 64 + c];
    }
    union { int i[4]; bf16x8 v; } bu;
    bu.i[0] = __builtin_amdgcn_ds_bpermute(baddr, (int)pk.x);
    bu.i[1] = __builtin_amdgcn_ds_bpermute(baddr, (int)pk.y);
    bu.i[2] = __builtin_amdgcn_ds_bpermute(baddr, (int)pk.z);
    bu.i[3] = __builtin_amdgcn_ds_bpermute(baddr, (int)pk.w);
    bf16x8 bfr = bu.v;
    acc[0] = __builtin_amdgcn_mfma_f32_16x16x32_bf16(a0, bfr, acc[0], 0, 0, 0);
    acc[1] = __builtin_amdgcn_mfma_f32_16x16x32_bf16(a1, bfr, acc[1], 0, 0, 0);
    acc[2] = __builtin_amdgcn_mfma_f32_16x16x32_bf16(a2, bfr, acc[2], 0, 0, 0);
    acc[3] = __builtin_amdgcn_mfma_f32_16x16x32_bf16(a3, bfr, acc[3], 0, 0, 0);
    acc[4] = __builtin_amdgcn_mfma_f32_16x16x32_bf16(a4, bfr, acc[4], 0, 0, 0);
    acc[5] = __builtin_amdgcn_mfma_f32_16x16x32_bf16(a5, bfr, acc[5], 0, 0, 0);
    acc[6] = __builtin_amdgcn_mfma_f32_16x16x32_bf16(a6, bfr, acc[6], 0, 0, 0);
    acc[7] = __builtin_amdgcn_mfma_f32_16x16x32_bf16(a7, bfr, acc[7], 0, 0, 0);
  }

  // ---- K-half reduce (conflict-free [f][pxg*64+lane] f32x4 layout) ----
  __syncthreads();            // all K-loops done; dsu region dead
  if (kh == 1) {
#pragma unroll
    for (int f = 0; f < 8; f++) redf[f * 128 + pxg * 64 + lane] = acc[f];
  }
  __syncthreads();
  if (kh == 0) {
#pragma unroll
    for (int f = 0; f < 8; f++) acc[f] += redf[f * 128 + pxg * 64 + lane];
    if (MODE == 1) {
#pragma unroll
      for (int f = 0; f < 8; f++) {
#pragma unroll
        for (int r = 0; r < 4; r++) {
          int o = (f >> 2) * 64 + (f & 3) * 16 + quad * 4 + r;
          outf[(size_t)(b * COUT + o) * HWSZ + y * WW + x0 + pxg * 16 + l15] =
              fmaxf(acc[f][r] + cbv[o], 0.f);
        }
      }
    } else {
      int pl = pxg * 16 + l15;
#pragma unroll
      for (int f = 0; f < 8; f++) {
        s16x4 t4;
#pragma unroll
        for (int r = 0; r < 4; r++) {
          int o = (f >> 2) * 64 + (f & 3) * 16 + quad * 4 + r;
          t4[r] = tobf(fmaxf(acc[f][r] + cbv[o], 0.f));
        }
        *(s16x4*)&trans[pl * 136 + (f >> 2) * 64 + (f & 3) * 16 + quad * 4] = t4;
      }
    }
  }
  if (MODE == 0) {
    __syncthreads();
    int pw = tid >> 3, cs = (tid & 7) * 16;
    u16x8 va = *(const u16x8*)&trans[pw * 136 + cs];
    u16x8 vb = *(const u16x8*)&trans[pw * 136 + cs + 8];
    size_t gb = ((size_t)(b * HWSZ) + y * WW + x0 + pw) * 128 + cs;
    *(u16x8*)&outb[gb] = va;
    *(u16x8*)&outb[gb + 8] = vb;
  }
}

// ---------------------------------------------------------------------------
extern "C" void kernel_launch(void* const* d_in, const int* in_sizes, int n_in,
                              void* d_out, int out_size, void* d_ws, size_t ws_size,
                              hipStream_t stream) {
  const float* x        = (const float*)d_in[0];
  const float* dc1_offw = (const float*)d_in[1];
  const float* dc1_offb = (const float*)d_in[2];
  const float* dc1_w    = (const float*)d_in[3];
  const float* bn1_g    = (const float*)d_in[4];
  const float* bn1_b    = (const float*)d_in[5];
  const float* bn1_m    = (const float*)d_in[6];
  const float* bn1_v    = (const float*)d_in[7];
  const float* dc2_offw = (const float*)d_in[8];
  const float* dc2_offb = (const float*)d_in[9];
  const float* dc2_w    = (const float*)d_in[10];
  const float* bn2_g    = (const float*)d_in[11];
  const float* bn2_b    = (const float*)d_in[12];
  const float* bn2_m    = (const float*)d_in[13];
  const float* bn2_v    = (const float*)d_in[14];
  const float* id_w     = (const float*)d_in[15];
  const float* id_b     = (const float*)d_in[16];
  const float* bn3_g    = (const float*)d_in[17];
  const float* bn3_b    = (const float*)d_in[18];
  const float* bn3_m    = (const float*)d_in[19];
  const float* bn3_v    = (const float*)d_in[20];

  float* wsf = (float*)d_ws;
  float* off1 = wsf;                                   // 2*18*16384 f
  float* off2 = off1 + (size_t)BB * 18 * HWSZ;
  float* cb1  = off2 + (size_t)BB * 18 * HWSZ;
  float* cb2  = cb1 + 128;
  unsigned short* xbf = (unsigned short*)(cb2 + 128);  // NHWC (B,H,W,64)
  unsigned short* h1  = xbf + (size_t)BB * HWSZ * 64;  // NHWC (B,H,W,128)
  short* wbf1  = (short*)(h1 + (size_t)BB * HWSZ * COUT);  // frag 128x576
  short* wbf2  = wbf1 + (size_t)128 * 576;             // frag 128x1216
  short* woff1 = wbf2 + (size_t)128 * 1216;            // frag-order 18*1024
  short* woff2 = woff1 + (size_t)18 * 1024;            // frag-order 36*1024

  hipLaunchKernelGGL(prep_all_kernel, dim3((PA5 + 255) / 256), dim3(256), 0, stream,
                     dc1_w, dc2_w, id_w, dc1_offw, dc2_offw,
                     bn1_g, bn1_b, bn1_m, bn1_v, bn2_g, bn2_b, bn2_m, bn2_v,
                     bn3_g, bn3_b, bn3_m, bn3_v, id_b,
                     wbf1, wbf2, woff1, woff2, cb1, cb2);
  hipLaunchKernelGGL(xcast_kernel, dim3(BB * HWSZ / 64), dim3(256), 0, stream, x, xbf);

  // --- layer 1 ---
  hipLaunchKernelGGL(offconv_mfma_kernel, dim3(512), dim3(512), 0, stream,
                     xbf, woff1, dc1_offb, off1, 6);
  hipLaunchKernelGGL((deform_mfma_kernel<6, 576, 576, 0>), dim3(1024), dim3(256), 0, stream,
                     xbf, off1, wbf1, cb1, (const unsigned short*)nullptr,
                     (float*)nullptr, h1);
  // --- layer 2 (identity residual folded into GEMM) ---
  hipLaunchKernelGGL(offconv_mfma_kernel, dim3(512), dim3(512), 0, stream,
                     h1, woff2, dc2_offb, off2, 7);
  hipLaunchKernelGGL((deform_mfma_kernel<7, 1152, 1216, 1>), dim3(1024), dim3(256), 0, stream,
                     h1, off2, wbf2, cb2, xbf, (float*)d_out,
                     (unsigned short*)nullptr);
}

// Round 11
// 182.453 us; speedup vs baseline: 2.2770x; 1.0278x over previous
//
#include <hip/hip_runtime.h>
#include <math.h>

#define HH 128
#define WW 128
#define HWSZ (HH * WW)
#define BB 2
#define COUT 128

typedef __bf16 bf16x8 __attribute__((ext_vector_type(8)));
typedef float f32x4 __attribute__((ext_vector_type(4)));
typedef float f32x2 __attribute__((ext_vector_type(2)));
typedef short s16x8 __attribute__((ext_vector_type(8)));
typedef short s16x4 __attribute__((ext_vector_type(4)));
typedef unsigned short u16x4 __attribute__((ext_vector_type(4)));
typedef unsigned short u16x8 __attribute__((ext_vector_type(8)));

__device__ __forceinline__ short tobf(float f) {
  union { float f; unsigned u; } v; v.f = f;
  unsigned r = v.u + 0x7fffu + ((v.u >> 16) & 1u);  // RNE
  return (short)(r >> 16);
}
__device__ __forceinline__ float asf(unsigned u) {
  union { unsigned u; float f; } v; v.u = u;
  return v.f;
}
__device__ __forceinline__ f32x2 up2(unsigned u) {   // 2 bf16 -> 2 f32
  f32x2 r; r[0] = asf(u << 16); r[1] = asf(u & 0xffff0000u); return r;
}
// truncating pack of 2 f32 -> 2 bf16 in ONE v_perm_b32
__device__ __forceinline__ unsigned trunc2bf(f32x2 v) {
  union { float f; unsigned u; } a, b;
  a.f = v[0]; b.f = v[1];
  return __builtin_amdgcn_perm(b.u, a.u, 0x07060302u);
}

// ---------------------------------------------------------------------------
// Merged prep (identical to round 9/10: wbf in MFMA A-fragment order).
// ---------------------------------------------------------------------------
#define PA0 73728
#define PA1 221184
#define PA2 229376
#define PA3 247808
#define PA4 284672
#define PA5 284928
__global__ __launch_bounds__(256) void prep_all_kernel(
    const float* __restrict__ dc1_w, const float* __restrict__ dc2_w,
    const float* __restrict__ id_w, const float* __restrict__ dc1_offw,
    const float* __restrict__ dc2_offw,
    const float* g1, const float* b1, const float* m1, const float* v1,
    const float* g2, const float* b2, const float* m2, const float* v2,
    const float* g3, const float* b3, const float* m3, const float* v3,
    const float* idb,
    short* __restrict__ wbf1, short* __restrict__ wbf2,
    short* __restrict__ woff1, short* __restrict__ woff2,
    float* __restrict__ cb1, float* __restrict__ cb2) {
  int idx = blockIdx.x * 256 + threadIdx.x;
  if (idx < PA0) {
    int o = idx / 576, k = idx - o * 576;
    float inv = g1[o] / sqrtf(v1[o] + 1e-5f);
    int col = (k % 9) * 64 + k / 9;
    int di = (((col >> 5) * 2 + (o >> 6)) * 4 + ((o >> 4) & 3)) * 512
           + (((o & 15) | (((col >> 3) & 3) << 4)) * 8) + (col & 7);
    wbf1[di] = tobf(dc1_w[(size_t)o * 576 + k] * inv);
  } else if (idx < PA1) {
    int j = idx - PA0;
    int o = j / 1152, k = j - o * 1152;
    float inv = g2[o] / sqrtf(v2[o] + 1e-5f);
    int col = (k % 9) * 128 + k / 9;
    int di = (((col >> 5) * 2 + (o >> 6)) * 4 + ((o >> 4) & 3)) * 512
           + (((o & 15) | (((col >> 3) & 3) << 4)) * 8) + (col & 7);
    wbf2[di] = tobf(dc2_w[(size_t)o * 1152 + k] * inv);
  } else if (idx < PA2) {
    int j = idx - PA1;
    int o = j >> 6, k = j & 63;
    float inv = g3[o] / sqrtf(v3[o] + 1e-5f);
    int col = 1152 + k;
    int di = (((col >> 5) * 2 + (o >> 6)) * 4 + ((o >> 4) & 3)) * 512
           + (((o & 15) | (((col >> 3) & 3) << 4)) * 8) + (col & 7);
    wbf2[di] = tobf(id_w[(size_t)o * 64 + k] * inv);
  } else if (idx < PA3) {
    int j = idx - PA2;
    int o = j / 576, k = j - o * 576;
    int col = (k % 9) * 64 + k / 9;
    int di = ((col >> 5) * 2 + (o >> 4)) * 512 + ((col >> 3) & 3) * 128
           + (o & 15) * 8 + (col & 7);
    woff1[di] = (o < 18) ? tobf(dc1_offw[(size_t)o * 576 + k]) : (short)0;
  } else if (idx < PA4) {
    int j = idx - PA3;
    int o = j / 1152, k = j - o * 1152;
    int col = (k % 9) * 128 + k / 9;
    int di = ((col >> 5) * 2 + (o >> 4)) * 512 + ((col >> 3) & 3) * 128
           + (o & 15) * 8 + (col & 7);
    woff2[di] = (o < 18) ? tobf(dc2_offw[(size_t)o * 1152 + k]) : (short)0;
  } else if (idx < PA5) {
    int j = idx - PA4;
    if (j < 128) {
      float inv = g1[j] / sqrtf(v1[j] + 1e-5f);
      cb1[j] = b1[j] - m1[j] * inv;
    } else {
      int o = j - 128;
      float inv2_ = g2[o] / sqrtf(v2[o] + 1e-5f);
      float inv3_ = g3[o] / sqrtf(v3[o] + 1e-5f);
      cb2[o] = (b2[o] - m2[o] * inv2_) + idb[o] * inv3_ + (b3[o] - m3[o] * inv3_);
    }
  }
}

// ---------------------------------------------------------------------------
// x (B,64,H,W) fp32 NCHW -> xnhwc (B,H,W,64) bf16
// ---------------------------------------------------------------------------
__global__ __launch_bounds__(256) void xcast_kernel(const float* __restrict__ x,
                                                    unsigned short* __restrict__ xn) {
  __shared__ short lds[64 * 72];
  int tid = threadIdx.x;
  int gp0 = blockIdx.x * 64;
  int b = gp0 >> 14;
  int pl0 = gp0 & 16383;
  int p = tid & 63;
  int cb = (tid >> 6) * 16;
#pragma unroll
  for (int i = 0; i < 16; i++) {
    int c = cb + i;
    lds[p * 72 + c] = tobf(x[((size_t)(b * 64 + c)) * HWSZ + pl0 + p]);
  }
  __syncthreads();
  int pw = tid >> 2, cseg = (tid & 3) * 16;
  u16x8 a = *(const u16x8*)&lds[pw * 72 + cseg];
  u16x8 b8 = *(const u16x8*)&lds[pw * 72 + cseg + 8];
  *(u16x8*)&xn[(size_t)(gp0 + pw) * 64 + cseg] = a;
  *(u16x8*)&xn[(size_t)(gp0 + pw) * 64 + cseg + 8] = b8;
}

// ---------------------------------------------------------------------------
// Offset conv, barrier-free K-loop; templated Cin + full unroll so the
// compiler hoists loads across chunks (software pipelining).
// ---------------------------------------------------------------------------
template <int CSH>
__global__ __launch_bounds__(512, 4) void offconv_mfma_kernel(
    const unsigned short* __restrict__ in, const short* __restrict__ woff,
    const float* __restrict__ offb, float* __restrict__ off) {
  __shared__ float redf[4 * 64 * 8];
  constexpr int Cin = 1 << CSH;
  constexpr int HK = (9 << CSH) >> 1;
  constexpr int NCh = HK >> 5;
  const int tid = threadIdx.x;
  const int lane = tid & 63, wv = tid >> 6;
  const int pxg = wv & 3, kh = wv >> 2;
  const int pb = ((blockIdx.x & 7) << 6) | (blockIdx.x >> 3);
  const int pix0 = pb << 6;
  const int x0 = pix0 & 127, y = (pix0 >> 7) & 127, b = pix0 >> 14;
  const unsigned short* inb = in + (size_t)b * HWSZ * Cin;
  const int l15 = lane & 15, quad = lane >> 4;
  const int px = x0 + pxg * 16 + l15;

  f32x4 acc[2];
  acc[0] = (f32x4){0.f, 0.f, 0.f, 0.f};
  acc[1] = (f32x4){0.f, 0.f, 0.f, 0.f};

#pragma unroll
  for (int i = 0; i < NCh; i++) {
    int k0 = kh * HK + i * 32;
    int n = k0 >> CSH;
    int c0 = (k0 & (Cin - 1)) + quad * 8;
    int yy = y + n / 3 - 1;
    int xx = px + n % 3 - 1;
    bf16x8 bv = {};
    if (((unsigned)yy < (unsigned)HH) && ((unsigned)xx < (unsigned)WW))
      bv = *(const bf16x8*)&inb[((size_t)yy * WW + xx) * Cin + c0];
    int fbase = (k0 >> 5) * 1024 + lane * 8;
    bf16x8 a0 = *(const bf16x8*)&woff[fbase];
    bf16x8 a1 = *(const bf16x8*)&woff[fbase + 512];
    acc[0] = __builtin_amdgcn_mfma_f32_16x16x32_bf16(a0, bv, acc[0], 0, 0, 0);
    acc[1] = __builtin_amdgcn_mfma_f32_16x16x32_bf16(a1, bv, acc[1], 0, 0, 0);
  }
  if (kh == 1) {
    *(f32x4*)&redf[(pxg * 64 + lane) * 8] = acc[0];
    *(f32x4*)&redf[(pxg * 64 + lane) * 8 + 4] = acc[1];
  }
  __syncthreads();
  if (kh == 0) {
    acc[0] += *(const f32x4*)&redf[(pxg * 64 + lane) * 8];
    acc[1] += *(const f32x4*)&redf[(pxg * 64 + lane) * 8 + 4];
#pragma unroll
    for (int ot = 0; ot < 2; ot++) {
#pragma unroll
      for (int r = 0; r < 4; r++) {
        int o = ot * 16 + quad * 4 + r;
        if (o < 18)
          off[(size_t)(b * 18 + o) * HWSZ + y * WW + px] = acc[ot][r] + offb[o];
      }
    }
  }
}

// ---------------------------------------------------------------------------
// Deformable conv, barrier-free K-loop + MANUAL DEPTH-1 SOFTWARE PIPELINE
// in named register sets (A/B macros - the round-8 no-spill pattern).
// Block: 32 px x 128 out, 256 thr = 4 waves = 2 px-groups x 2 K-halves.
// Per chunk: 8 A-frag global loads + 4 tap loads issued one chunk AHEAD of
// the blend+bpermute+8xMFMA that consumes them. Residual (identity) chunks
// handled in a separate post-loop. K-halves reduced via LDS f32 once.
// ---------------------------------------------------------------------------
#define LOADW(P, kc_)                                           \
  {                                                             \
    const short* wf_ = wfb + (size_t)(kc_) * 4096;              \
    P##w0 = *(const bf16x8*)(wf_);                              \
    P##w1 = *(const bf16x8*)(wf_ + 512);                        \
    P##w2 = *(const bf16x8*)(wf_ + 1024);                       \
    P##w3 = *(const bf16x8*)(wf_ + 1536);                       \
    P##w4 = *(const bf16x8*)(wf_ + 2048);                       \
    P##w5 = *(const bf16x8*)(wf_ + 2560);                       \
    P##w6 = *(const bf16x8*)(wf_ + 3072);                       \
    P##w7 = *(const bf16x8*)(wf_ + 3584);                       \
  }

#define LOADT(P, kc_)                                           \
  {                                                             \
    int k0_ = (kc_) << 5;                                       \
    int n_ = k0_ >> CSH;                                        \
    int c0_ = (k0_ & (Cin - 1)) + cq * 8;                       \
    uint4 d4_ = dsu[(n_ << 5) + dp];                            \
    int dx_ = (int)(d4_.w & 0xffffu);                           \
    int dy_ = (int)d4_.w >> 16;                                 \
    const unsigned short* ptr_ = inb + (int)d4_.z + c0_;        \
    P##q0 = *(const uint4*)(ptr_);                              \
    P##q1 = *(const uint4*)(ptr_ + dx_);                        \
    P##q2 = *(const uint4*)(ptr_ + dy_);                        \
    P##q3 = *(const uint4*)(ptr_ + dx_ + dy_);                  \
    P##wa = d4_.x;                                              \
    P##wb = d4_.y;                                              \
  }

#define COMPUTE(P)                                                            \
  {                                                                           \
    float w0_ = asf(P##wa << 16), w1_ = asf(P##wa & 0xffff0000u);             \
    float w2_ = asf(P##wb << 16), w3_ = asf(P##wb & 0xffff0000u);             \
    f32x2 v0_ = up2(P##q0.x) * w0_ + up2(P##q1.x) * w1_                       \
              + up2(P##q2.x) * w2_ + up2(P##q3.x) * w3_;                      \
    f32x2 v1_ = up2(P##q0.y) * w0_ + up2(P##q1.y) * w1_                       \
              + up2(P##q2.y) * w2_ + up2(P##q3.y) * w3_;                      \
    f32x2 v2_ = up2(P##q0.z) * w0_ + up2(P##q1.z) * w1_                       \
              + up2(P##q2.z) * w2_ + up2(P##q3.z) * w3_;                      \
    f32x2 v3_ = up2(P##q0.w) * w0_ + up2(P##q1.w) * w1_                       \
              + up2(P##q2.w) * w2_ + up2(P##q3.w) * w3_;                      \
    union { int i[4]; bf16x8 v; } bu_;                                        \
    bu_.i[0] = __builtin_amdgcn_ds_bpermute(baddr, (int)trunc2bf(v0_));       \
    bu_.i[1] = __builtin_amdgcn_ds_bpermute(baddr, (int)trunc2bf(v1_));       \
    bu_.i[2] = __builtin_amdgcn_ds_bpermute(baddr, (int)trunc2bf(v2_));       \
    bu_.i[3] = __builtin_amdgcn_ds_bpermute(baddr, (int)trunc2bf(v3_));       \
    bf16x8 bfr_ = bu_.v;                                                      \
    acc[0] = __builtin_amdgcn_mfma_f32_16x16x32_bf16(P##w0, bfr_, acc[0], 0, 0, 0); \
    acc[1] = __builtin_amdgcn_mfma_f32_16x16x32_bf16(P##w1, bfr_, acc[1], 0, 0, 0); \
    acc[2] = __builtin_amdgcn_mfma_f32_16x16x32_bf16(P##w2, bfr_, acc[2], 0, 0, 0); \
    acc[3] = __builtin_amdgcn_mfma_f32_16x16x32_bf16(P##w3, bfr_, acc[3], 0, 0, 0); \
    acc[4] = __builtin_amdgcn_mfma_f32_16x16x32_bf16(P##w4, bfr_, acc[4], 0, 0, 0); \
    acc[5] = __builtin_amdgcn_mfma_f32_16x16x32_bf16(P##w5, bfr_, acc[5], 0, 0, 0); \
    acc[6] = __builtin_amdgcn_mfma_f32_16x16x32_bf16(P##w6, bfr_, acc[6], 0, 0, 0); \
    acc[7] = __builtin_amdgcn_mfma_f32_16x16x32_bf16(P##w7, bfr_, acc[7], 0, 0, 0); \
  }

template <int CSH, int KCONV, int KTOT, int MODE>
__global__ __launch_bounds__(256, 3) void deform_mfma_kernel(
    const unsigned short* __restrict__ in, const float* __restrict__ off,
    const short* __restrict__ wbf, const float* __restrict__ cbv,
    const unsigned short* __restrict__ xid, float* __restrict__ outf,
    unsigned short* __restrict__ outb) {
  __shared__ __align__(16) char smem[25088];
  uint4* dsu = (uint4*)smem;                    // [288] {w01,w23,base,dy|dx}
  f32x4* redf = (f32x4*)smem;                   // [8][128] K-half reduce
  short* trans = (short*)(smem + 16384);        // 32 x 136 (mode 0)

  const int tid = threadIdx.x;
  const int lane = tid & 63, wv = tid >> 6;
  const int pb = ((blockIdx.x & 7) << 7) | (blockIdx.x >> 3);  // XCD swizzle
  const int pix0 = pb << 5;
  const int x0 = pix0 & 127, y = (pix0 >> 7) & 127, b = pix0 >> 14;
  constexpr int Cin = 1 << CSH;
  const unsigned short* inb = in + (size_t)b * HWSZ * Cin;
  const int l15 = lane & 15, quad = lane >> 4;
  const int pxg = wv & 1, kh = wv >> 1;         // wave: 16px x 128out x halfK
  const int dp = pxg * 16 + (lane >> 2);        // sampled pixel (block-local)
  const int cq = lane & 3;                      // sampled channel group
  const int baddr = (((lane & 15) << 2) | (lane >> 4)) << 2;  // bpermute src*4

  constexpr int NC = KTOT >> 5;
  constexpr int NCONV = KCONV >> 5;
  constexpr int HC = NC >> 1;
  const int kcBeg = kh * HC;
  const int kcEnd = kcBeg + HC;
  const int kcEndConv = (kcEnd < NCONV) ? kcEnd : NCONV;
  const short* wfb = wbf + lane * 8;

  // pipeline register sets (named; no arrays -> no scratch)
  bf16x8 Aw0, Aw1, Aw2, Aw3, Aw4, Aw5, Aw6, Aw7;
  bf16x8 Bw0, Bw1, Bw2, Bw3, Bw4, Bw5, Bw6, Bw7;
  uint4 Aq0, Aq1, Aq2, Aq3, Bq0, Bq1, Bq2, Bq3;
  unsigned Awa, Awb, Bwa, Bwb;

  // chunk-0 weights don't depend on descriptors: issue before the barrier
  LOADW(A, kcBeg);

  // ---- bilinear descriptors: 9 kernel points x 32 pixels ----
  for (int t = tid; t < 288; t += 256) {
    int n = t >> 5, pp = t & 31;
    float offy = off[(size_t)(b * 18 + n) * HWSZ + y * WW + x0 + pp];
    float offx = off[(size_t)(b * 18 + 9 + n) * HWSZ + y * WW + x0 + pp];
    float py = offy + (float)(n / 3 - 1) + (float)(y + 1);
    float px = offx + (float)(n % 3 - 1) + (float)(x0 + pp + 1);
    py = fminf(fmaxf(py, 0.f), 129.f);
    px = fminf(fmaxf(px, 0.f), 129.f);
    float fy = floorf(py), fx = floorf(px);
    float qy1 = fminf(fy + 1.f, 129.f), qx1 = fminf(fx + 1.f, 129.f);
    float ty0 = 1.f + fy - py, ty1 = 1.f - (qy1 - py);
    float tx0 = 1.f + fx - px, tx1 = 1.f - (qx1 - px);
    int iy0 = (int)fy - 1, ix0 = (int)fx - 1;
    int iy1 = (int)qy1 - 1, ix1 = (int)qx1 - 1;
    if ((unsigned)iy0 >= (unsigned)HH) ty0 = 0.f;
    if ((unsigned)iy1 >= (unsigned)HH) ty1 = 0.f;
    if ((unsigned)ix0 >= (unsigned)WW) tx0 = 0.f;
    if ((unsigned)ix1 >= (unsigned)WW) tx1 = 0.f;
    int by0 = min(max(iy0, 0), HH - 1), by1 = min(max(iy1, 0), HH - 1);
    int bx0 = min(max(ix0, 0), WW - 1), bx1 = min(max(ix1, 0), WW - 1);
    uint4 d4;
    d4.x = (unsigned)(unsigned short)tobf(ty0 * tx0)
         | ((unsigned)(unsigned short)tobf(ty0 * tx1) << 16);
    d4.y = (unsigned)(unsigned short)tobf(ty1 * tx0)
         | ((unsigned)(unsigned short)tobf(ty1 * tx1) << 16);
    d4.z = (unsigned)((by0 * WW + bx0) * Cin);
    d4.w = (unsigned)((((by1 - by0) * WW * Cin) << 16) | ((bx1 - bx0) * Cin));
    dsu[t] = d4;
  }

  f32x4 acc[8];
#pragma unroll
  for (int j = 0; j < 8; j++) acc[j] = (f32x4){0.f, 0.f, 0.f, 0.f};

  __syncthreads();            // descriptors ready

  // ---- pipelined conv-chunk loop (ping-pong A/B register sets) ----
  LOADT(A, kcBeg);
  int i = kcBeg;
  for (; i + 2 <= kcEndConv; i += 2) {
    LOADW(B, i + 1);
    LOADT(B, i + 1);
    COMPUTE(A);
    if (i + 2 < kcEndConv) {
      LOADW(A, i + 2);
      LOADT(A, i + 2);
    }
    COMPUTE(B);
  }
  if (i < kcEndConv) {        // odd tail (A holds it)
    COMPUTE(A);
    i++;
  }

  // ---- residual (identity) chunks: layer 2, kh=1 only ----
  if (KCONV < KTOT) {
    for (; i < kcEnd; i++) {
      LOADW(A, i);
      int c = ((i << 5) - KCONV) + cq * 8;
      uint4 pk = *(const uint4*)&xid[((size_t)(b * HWSZ) + y * WW + x0 + dp) * 64 + c];
      union { int i[4]; bf16x8 v; } bu;
      bu.i[0] = __builtin_amdgcn_ds_bpermute(baddr, (int)pk.x);
      bu.i[1] = __builtin_amdgcn_ds_bpermute(baddr, (int)pk.y);
      bu.i[2] = __builtin_amdgcn_ds_bpermute(baddr, (int)pk.z);
      bu.i[3] = __builtin_amdgcn_ds_bpermute(baddr, (int)pk.w);
      bf16x8 bfr = bu.v;
      acc[0] = __builtin_amdgcn_mfma_f32_16x16x32_bf16(Aw0, bfr, acc[0], 0, 0, 0);
      acc[1] = __builtin_amdgcn_mfma_f32_16x16x32_bf16(Aw1, bfr, acc[1], 0, 0, 0);
      acc[2] = __builtin_amdgcn_mfma_f32_16x16x32_bf16(Aw2, bfr, acc[2], 0, 0, 0);
      acc[3] = __builtin_amdgcn_mfma_f32_16x16x32_bf16(Aw3, bfr, acc[3], 0, 0, 0);
      acc[4] = __builtin_amdgcn_mfma_f32_16x16x32_bf16(Aw4, bfr, acc[4], 0, 0, 0);
      acc[5] = __builtin_amdgcn_mfma_f32_16x16x32_bf16(Aw5, bfr, acc[5], 0, 0, 0);
      acc[6] = __builtin_amdgcn_mfma_f32_16x16x32_bf16(Aw6, bfr, acc[6], 0, 0, 0);
      acc[7] = __builtin_amdgcn_mfma_f32_16x16x32_bf16(Aw7, bfr, acc[7], 0, 0, 0);
    }
  }

  // ---- K-half reduce (dsu region dead after this barrier) ----
  __syncthreads();
  if (kh == 1) {
#pragma unroll
    for (int f = 0; f < 8; f++) redf[f * 128 + pxg * 64 + lane] = acc[f];
  }
  __syncthreads();
  if (kh == 0) {
#pragma unroll
    for (int f = 0; f < 8; f++) acc[f] += redf[f * 128 + pxg * 64 + lane];
    if (MODE == 1) {
#pragma unroll
      for (int f = 0; f < 8; f++) {
#pragma unroll
        for (int r = 0; r < 4; r++) {
          int o = (f >> 2) * 64 + (f & 3) * 16 + quad * 4 + r;
          outf[(size_t)(b * COUT + o) * HWSZ + y * WW + x0 + pxg * 16 + l15] =
              fmaxf(acc[f][r] + cbv[o], 0.f);
        }
      }
    } else {
      int pl = pxg * 16 + l15;
#pragma unroll
      for (int f = 0; f < 8; f++) {
        s16x4 t4;
#pragma unroll
        for (int r = 0; r < 4; r++) {
          int o = (f >> 2) * 64 + (f & 3) * 16 + quad * 4 + r;
          t4[r] = tobf(fmaxf(acc[f][r] + cbv[o], 0.f));
        }
        *(s16x4*)&trans[pl * 136 + (f >> 2) * 64 + (f & 3) * 16 + quad * 4] = t4;
      }
    }
  }
  if (MODE == 0) {
    __syncthreads();
    int pw = tid >> 3, cs = (tid & 7) * 16;
    u16x8 va = *(const u16x8*)&trans[pw * 136 + cs];
    u16x8 vb = *(const u16x8*)&trans[pw * 136 + cs + 8];
    size_t gb = ((size_t)(b * HWSZ) + y * WW + x0 + pw) * 128 + cs;
    *(u16x8*)&outb[gb] = va;
    *(u16x8*)&outb[gb + 8] = vb;
  }
}

// ---------------------------------------------------------------------------
extern "C" void kernel_launch(void* const* d_in, const int* in_sizes, int n_in,
                              void* d_out, int out_size, void* d_ws, size_t ws_size,
                              hipStream_t stream) {
  const float* x        = (const float*)d_in[0];
  const float* dc1_offw = (const float*)d_in[1];
  const float* dc1_offb = (const float*)d_in[2];
  const float* dc1_w    = (const float*)d_in[3];
  const float* bn1_g    = (const float*)d_in[4];
  const float* bn1_b    = (const float*)d_in[5];
  const float* bn1_m    = (const float*)d_in[6];
  const float* bn1_v    = (const float*)d_in[7];
  const float* dc2_offw = (const float*)d_in[8];
  const float* dc2_offb = (const float*)d_in[9];
  const float* dc2_w    = (const float*)d_in[10];
  const float* bn2_g    = (const float*)d_in[11];
  const float* bn2_b    = (const float*)d_in[12];
  const float* bn2_m    = (const float*)d_in[13];
  const float* bn2_v    = (const float*)d_in[14];
  const float* id_w     = (const float*)d_in[15];
  const float* id_b     = (const float*)d_in[16];
  const float* bn3_g    = (const float*)d_in[17];
  const float* bn3_b    = (const float*)d_in[18];
  const float* bn3_m    = (const float*)d_in[19];
  const float* bn3_v    = (const float*)d_in[20];

  float* wsf = (float*)d_ws;
  float* off1 = wsf;                                   // 2*18*16384 f
  float* off2 = off1 + (size_t)BB * 18 * HWSZ;
  float* cb1  = off2 + (size_t)BB * 18 * HWSZ;
  float* cb2  = cb1 + 128;
  unsigned short* xbf = (unsigned short*)(cb2 + 128);  // NHWC (B,H,W,64)
  unsigned short* h1  = xbf + (size_t)BB * HWSZ * 64;  // NHWC (B,H,W,128)
  short* wbf1  = (short*)(h1 + (size_t)BB * HWSZ * COUT);  // frag 128x576
  short* wbf2  = wbf1 + (size_t)128 * 576;             // frag 128x1216
  short* woff1 = wbf2 + (size_t)128 * 1216;            // frag-order 18*1024
  short* woff2 = woff1 + (size_t)18 * 1024;            // frag-order 36*1024

  hipLaunchKernelGGL(prep_all_kernel, dim3((PA5 + 255) / 256), dim3(256), 0, stream,
                     dc1_w, dc2_w, id_w, dc1_offw, dc2_offw,
                     bn1_g, bn1_b, bn1_m, bn1_v, bn2_g, bn2_b, bn2_m, bn2_v,
                     bn3_g, bn3_b, bn3_m, bn3_v, id_b,
                     wbf1, wbf2, woff1, woff2, cb1, cb2);
  hipLaunchKernelGGL(xcast_kernel, dim3(BB * HWSZ / 64), dim3(256), 0, stream, x, xbf);

  // --- layer 1 ---
  hipLaunchKernelGGL((offconv_mfma_kernel<6>), dim3(512), dim3(512), 0, stream,
                     xbf, woff1, dc1_offb, off1);
  hipLaunchKernelGGL((deform_mfma_kernel<6, 576, 576, 0>), dim3(1024), dim3(256), 0, stream,
                     xbf, off1, wbf1, cb1, (const unsigned short*)nullptr,
                     (float*)nullptr, h1);
  // --- layer 2 (identity residual folded into GEMM) ---
  hipLaunchKernelGGL((offconv_mfma_kernel<7>), dim3(512), dim3(512), 0, stream,
                     h1, woff2, dc2_offb, off2);
  hipLaunchKernelGGL((deform_mfma_kernel<7, 1152, 1216, 1>), dim3(1024), dim3(256), 0, stream,
                     h1, off2, wbf2, cb2, xbf, (float*)d_out,
                     (unsigned short*)nullptr);
}

// Round 13
// 178.001 us; speedup vs baseline: 2.3339x; 1.0250x over previous
//
#include <hip/hip_runtime.h>
#include <math.h>

#define HH 128
#define WW 128
#define HWSZ (HH * WW)
#define BB 2
#define COUT 128

typedef __bf16 bf16x8 __attribute__((ext_vector_type(8)));
typedef float f32x4 __attribute__((ext_vector_type(4)));
typedef float f32x2 __attribute__((ext_vector_type(2)));
typedef short s16x8 __attribute__((ext_vector_type(8)));
typedef short s16x4 __attribute__((ext_vector_type(4)));
typedef unsigned short u16x4 __attribute__((ext_vector_type(4)));
typedef unsigned short u16x8 __attribute__((ext_vector_type(8)));

__device__ __forceinline__ short tobf(float f) {
  union { float f; unsigned u; } v; v.f = f;
  unsigned r = v.u + 0x7fffu + ((v.u >> 16) & 1u);  // RNE
  return (short)(r >> 16);
}
__device__ __forceinline__ float asf(unsigned u) {
  union { unsigned u; float f; } v; v.u = u;
  return v.f;
}
__device__ __forceinline__ f32x2 up2(unsigned u) {   // 2 bf16 -> 2 f32
  f32x2 r; r[0] = asf(u << 16); r[1] = asf(u & 0xffff0000u); return r;
}
// truncating pack of 2 f32 -> 2 bf16 in ONE v_perm_b32
__device__ __forceinline__ unsigned trunc2bf(f32x2 v) {
  union { float f; unsigned u; } a, b;
  a.f = v[0]; b.f = v[1];
  return __builtin_amdgcn_perm(b.u, a.u, 0x07060302u);
}

// ---------------------------------------------------------------------------
// Merged prep (identical to rounds 9-11: wbf in MFMA A-fragment order).
// ---------------------------------------------------------------------------
#define PA0 73728
#define PA1 221184
#define PA2 229376
#define PA3 247808
#define PA4 284672
#define PA5 284928
__global__ __launch_bounds__(256) void prep_all_kernel(
    const float* __restrict__ dc1_w, const float* __restrict__ dc2_w,
    const float* __restrict__ id_w, const float* __restrict__ dc1_offw,
    const float* __restrict__ dc2_offw,
    const float* g1, const float* b1, const float* m1, const float* v1,
    const float* g2, const float* b2, const float* m2, const float* v2,
    const float* g3, const float* b3, const float* m3, const float* v3,
    const float* idb,
    short* __restrict__ wbf1, short* __restrict__ wbf2,
    short* __restrict__ woff1, short* __restrict__ woff2,
    float* __restrict__ cb1, float* __restrict__ cb2) {
  int idx = blockIdx.x * 256 + threadIdx.x;
  if (idx < PA0) {
    int o = idx / 576, k = idx - o * 576;
    float inv = g1[o] / sqrtf(v1[o] + 1e-5f);
    int col = (k % 9) * 64 + k / 9;
    int di = (((col >> 5) * 2 + (o >> 6)) * 4 + ((o >> 4) & 3)) * 512
           + (((o & 15) | (((col >> 3) & 3) << 4)) * 8) + (col & 7);
    wbf1[di] = tobf(dc1_w[(size_t)o * 576 + k] * inv);
  } else if (idx < PA1) {
    int j = idx - PA0;
    int o = j / 1152, k = j - o * 1152;
    float inv = g2[o] / sqrtf(v2[o] + 1e-5f);
    int col = (k % 9) * 128 + k / 9;
    int di = (((col >> 5) * 2 + (o >> 6)) * 4 + ((o >> 4) & 3)) * 512
           + (((o & 15) | (((col >> 3) & 3) << 4)) * 8) + (col & 7);
    wbf2[di] = tobf(dc2_w[(size_t)o * 1152 + k] * inv);
  } else if (idx < PA2) {
    int j = idx - PA1;
    int o = j >> 6, k = j & 63;
    float inv = g3[o] / sqrtf(v3[o] + 1e-5f);
    int col = 1152 + k;
    int di = (((col >> 5) * 2 + (o >> 6)) * 4 + ((o >> 4) & 3)) * 512
           + (((o & 15) | (((col >> 3) & 3) << 4)) * 8) + (col & 7);
    wbf2[di] = tobf(id_w[(size_t)o * 64 + k] * inv);
  } else if (idx < PA3) {
    int j = idx - PA2;
    int o = j / 576, k = j - o * 576;
    int col = (k % 9) * 64 + k / 9;
    int di = ((col >> 5) * 2 + (o >> 4)) * 512 + ((col >> 3) & 3) * 128
           + (o & 15) * 8 + (col & 7);
    woff1[di] = (o < 18) ? tobf(dc1_offw[(size_t)o * 576 + k]) : (short)0;
  } else if (idx < PA4) {
    int j = idx - PA3;
    int o = j / 1152, k = j - o * 1152;
    int col = (k % 9) * 128 + k / 9;
    int di = ((col >> 5) * 2 + (o >> 4)) * 512 + ((col >> 3) & 3) * 128
           + (o & 15) * 8 + (col & 7);
    woff2[di] = (o < 18) ? tobf(dc2_offw[(size_t)o * 1152 + k]) : (short)0;
  } else if (idx < PA5) {
    int j = idx - PA4;
    if (j < 128) {
      float inv = g1[j] / sqrtf(v1[j] + 1e-5f);
      cb1[j] = b1[j] - m1[j] * inv;
    } else {
      int o = j - 128;
      float inv2_ = g2[o] / sqrtf(v2[o] + 1e-5f);
      float inv3_ = g3[o] / sqrtf(v3[o] + 1e-5f);
      cb2[o] = (b2[o] - m2[o] * inv2_) + idb[o] * inv3_ + (b3[o] - m3[o] * inv3_);
    }
  }
}

// ---------------------------------------------------------------------------
// x (B,64,H,W) fp32 NCHW -> xnhwc (B,H,W,64) bf16
// ---------------------------------------------------------------------------
__global__ __launch_bounds__(256) void xcast_kernel(const float* __restrict__ x,
                                                    unsigned short* __restrict__ xn) {
  __shared__ short lds[64 * 72];
  int tid = threadIdx.x;
  int gp0 = blockIdx.x * 64;
  int b = gp0 >> 14;
  int pl0 = gp0 & 16383;
  int p = tid & 63;
  int cb = (tid >> 6) * 16;
#pragma unroll
  for (int i = 0; i < 16; i++) {
    int c = cb + i;
    lds[p * 72 + c] = tobf(x[((size_t)(b * 64 + c)) * HWSZ + pl0 + p]);
  }
  __syncthreads();
  int pw = tid >> 2, cseg = (tid & 3) * 16;
  u16x8 a = *(const u16x8*)&lds[pw * 72 + cseg];
  u16x8 b8 = *(const u16x8*)&lds[pw * 72 + cseg + 8];
  *(u16x8*)&xn[(size_t)(gp0 + pw) * 64 + cseg] = a;
  *(u16x8*)&xn[(size_t)(gp0 + pw) * 64 + cseg + 8] = b8;
}

// ---------------------------------------------------------------------------
// Offset conv, barrier-free K-loop (unchanged from round 11).
// ---------------------------------------------------------------------------
template <int CSH>
__global__ __launch_bounds__(512, 4) void offconv_mfma_kernel(
    const unsigned short* __restrict__ in, const short* __restrict__ woff,
    const float* __restrict__ offb, float* __restrict__ off) {
  __shared__ float redf[4 * 64 * 8];
  constexpr int Cin = 1 << CSH;
  constexpr int HK = (9 << CSH) >> 1;
  constexpr int NCh = HK >> 5;
  const int tid = threadIdx.x;
  const int lane = tid & 63, wv = tid >> 6;
  const int pxg = wv & 3, kh = wv >> 2;
  const int pb = ((blockIdx.x & 7) << 6) | (blockIdx.x >> 3);
  const int pix0 = pb << 6;
  const int x0 = pix0 & 127, y = (pix0 >> 7) & 127, b = pix0 >> 14;
  const unsigned short* inb = in + (size_t)b * HWSZ * Cin;
  const int l15 = lane & 15, quad = lane >> 4;
  const int px = x0 + pxg * 16 + l15;

  f32x4 acc[2];
  acc[0] = (f32x4){0.f, 0.f, 0.f, 0.f};
  acc[1] = (f32x4){0.f, 0.f, 0.f, 0.f};

#pragma unroll
  for (int i = 0; i < NCh; i++) {
    int k0 = kh * HK + i * 32;
    int n = k0 >> CSH;
    int c0 = (k0 & (Cin - 1)) + quad * 8;
    int yy = y + n / 3 - 1;
    int xx = px + n % 3 - 1;
    bf16x8 bv = {};
    if (((unsigned)yy < (unsigned)HH) && ((unsigned)xx < (unsigned)WW))
      bv = *(const bf16x8*)&inb[((size_t)yy * WW + xx) * Cin + c0];
    int fbase = (k0 >> 5) * 1024 + lane * 8;
    bf16x8 a0 = *(const bf16x8*)&woff[fbase];
    bf16x8 a1 = *(const bf16x8*)&woff[fbase + 512];
    acc[0] = __builtin_amdgcn_mfma_f32_16x16x32_bf16(a0, bv, acc[0], 0, 0, 0);
    acc[1] = __builtin_amdgcn_mfma_f32_16x16x32_bf16(a1, bv, acc[1], 0, 0, 0);
  }
  if (kh == 1) {
    *(f32x4*)&redf[(pxg * 64 + lane) * 8] = acc[0];
    *(f32x4*)&redf[(pxg * 64 + lane) * 8 + 4] = acc[1];
  }
  __syncthreads();
  if (kh == 0) {
    acc[0] += *(const f32x4*)&redf[(pxg * 64 + lane) * 8];
    acc[1] += *(const f32x4*)&redf[(pxg * 64 + lane) * 8 + 4];
#pragma unroll
    for (int ot = 0; ot < 2; ot++) {
#pragma unroll
      for (int r = 0; r < 4; r++) {
        int o = ot * 16 + quad * 4 + r;
        if (o < 18)
          off[(size_t)(b * 18 + o) * HWSZ + y * WW + px] = acc[ot][r] + offb[o];
      }
    }
  }
}

// ---------------------------------------------------------------------------
// Deformable conv, barrier-free K-loop, wave = 32 px x 128 out (NB=2):
// each weight-stream read feeds 32 px (2x fewer weight L1 bytes/MAC).
// Block: 64 px x 128 out, 256 thr = 4 waves = 2 px-groups x 2 K-halves.
// Depth-1 ping-pong in named registers (no-spill pattern). BLEND1 takes
// explicit register args (no token pasting next to member access).
// ---------------------------------------------------------------------------
#define LOADW(P, kc_)                                           \
  {                                                             \
    const short* wf_ = wfb + (size_t)(kc_) * 4096;              \
    P##w0 = *(const bf16x8*)(wf_);                              \
    P##w1 = *(const bf16x8*)(wf_ + 512);                        \
    P##w2 = *(const bf16x8*)(wf_ + 1024);                       \
    P##w3 = *(const bf16x8*)(wf_ + 1536);                       \
    P##w4 = *(const bf16x8*)(wf_ + 2048);                       \
    P##w5 = *(const bf16x8*)(wf_ + 2560);                       \
    P##w6 = *(const bf16x8*)(wf_ + 3072);                       \
    P##w7 = *(const bf16x8*)(wf_ + 3584);                       \
  }

#define LOADT(P, kc_)                                           \
  {                                                             \
    int k0_ = (kc_) << 5;                                       \
    int n_ = k0_ >> CSH;                                        \
    int c0_ = (k0_ & (Cin - 1)) + cq * 8;                       \
    uint4 d4_ = dsu[(n_ << 6) + dp0];                           \
    int dx_ = (int)(d4_.w & 0xffffu);                           \
    int dy_ = (int)d4_.w >> 16;                                 \
    const unsigned short* p_ = inb + (int)d4_.z + c0_;          \
    P##q00 = *(const uint4*)(p_);                               \
    P##q01 = *(const uint4*)(p_ + dx_);                         \
    P##q02 = *(const uint4*)(p_ + dy_);                         \
    P##q03 = *(const uint4*)(p_ + dx_ + dy_);                   \
    P##wa0 = d4_.x; P##wb0 = d4_.y;                             \
    uint4 e4_ = dsu[(n_ << 6) + dp1];                           \
    int ex_ = (int)(e4_.w & 0xffffu);                           \
    int ey_ = (int)e4_.w >> 16;                                 \
    const unsigned short* q_ = inb + (int)e4_.z + c0_;          \
    P##q10 = *(const uint4*)(q_);                               \
    P##q11 = *(const uint4*)(q_ + ex_);                         \
    P##q12 = *(const uint4*)(q_ + ey_);                         \
    P##q13 = *(const uint4*)(q_ + ex_ + ey_);                   \
    P##wa1 = e4_.x; P##wb1 = e4_.y;                             \
  }

// explicit-register blend: no pasting adjacent to member access
#define BLEND1(r0, r1, r2, r3, wav, wbv, pkv)                                 \
  {                                                                           \
    float w0_ = asf((wav) << 16), w1_ = asf((wav) & 0xffff0000u);             \
    float w2_ = asf((wbv) << 16), w3_ = asf((wbv) & 0xffff0000u);             \
    f32x2 v0_ = up2(r0.x) * w0_ + up2(r1.x) * w1_                             \
              + up2(r2.x) * w2_ + up2(r3.x) * w3_;                            \
    f32x2 v1_ = up2(r0.y) * w0_ + up2(r1.y) * w1_                             \
              + up2(r2.y) * w2_ + up2(r3.y) * w3_;                            \
    f32x2 v2_ = up2(r0.z) * w0_ + up2(r1.z) * w1_                             \
              + up2(r2.z) * w2_ + up2(r3.z) * w3_;                            \
    f32x2 v3_ = up2(r0.w) * w0_ + up2(r1.w) * w1_                             \
              + up2(r2.w) * w2_ + up2(r3.w) * w3_;                            \
    pkv.x = trunc2bf(v0_); pkv.y = trunc2bf(v1_);                             \
    pkv.z = trunc2bf(v2_); pkv.w = trunc2bf(v3_);                             \
  }

#define XPOSE(pkv, bfrv)                                                      \
  {                                                                           \
    union { int i[4]; bf16x8 v; } bu_;                                        \
    bu_.i[0] = __builtin_amdgcn_ds_bpermute(baddr, (int)pkv.x);               \
    bu_.i[1] = __builtin_amdgcn_ds_bpermute(baddr, (int)pkv.y);               \
    bu_.i[2] = __builtin_amdgcn_ds_bpermute(baddr, (int)pkv.z);               \
    bu_.i[3] = __builtin_amdgcn_ds_bpermute(baddr, (int)pkv.w);               \
    bfrv = bu_.v;                                                             \
  }

#define MFMA16(P, bfr0v, bfr1v)                                                     \
  {                                                                                 \
    acc[0] = __builtin_amdgcn_mfma_f32_16x16x32_bf16(P##w0, bfr0v, acc[0], 0, 0, 0);  \
    acc[8] = __builtin_amdgcn_mfma_f32_16x16x32_bf16(P##w0, bfr1v, acc[8], 0, 0, 0);  \
    acc[1] = __builtin_amdgcn_mfma_f32_16x16x32_bf16(P##w1, bfr0v, acc[1], 0, 0, 0);  \
    acc[9] = __builtin_amdgcn_mfma_f32_16x16x32_bf16(P##w1, bfr1v, acc[9], 0, 0, 0);  \
    acc[2] = __builtin_amdgcn_mfma_f32_16x16x32_bf16(P##w2, bfr0v, acc[2], 0, 0, 0);  \
    acc[10] = __builtin_amdgcn_mfma_f32_16x16x32_bf16(P##w2, bfr1v, acc[10], 0, 0, 0);\
    acc[3] = __builtin_amdgcn_mfma_f32_16x16x32_bf16(P##w3, bfr0v, acc[3], 0, 0, 0);  \
    acc[11] = __builtin_amdgcn_mfma_f32_16x16x32_bf16(P##w3, bfr1v, acc[11], 0, 0, 0);\
    acc[4] = __builtin_amdgcn_mfma_f32_16x16x32_bf16(P##w4, bfr0v, acc[4], 0, 0, 0);  \
    acc[12] = __builtin_amdgcn_mfma_f32_16x16x32_bf16(P##w4, bfr1v, acc[12], 0, 0, 0);\
    acc[5] = __builtin_amdgcn_mfma_f32_16x16x32_bf16(P##w5, bfr0v, acc[5], 0, 0, 0);  \
    acc[13] = __builtin_amdgcn_mfma_f32_16x16x32_bf16(P##w5, bfr1v, acc[13], 0, 0, 0);\
    acc[6] = __builtin_amdgcn_mfma_f32_16x16x32_bf16(P##w6, bfr0v, acc[6], 0, 0, 0);  \
    acc[14] = __builtin_amdgcn_mfma_f32_16x16x32_bf16(P##w6, bfr1v, acc[14], 0, 0, 0);\
    acc[7] = __builtin_amdgcn_mfma_f32_16x16x32_bf16(P##w7, bfr0v, acc[7], 0, 0, 0);  \
    acc[15] = __builtin_amdgcn_mfma_f32_16x16x32_bf16(P##w7, bfr1v, acc[15], 0, 0, 0);\
  }

#define COMPUTE(P)                                                            \
  {                                                                           \
    uint4 pk0_, pk1_;                                                         \
    BLEND1(P##q00, P##q01, P##q02, P##q03, P##wa0, P##wb0, pk0_);             \
    BLEND1(P##q10, P##q11, P##q12, P##q13, P##wa1, P##wb1, pk1_);             \
    bf16x8 bf0_, bf1_;                                                        \
    XPOSE(pk0_, bf0_);                                                        \
    XPOSE(pk1_, bf1_);                                                        \
    MFMA16(P, bf0_, bf1_);                                                    \
  }

template <int CSH, int KCONV, int KTOT, int MODE>
__global__ __launch_bounds__(256, 2) void deform_mfma_kernel(
    const unsigned short* __restrict__ in, const float* __restrict__ off,
    const short* __restrict__ wbf, const float* __restrict__ cbv,
    const unsigned short* __restrict__ xid, float* __restrict__ outf,
    unsigned short* __restrict__ outb) {
  __shared__ __align__(16) char smem[50176];
  uint4* dsu = (uint4*)smem;                    // [576] {w01,w23,base,dy|dx}
  f32x4* redf = (f32x4*)smem;                   // [16*128] (overlays dsu)
  short* trans = (short*)(smem + 32768);        // 64 x 136 (mode 0)

  const int tid = threadIdx.x;
  const int lane = tid & 63, wv = tid >> 6;
  const int pb = ((blockIdx.x & 7) << 6) | (blockIdx.x >> 3);  // XCD swizzle
  const int pix0 = pb << 6;
  const int x0 = pix0 & 127, y = (pix0 >> 7) & 127, b = pix0 >> 14;
  constexpr int Cin = 1 << CSH;
  const unsigned short* inb = in + (size_t)b * HWSZ * Cin;
  const int l15 = lane & 15, quad = lane >> 4;
  const int pxg = wv & 1, kh = wv >> 1;         // wave: 32px x 128out x halfK
  const int dp0 = pxg * 32 + (lane >> 2);       // sampled pixel 0
  const int dp1 = dp0 + 16;                     // sampled pixel 1
  const int cq = lane & 3;                      // sampled channel group
  const int baddr = (((lane & 15) << 2) | (lane >> 4)) << 2;  // bpermute src*4

  constexpr int NC = KTOT >> 5;
  constexpr int NCONV = KCONV >> 5;
  constexpr int HC = NC >> 1;
  const int kcBeg = kh * HC;
  const int kcEnd = kcBeg + HC;
  const int kcEndConv = (kcEnd < NCONV) ? kcEnd : NCONV;
  const short* wfb = wbf + lane * 8;

  // pipeline register sets (named; no runtime-indexed arrays -> no scratch)
  bf16x8 Aw0, Aw1, Aw2, Aw3, Aw4, Aw5, Aw6, Aw7;
  bf16x8 Bw0, Bw1, Bw2, Bw3, Bw4, Bw5, Bw6, Bw7;
  uint4 Aq00, Aq01, Aq02, Aq03, Aq10, Aq11, Aq12, Aq13;
  uint4 Bq00, Bq01, Bq02, Bq03, Bq10, Bq11, Bq12, Bq13;
  unsigned Awa0, Awb0, Awa1, Awb1, Bwa0, Bwb0, Bwa1, Bwb1;

  // chunk-0 weights don't depend on descriptors: issue before the barrier
  LOADW(A, kcBeg);

  // ---- bilinear descriptors: 9 kernel points x 64 pixels ----
  for (int t = tid; t < 576; t += 256) {
    int n = t >> 6, pp = t & 63;
    float offy = off[(size_t)(b * 18 + n) * HWSZ + y * WW + x0 + pp];
    float offx = off[(size_t)(b * 18 + 9 + n) * HWSZ + y * WW + x0 + pp];
    float py = offy + (float)(n / 3 - 1) + (float)(y + 1);
    float px = offx + (float)(n % 3 - 1) + (float)(x0 + pp + 1);
    py = fminf(fmaxf(py, 0.f), 129.f);
    px = fminf(fmaxf(px, 0.f), 129.f);
    float fy = floorf(py), fx = floorf(px);
    float qy1 = fminf(fy + 1.f, 129.f), qx1 = fminf(fx + 1.f, 129.f);
    float ty0 = 1.f + fy - py, ty1 = 1.f - (qy1 - py);
    float tx0 = 1.f + fx - px, tx1 = 1.f - (qx1 - px);
    int iy0 = (int)fy - 1, ix0 = (int)fx - 1;
    int iy1 = (int)qy1 - 1, ix1 = (int)qx1 - 1;
    if ((unsigned)iy0 >= (unsigned)HH) ty0 = 0.f;
    if ((unsigned)iy1 >= (unsigned)HH) ty1 = 0.f;
    if ((unsigned)ix0 >= (unsigned)WW) tx0 = 0.f;
    if ((unsigned)ix1 >= (unsigned)WW) tx1 = 0.f;
    int by0 = min(max(iy0, 0), HH - 1), by1 = min(max(iy1, 0), HH - 1);
    int bx0 = min(max(ix0, 0), WW - 1), bx1 = min(max(ix1, 0), WW - 1);
    uint4 d4;
    d4.x = (unsigned)(unsigned short)tobf(ty0 * tx0)
         | ((unsigned)(unsigned short)tobf(ty0 * tx1) << 16);
    d4.y = (unsigned)(unsigned short)tobf(ty1 * tx0)
         | ((unsigned)(unsigned short)tobf(ty1 * tx1) << 16);
    d4.z = (unsigned)((by0 * WW + bx0) * Cin);
    d4.w = (unsigned)((((by1 - by0) * WW * Cin) << 16) | ((bx1 - bx0) * Cin));
    dsu[t] = d4;
  }

  f32x4 acc[16];
#pragma unroll
  for (int j = 0; j < 16; j++) acc[j] = (f32x4){0.f, 0.f, 0.f, 0.f};

  __syncthreads();            // descriptors ready

  // ---- pipelined conv-chunk loop (ping-pong A/B register sets) ----
  LOADT(A, kcBeg);
  int i = kcBeg;
  for (; i + 2 <= kcEndConv; i += 2) {
    LOADW(B, i + 1);
    LOADT(B, i + 1);
    COMPUTE(A);
    if (i + 2 < kcEndConv) {
      LOADW(A, i + 2);
      LOADT(A, i + 2);
    }
    COMPUTE(B);
  }
  if (i < kcEndConv) {        // odd tail (A holds it)
    COMPUTE(A);
    i++;
  }

  // ---- residual (identity) chunks: layer 2, kh=1 only ----
  if (KCONV < KTOT) {
    for (; i < kcEnd; i++) {
      LOADW(A, i);
      int c = ((i << 5) - KCONV) + cq * 8;
      uint4 pk0 = *(const uint4*)&xid[((size_t)(b * HWSZ) + y * WW + x0 + dp0) * 64 + c];
      uint4 pk1 = *(const uint4*)&xid[((size_t)(b * HWSZ) + y * WW + x0 + dp1) * 64 + c];
      bf16x8 bf0, bf1;
      XPOSE(pk0, bf0);
      XPOSE(pk1, bf1);
      MFMA16(A, bf0, bf1);
    }
  }

  // ---- K-half reduce (redf overlays dsu; dsu dead after this barrier) ----
  __syncthreads();
  if (kh == 1) {
#pragma unroll
    for (int f = 0; f < 16; f++) redf[f * 128 + pxg * 64 + lane] = acc[f];
  }
  __syncthreads();
  if (kh == 0) {
#pragma unroll
    for (int f = 0; f < 16; f++) acc[f] += redf[f * 128 + pxg * 64 + lane];
    if (MODE == 1) {
#pragma unroll
      for (int f = 0; f < 16; f++) {
        int px_ = x0 + pxg * 32 + (f >> 3) * 16 + l15;
        int fo = f & 7;
#pragma unroll
        for (int r = 0; r < 4; r++) {
          int o = (fo >> 2) * 64 + (fo & 3) * 16 + quad * 4 + r;
          outf[(size_t)(b * COUT + o) * HWSZ + y * WW + px_] =
              fmaxf(acc[f][r] + cbv[o], 0.f);
        }
      }
    } else {
#pragma unroll
      for (int f = 0; f < 16; f++) {
        int pl = pxg * 32 + (f >> 3) * 16 + l15;
        int fo = f & 7;
        s16x4 t4;
#pragma unroll
        for (int r = 0; r < 4; r++) {
          int o = (fo >> 2) * 64 + (fo & 3) * 16 + quad * 4 + r;
          t4[r] = tobf(fmaxf(acc[f][r] + cbv[o], 0.f));
        }
        *(s16x4*)&trans[pl * 136 + (fo >> 2) * 64 + (fo & 3) * 16 + quad * 4] = t4;
      }
    }
  }
  if (MODE == 0) {
    __syncthreads();
    int pw = tid >> 2, cs = (tid & 3) * 32;
    size_t gb = ((size_t)(b * HWSZ) + y * WW + x0 + pw) * 128 + cs;
#pragma unroll
    for (int s = 0; s < 4; s++) {
      u16x8 v8 = *(const u16x8*)&trans[pw * 136 + cs + s * 8];
      *(u16x8*)&outb[gb + s * 8] = v8;
    }
  }
}

// ---------------------------------------------------------------------------
extern "C" void kernel_launch(void* const* d_in, const int* in_sizes, int n_in,
                              void* d_out, int out_size, void* d_ws, size_t ws_size,
                              hipStream_t stream) {
  const float* x        = (const float*)d_in[0];
  const float* dc1_offw = (const float*)d_in[1];
  const float* dc1_offb = (const float*)d_in[2];
  const float* dc1_w    = (const float*)d_in[3];
  const float* bn1_g    = (const float*)d_in[4];
  const float* bn1_b    = (const float*)d_in[5];
  const float* bn1_m    = (const float*)d_in[6];
  const float* bn1_v    = (const float*)d_in[7];
  const float* dc2_offw = (const float*)d_in[8];
  const float* dc2_offb = (const float*)d_in[9];
  const float* dc2_w    = (const float*)d_in[10];
  const float* bn2_g    = (const float*)d_in[11];
  const float* bn2_b    = (const float*)d_in[12];
  const float* bn2_m    = (const float*)d_in[13];
  const float* bn2_v    = (const float*)d_in[14];
  const float* id_w     = (const float*)d_in[15];
  const float* id_b     = (const float*)d_in[16];
  const float* bn3_g    = (const float*)d_in[17];
  const float* bn3_b    = (const float*)d_in[18];
  const float* bn3_m    = (const float*)d_in[19];
  const float* bn3_v    = (const float*)d_in[20];

  float* wsf = (float*)d_ws;
  float* off1 = wsf;                                   // 2*18*16384 f
  float* off2 = off1 + (size_t)BB * 18 * HWSZ;
  float* cb1  = off2 + (size_t)BB * 18 * HWSZ;
  float* cb2  = cb1 + 128;
  unsigned short* xbf = (unsigned short*)(cb2 + 128);  // NHWC (B,H,W,64)
  unsigned short* h1  = xbf + (size_t)BB * HWSZ * 64;  // NHWC (B,H,W,128)
  short* wbf1  = (short*)(h1 + (size_t)BB * HWSZ * COUT);  // frag 128x576
  short* wbf2  = wbf1 + (size_t)128 * 576;             // frag 128x1216
  short* woff1 = wbf2 + (size_t)128 * 1216;            // frag-order 18*1024
  short* woff2 = woff1 + (size_t)18 * 1024;            // frag-order 36*1024

  hipLaunchKernelGGL(prep_all_kernel, dim3((PA5 + 255) / 256), dim3(256), 0, stream,
                     dc1_w, dc2_w, id_w, dc1_offw, dc2_offw,
                     bn1_g, bn1_b, bn1_m, bn1_v, bn2_g, bn2_b, bn2_m, bn2_v,
                     bn3_g, bn3_b, bn3_m, bn3_v, id_b,
                     wbf1, wbf2, woff1, woff2, cb1, cb2);
  hipLaunchKernelGGL(xcast_kernel, dim3(BB * HWSZ / 64), dim3(256), 0, stream, x, xbf);

  // --- layer 1 ---
  hipLaunchKernelGGL((offconv_mfma_kernel<6>), dim3(512), dim3(512), 0, stream,
                     xbf, woff1, dc1_offb, off1);
  hipLaunchKernelGGL((deform_mfma_kernel<6, 576, 576, 0>), dim3(512), dim3(256), 0, stream,
                     xbf, off1, wbf1, cb1, (const unsigned short*)nullptr,
                     (float*)nullptr, h1);
  // --- layer 2 (identity residual folded into GEMM) ---
  hipLaunchKernelGGL((offconv_mfma_kernel<7>), dim3(512), dim3(512), 0, stream,
                     h1, woff2, dc2_offb, off2);
  hipLaunchKernelGGL((deform_mfma_kernel<7, 1152, 1216, 1>), dim3(512), dim3(256), 0, stream,
                     h1, off2, wbf2, cb2, xbf, (float*)d_out,
                     (unsigned short*)nullptr);
}

// Round 14
// 172.419 us; speedup vs baseline: 2.4095x; 1.0324x over previous
//
#include <hip/hip_runtime.h>
#include <math.h>

#define HH 128
#define WW 128
#define HWSZ (HH * WW)
#define BB 2
#define COUT 128

typedef __bf16 bf16x8 __attribute__((ext_vector_type(8)));
typedef float f32x4 __attribute__((ext_vector_type(4)));
typedef float f32x2 __attribute__((ext_vector_type(2)));
typedef short s16x8 __attribute__((ext_vector_type(8)));
typedef short s16x4 __attribute__((ext_vector_type(4)));
typedef unsigned short u16x4 __attribute__((ext_vector_type(4)));
typedef unsigned short u16x8 __attribute__((ext_vector_type(8)));

__device__ __forceinline__ short tobf(float f) {
  union { float f; unsigned u; } v; v.f = f;
  unsigned r = v.u + 0x7fffu + ((v.u >> 16) & 1u);  // RNE
  return (short)(r >> 16);
}
__device__ __forceinline__ float asf(unsigned u) {
  union { unsigned u; float f; } v; v.u = u;
  return v.f;
}
__device__ __forceinline__ f32x2 up2(unsigned u) {   // 2 bf16 -> 2 f32
  f32x2 r; r[0] = asf(u << 16); r[1] = asf(u & 0xffff0000u); return r;
}
// truncating pack of 2 f32 -> 2 bf16 in ONE v_perm_b32
__device__ __forceinline__ unsigned trunc2bf(f32x2 v) {
  union { float f; unsigned u; } a, b;
  a.f = v[0]; b.f = v[1];
  return __builtin_amdgcn_perm(b.u, a.u, 0x07060302u);
}

// ---------------------------------------------------------------------------
// Merged prep (same as rounds 9-13).
// ---------------------------------------------------------------------------
#define PA0 73728
#define PA1 221184
#define PA2 229376
#define PA3 247808
#define PA4 284672
#define PA5 284928
__global__ __launch_bounds__(256) void prep_all_kernel(
    const float* __restrict__ dc1_w, const float* __restrict__ dc2_w,
    const float* __restrict__ id_w, const float* __restrict__ dc1_offw,
    const float* __restrict__ dc2_offw,
    const float* g1, const float* b1, const float* m1, const float* v1,
    const float* g2, const float* b2, const float* m2, const float* v2,
    const float* g3, const float* b3, const float* m3, const float* v3,
    const float* idb,
    short* __restrict__ wbf1, short* __restrict__ wbf2,
    short* __restrict__ woff1, short* __restrict__ woff2,
    float* __restrict__ cb1, float* __restrict__ cb2) {
  int idx = blockIdx.x * 256 + threadIdx.x;
  if (idx < PA0) {
    int o = idx / 576, k = idx - o * 576;
    float inv = g1[o] / sqrtf(v1[o] + 1e-5f);
    int col = (k % 9) * 64 + k / 9;
    int di = (((col >> 5) * 2 + (o >> 6)) * 4 + ((o >> 4) & 3)) * 512
           + (((o & 15) | (((col >> 3) & 3) << 4)) * 8) + (col & 7);
    wbf1[di] = tobf(dc1_w[(size_t)o * 576 + k] * inv);
  } else if (idx < PA1) {
    int j = idx - PA0;
    int o = j / 1152, k = j - o * 1152;
    float inv = g2[o] / sqrtf(v2[o] + 1e-5f);
    int col = (k % 9) * 128 + k / 9;
    int di = (((col >> 5) * 2 + (o >> 6)) * 4 + ((o >> 4) & 3)) * 512
           + (((o & 15) | (((col >> 3) & 3) << 4)) * 8) + (col & 7);
    wbf2[di] = tobf(dc2_w[(size_t)o * 1152 + k] * inv);
  } else if (idx < PA2) {
    int j = idx - PA1;
    int o = j >> 6, k = j & 63;
    float inv = g3[o] / sqrtf(v3[o] + 1e-5f);
    int col = 1152 + k;
    int di = (((col >> 5) * 2 + (o >> 6)) * 4 + ((o >> 4) & 3)) * 512
           + (((o & 15) | (((col >> 3) & 3) << 4)) * 8) + (col & 7);
    wbf2[di] = tobf(id_w[(size_t)o * 64 + k] * inv);
  } else if (idx < PA3) {
    int j = idx - PA2;
    int o = j / 576, k = j - o * 576;
    int col = (k % 9) * 64 + k / 9;
    int di = ((col >> 5) * 2 + (o >> 4)) * 512 + ((col >> 3) & 3) * 128
           + (o & 15) * 8 + (col & 7);
    woff1[di] = (o < 18) ? tobf(dc1_offw[(size_t)o * 576 + k]) : (short)0;
  } else if (idx < PA4) {
    int j = idx - PA3;
    int o = j / 1152, k = j - o * 1152;
    int col = (k % 9) * 128 + k / 9;
    int di = ((col >> 5) * 2 + (o >> 4)) * 512 + ((col >> 3) & 3) * 128
           + (o & 15) * 8 + (col & 7);
    woff2[di] = (o < 18) ? tobf(dc2_offw[(size_t)o * 1152 + k]) : (short)0;
  } else if (idx < PA5) {
    int j = idx - PA4;
    if (j < 128) {
      float inv = g1[j] / sqrtf(v1[j] + 1e-5f);
      cb1[j] = b1[j] - m1[j] * inv;
    } else {
      int o = j - 128;
      float inv2_ = g2[o] / sqrtf(v2[o] + 1e-5f);
      float inv3_ = g3[o] / sqrtf(v3[o] + 1e-5f);
      cb2[o] = (b2[o] - m2[o] * inv2_) + idb[o] * inv3_ + (b3[o] - m3[o] * inv3_);
    }
  }
}

// ---------------------------------------------------------------------------
// x (B,64,H,W) fp32 NCHW -> xnhwc (B,H,W,64) bf16
// ---------------------------------------------------------------------------
__global__ __launch_bounds__(256) void xcast_kernel(const float* __restrict__ x,
                                                    unsigned short* __restrict__ xn) {
  __shared__ short lds[64 * 72];
  int tid = threadIdx.x;
  int gp0 = blockIdx.x * 64;
  int b = gp0 >> 14;
  int pl0 = gp0 & 16383;
  int p = tid & 63;
  int cb = (tid >> 6) * 16;
#pragma unroll
  for (int i = 0; i < 16; i++) {
    int c = cb + i;
    lds[p * 72 + c] = tobf(x[((size_t)(b * 64 + c)) * HWSZ + pl0 + p]);
  }
  __syncthreads();
  int pw = tid >> 2, cseg = (tid & 3) * 16;
  u16x8 a = *(const u16x8*)&lds[pw * 72 + cseg];
  u16x8 b8 = *(const u16x8*)&lds[pw * 72 + cseg + 8];
  *(u16x8*)&xn[(size_t)(gp0 + pw) * 64 + cseg] = a;
  *(u16x8*)&xn[(size_t)(gp0 + pw) * 64 + cseg + 8] = b8;
}

// ---------------------------------------------------------------------------
// FUSED layer kernel: offset conv (phase A) + deformable conv (phase C),
// all per 64-px block, barrier-free K-loops.
// Phase A: each of 4 waves computes 16 px x 32 offset-M over full K
//   (fragment-ordered woff weights, direct NHWC B loads) -> offlds (LDS).
// Phase B: bilinear descriptors from offlds -> dsu.
// Phase C: wave = 32 px x 128 out x half-K, NB=2, depth-1 register
//   ping-pong; residual chunks (layer 2) in post-loop; LDS f32 K-reduce.
// LDS overlay: [0,9.2K) dsu -> redf[0,32K) post-loop; [32K,..) offlds -> trans.
// ---------------------------------------------------------------------------
#define LOADW(P, kc_)                                           \
  {                                                             \
    const short* wf_ = wfb + (size_t)(kc_) * 4096;              \
    P##w0 = *(const bf16x8*)(wf_);                              \
    P##w1 = *(const bf16x8*)(wf_ + 512);                        \
    P##w2 = *(const bf16x8*)(wf_ + 1024);                       \
    P##w3 = *(const bf16x8*)(wf_ + 1536);                       \
    P##w4 = *(const bf16x8*)(wf_ + 2048);                       \
    P##w5 = *(const bf16x8*)(wf_ + 2560);                       \
    P##w6 = *(const bf16x8*)(wf_ + 3072);                       \
    P##w7 = *(const bf16x8*)(wf_ + 3584);                       \
  }

#define LOADT(P, kc_)                                           \
  {                                                             \
    int k0_ = (kc_) << 5;                                       \
    int n_ = k0_ >> CSH;                                        \
    int c0_ = (k0_ & (Cin - 1)) + cq * 8;                       \
    uint4 d4_ = dsu[(n_ << 6) + dp0];                           \
    int dx_ = (int)(d4_.w & 0xffffu);                           \
    int dy_ = (int)d4_.w >> 16;                                 \
    const unsigned short* p_ = inb + (int)d4_.z + c0_;          \
    P##q00 = *(const uint4*)(p_);                               \
    P##q01 = *(const uint4*)(p_ + dx_);                         \
    P##q02 = *(const uint4*)(p_ + dy_);                         \
    P##q03 = *(const uint4*)(p_ + dx_ + dy_);                   \
    P##wa0 = d4_.x; P##wb0 = d4_.y;                             \
    uint4 e4_ = dsu[(n_ << 6) + dp1];                           \
    int ex_ = (int)(e4_.w & 0xffffu);                           \
    int ey_ = (int)e4_.w >> 16;                                 \
    const unsigned short* q_ = inb + (int)e4_.z + c0_;          \
    P##q10 = *(const uint4*)(q_);                               \
    P##q11 = *(const uint4*)(q_ + ex_);                         \
    P##q12 = *(const uint4*)(q_ + ey_);                         \
    P##q13 = *(const uint4*)(q_ + ex_ + ey_);                   \
    P##wa1 = e4_.x; P##wb1 = e4_.y;                             \
  }

// explicit-register blend (no pasting adjacent to member access)
#define BLEND1(r0, r1, r2, r3, wav, wbv, pkv)                                 \
  {                                                                           \
    float w0_ = asf((wav) << 16), w1_ = asf((wav) & 0xffff0000u);             \
    float w2_ = asf((wbv) << 16), w3_ = asf((wbv) & 0xffff0000u);             \
    f32x2 v0_ = up2(r0.x) * w0_ + up2(r1.x) * w1_                             \
              + up2(r2.x) * w2_ + up2(r3.x) * w3_;                            \
    f32x2 v1_ = up2(r0.y) * w0_ + up2(r1.y) * w1_                             \
              + up2(r2.y) * w2_ + up2(r3.y) * w3_;                            \
    f32x2 v2_ = up2(r0.z) * w0_ + up2(r1.z) * w1_                             \
              + up2(r2.z) * w2_ + up2(r3.z) * w3_;                            \
    f32x2 v3_ = up2(r0.w) * w0_ + up2(r1.w) * w1_                             \
              + up2(r2.w) * w2_ + up2(r3.w) * w3_;                            \
    pkv.x = trunc2bf(v0_); pkv.y = trunc2bf(v1_);                             \
    pkv.z = trunc2bf(v2_); pkv.w = trunc2bf(v3_);                             \
  }

#define XPOSE(pkv, bfrv)                                                      \
  {                                                                           \
    union { int i[4]; bf16x8 v; } bu_;                                        \
    bu_.i[0] = __builtin_amdgcn_ds_bpermute(baddr, (int)pkv.x);               \
    bu_.i[1] = __builtin_amdgcn_ds_bpermute(baddr, (int)pkv.y);               \
    bu_.i[2] = __builtin_amdgcn_ds_bpermute(baddr, (int)pkv.z);               \
    bu_.i[3] = __builtin_amdgcn_ds_bpermute(baddr, (int)pkv.w);               \
    bfrv = bu_.v;                                                             \
  }

#define MFMA16(P, bfr0v, bfr1v)                                                     \
  {                                                                                 \
    acc[0] = __builtin_amdgcn_mfma_f32_16x16x32_bf16(P##w0, bfr0v, acc[0], 0, 0, 0);  \
    acc[8] = __builtin_amdgcn_mfma_f32_16x16x32_bf16(P##w0, bfr1v, acc[8], 0, 0, 0);  \
    acc[1] = __builtin_amdgcn_mfma_f32_16x16x32_bf16(P##w1, bfr0v, acc[1], 0, 0, 0);  \
    acc[9] = __builtin_amdgcn_mfma_f32_16x16x32_bf16(P##w1, bfr1v, acc[9], 0, 0, 0);  \
    acc[2] = __builtin_amdgcn_mfma_f32_16x16x32_bf16(P##w2, bfr0v, acc[2], 0, 0, 0);  \
    acc[10] = __builtin_amdgcn_mfma_f32_16x16x32_bf16(P##w2, bfr1v, acc[10], 0, 0, 0);\
    acc[3] = __builtin_amdgcn_mfma_f32_16x16x32_bf16(P##w3, bfr0v, acc[3], 0, 0, 0);  \
    acc[11] = __builtin_amdgcn_mfma_f32_16x16x32_bf16(P##w3, bfr1v, acc[11], 0, 0, 0);\
    acc[4] = __builtin_amdgcn_mfma_f32_16x16x32_bf16(P##w4, bfr0v, acc[4], 0, 0, 0);  \
    acc[12] = __builtin_amdgcn_mfma_f32_16x16x32_bf16(P##w4, bfr1v, acc[12], 0, 0, 0);\
    acc[5] = __builtin_amdgcn_mfma_f32_16x16x32_bf16(P##w5, bfr0v, acc[5], 0, 0, 0);  \
    acc[13] = __builtin_amdgcn_mfma_f32_16x16x32_bf16(P##w5, bfr1v, acc[13], 0, 0, 0);\
    acc[6] = __builtin_amdgcn_mfma_f32_16x16x32_bf16(P##w6, bfr0v, acc[6], 0, 0, 0);  \
    acc[14] = __builtin_amdgcn_mfma_f32_16x16x32_bf16(P##w6, bfr1v, acc[14], 0, 0, 0);\
    acc[7] = __builtin_amdgcn_mfma_f32_16x16x32_bf16(P##w7, bfr0v, acc[7], 0, 0, 0);  \
    acc[15] = __builtin_amdgcn_mfma_f32_16x16x32_bf16(P##w7, bfr1v, acc[15], 0, 0, 0);\
  }

#define COMPUTE(P)                                                            \
  {                                                                           \
    uint4 pk0_, pk1_;                                                         \
    BLEND1(P##q00, P##q01, P##q02, P##q03, P##wa0, P##wb0, pk0_);             \
    BLEND1(P##q10, P##q11, P##q12, P##q13, P##wa1, P##wb1, pk1_);             \
    bf16x8 bf0_, bf1_;                                                        \
    XPOSE(pk0_, bf0_);                                                        \
    XPOSE(pk1_, bf1_);                                                        \
    MFMA16(P, bf0_, bf1_);                                                    \
  }

template <int CSH, int KCONV, int KTOT, int MODE>
__global__ __launch_bounds__(256, 2) void fused_layer_kernel(
    const unsigned short* __restrict__ in, const short* __restrict__ woff,
    const float* __restrict__ offb,
    const short* __restrict__ wbf, const float* __restrict__ cbv,
    const unsigned short* __restrict__ xid, float* __restrict__ outf,
    unsigned short* __restrict__ outb) {
  __shared__ __align__(16) char smem[50176];
  uint4* dsu = (uint4*)smem;                    // [576] descriptors
  f32x4* redf = (f32x4*)smem;                   // [16*128] overlays dsu (post)
  float* offlds = (float*)(smem + 32768);       // [18*64] phase A -> B
  short* trans = (short*)(smem + 32768);        // 64 x 136 (epilogue, mode 0)

  const int tid = threadIdx.x;
  const int lane = tid & 63, wv = tid >> 6;
  const int pb = ((blockIdx.x & 7) << 6) | (blockIdx.x >> 3);  // XCD swizzle
  const int pix0 = pb << 6;
  const int x0 = pix0 & 127, y = (pix0 >> 7) & 127, b = pix0 >> 14;
  constexpr int Cin = 1 << CSH;
  const unsigned short* inb = in + (size_t)b * HWSZ * Cin;
  const int l15 = lane & 15, quad = lane >> 4;
  const int pxg = wv & 1, kh = wv >> 1;         // phase-C wave roles
  const int dp0 = pxg * 32 + (lane >> 2);
  const int dp1 = dp0 + 16;
  const int cq = lane & 3;
  const int baddr = (((lane & 15) << 2) | (lane >> 4)) << 2;  // bpermute src*4

  // ================= Phase A: offset conv (16 px x 32 M per wave) ========
  {
    constexpr int NCh = (9 << CSH) >> 5;        // 18 or 36
    const int pxa = wv;                          // wave = px group 0..3
    const int px = x0 + pxa * 16 + l15;
    f32x4 aco0 = {0.f, 0.f, 0.f, 0.f};
    f32x4 aco1 = {0.f, 0.f, 0.f, 0.f};
#pragma unroll
    for (int i = 0; i < NCh; i++) {
      int k0 = i * 32;
      int n = k0 >> CSH;
      int c0 = (k0 & (Cin - 1)) + quad * 8;
      int yy = y + n / 3 - 1;
      int xx = px + n % 3 - 1;
      bf16x8 bv = {};
      if (((unsigned)yy < (unsigned)HH) && ((unsigned)xx < (unsigned)WW))
        bv = *(const bf16x8*)&inb[((size_t)yy * WW + xx) * Cin + c0];
      int fbase = i * 1024 + lane * 8;
      bf16x8 a0 = *(const bf16x8*)&woff[fbase];
      bf16x8 a1 = *(const bf16x8*)&woff[fbase + 512];
      aco0 = __builtin_amdgcn_mfma_f32_16x16x32_bf16(a0, bv, aco0, 0, 0, 0);
      aco1 = __builtin_amdgcn_mfma_f32_16x16x32_bf16(a1, bv, aco1, 0, 0, 0);
    }
#pragma unroll
    for (int r = 0; r < 4; r++) {
      int o0 = quad * 4 + r;                     // 0..15: always valid
      offlds[o0 * 64 + pxa * 16 + l15] = aco0[r] + offb[o0];
      int o1 = 16 + quad * 4 + r;
      if (o1 < 18)
        offlds[o1 * 64 + pxa * 16 + l15] = aco1[r] + offb[o1];
    }
  }

  // pipeline register sets (named; no runtime-indexed arrays -> no scratch)
  bf16x8 Aw0, Aw1, Aw2, Aw3, Aw4, Aw5, Aw6, Aw7;
  bf16x8 Bw0, Bw1, Bw2, Bw3, Bw4, Bw5, Bw6, Bw7;
  uint4 Aq00, Aq01, Aq02, Aq03, Aq10, Aq11, Aq12, Aq13;
  uint4 Bq00, Bq01, Bq02, Bq03, Bq10, Bq11, Bq12, Bq13;
  unsigned Awa0, Awb0, Awa1, Awb1, Bwa0, Bwb0, Bwa1, Bwb1;

  constexpr int NC = KTOT >> 5;
  constexpr int NCONV = KCONV >> 5;
  constexpr int HC = NC >> 1;
  const int kcBeg = kh * HC;
  const int kcEnd = kcBeg + HC;
  const int kcEndConv = (kcEnd < NCONV) ? kcEnd : NCONV;
  const short* wfb = wbf + lane * 8;

  LOADW(A, kcBeg);            // weights don't depend on descriptors
  __syncthreads();            // offlds complete

  // ================= Phase B: bilinear descriptors ========================
  for (int t = tid; t < 576; t += 256) {
    int n = t >> 6, pp = t & 63;
    float offy = offlds[n * 64 + pp];
    float offx = offlds[(9 + n) * 64 + pp];
    float py = offy + (float)(n / 3 - 1) + (float)(y + 1);
    float px = offx + (float)(n % 3 - 1) + (float)(x0 + pp + 1);
    py = fminf(fmaxf(py, 0.f), 129.f);
    px = fminf(fmaxf(px, 0.f), 129.f);
    float fy = floorf(py), fx = floorf(px);
    float qy1 = fminf(fy + 1.f, 129.f), qx1 = fminf(fx + 1.f, 129.f);
    float ty0 = 1.f + fy - py, ty1 = 1.f - (qy1 - py);
    float tx0 = 1.f + fx - px, tx1 = 1.f - (qx1 - px);
    int iy0 = (int)fy - 1, ix0 = (int)fx - 1;
    int iy1 = (int)qy1 - 1, ix1 = (int)qx1 - 1;
    if ((unsigned)iy0 >= (unsigned)HH) ty0 = 0.f;
    if ((unsigned)iy1 >= (unsigned)HH) ty1 = 0.f;
    if ((unsigned)ix0 >= (unsigned)WW) tx0 = 0.f;
    if ((unsigned)ix1 >= (unsigned)WW) tx1 = 0.f;
    int by0 = min(max(iy0, 0), HH - 1), by1 = min(max(iy1, 0), HH - 1);
    int bx0 = min(max(ix0, 0), WW - 1), bx1 = min(max(ix1, 0), WW - 1);
    uint4 d4;
    d4.x = (unsigned)(unsigned short)tobf(ty0 * tx0)
         | ((unsigned)(unsigned short)tobf(ty0 * tx1) << 16);
    d4.y = (unsigned)(unsigned short)tobf(ty1 * tx0)
         | ((unsigned)(unsigned short)tobf(ty1 * tx1) << 16);
    d4.z = (unsigned)((by0 * WW + bx0) * Cin);
    d4.w = (unsigned)((((by1 - by0) * WW * Cin) << 16) | ((bx1 - bx0) * Cin));
    dsu[t] = d4;
  }

  f32x4 acc[16];
#pragma unroll
  for (int j = 0; j < 16; j++) acc[j] = (f32x4){0.f, 0.f, 0.f, 0.f};

  __syncthreads();            // descriptors ready

  // ================= Phase C: pipelined deform GEMM =======================
  LOADT(A, kcBeg);
  int i = kcBeg;
  for (; i + 2 <= kcEndConv; i += 2) {
    LOADW(B, i + 1);
    LOADT(B, i + 1);
    COMPUTE(A);
    if (i + 2 < kcEndConv) {
      LOADW(A, i + 2);
      LOADT(A, i + 2);
    }
    COMPUTE(B);
  }
  if (i < kcEndConv) {        // odd tail (A holds it)
    COMPUTE(A);
    i++;
  }

  // residual (identity) chunks: layer 2, kh=1 only
  if (KCONV < KTOT) {
    for (; i < kcEnd; i++) {
      LOADW(A, i);
      int c = ((i << 5) - KCONV) + cq * 8;
      uint4 pk0 = *(const uint4*)&xid[((size_t)(b * HWSZ) + y * WW + x0 + dp0) * 64 + c];
      uint4 pk1 = *(const uint4*)&xid[((size_t)(b * HWSZ) + y * WW + x0 + dp1) * 64 + c];
      bf16x8 bf0, bf1;
      XPOSE(pk0, bf0);
      XPOSE(pk1, bf1);
      MFMA16(A, bf0, bf1);
    }
  }

  // ---- K-half reduce (redf overlays dsu; both dead regions by now) ----
  __syncthreads();
  if (kh == 1) {
#pragma unroll
    for (int f = 0; f < 16; f++) redf[f * 128 + pxg * 64 + lane] = acc[f];
  }
  __syncthreads();
  if (kh == 0) {
#pragma unroll
    for (int f = 0; f < 16; f++) acc[f] += redf[f * 128 + pxg * 64 + lane];
    if (MODE == 1) {
#pragma unroll
      for (int f = 0; f < 16; f++) {
        int px_ = x0 + pxg * 32 + (f >> 3) * 16 + l15;
        int fo = f & 7;
#pragma unroll
        for (int r = 0; r < 4; r++) {
          int o = (fo >> 2) * 64 + (fo & 3) * 16 + quad * 4 + r;
          outf[(size_t)(b * COUT + o) * HWSZ + y * WW + px_] =
              fmaxf(acc[f][r] + cbv[o], 0.f);
        }
      }
    } else {
#pragma unroll
      for (int f = 0; f < 16; f++) {
        int pl = pxg * 32 + (f >> 3) * 16 + l15;
        int fo = f & 7;
        s16x4 t4;
#pragma unroll
        for (int r = 0; r < 4; r++) {
          int o = (fo >> 2) * 64 + (fo & 3) * 16 + quad * 4 + r;
          t4[r] = tobf(fmaxf(acc[f][r] + cbv[o], 0.f));
        }
        *(s16x4*)&trans[pl * 136 + (fo >> 2) * 64 + (fo & 3) * 16 + quad * 4] = t4;
      }
    }
  }
  if (MODE == 0) {
    __syncthreads();
    int pw = tid >> 2, cs = (tid & 3) * 32;
    size_t gb = ((size_t)(b * HWSZ) + y * WW + x0 + pw) * 128 + cs;
#pragma unroll
    for (int s = 0; s < 4; s++) {
      u16x8 v8 = *(const u16x8*)&trans[pw * 136 + cs + s * 8];
      *(u16x8*)&outb[gb + s * 8] = v8;
    }
  }
}

// ---------------------------------------------------------------------------
extern "C" void kernel_launch(void* const* d_in, const int* in_sizes, int n_in,
                              void* d_out, int out_size, void* d_ws, size_t ws_size,
                              hipStream_t stream) {
  const float* x        = (const float*)d_in[0];
  const float* dc1_offw = (const float*)d_in[1];
  const float* dc1_offb = (const float*)d_in[2];
  const float* dc1_w    = (const float*)d_in[3];
  const float* bn1_g    = (const float*)d_in[4];
  const float* bn1_b    = (const float*)d_in[5];
  const float* bn1_m    = (const float*)d_in[6];
  const float* bn1_v    = (const float*)d_in[7];
  const float* dc2_offw = (const float*)d_in[8];
  const float* dc2_offb = (const float*)d_in[9];
  const float* dc2_w    = (const float*)d_in[10];
  const float* bn2_g    = (const float*)d_in[11];
  const float* bn2_b    = (const float*)d_in[12];
  const float* bn2_m    = (const float*)d_in[13];
  const float* bn2_v    = (const float*)d_in[14];
  const float* id_w     = (const float*)d_in[15];
  const float* id_b     = (const float*)d_in[16];
  const float* bn3_g    = (const float*)d_in[17];
  const float* bn3_b    = (const float*)d_in[18];
  const float* bn3_m    = (const float*)d_in[19];
  const float* bn3_v    = (const float*)d_in[20];

  float* wsf = (float*)d_ws;
  float* cb1  = wsf;
  float* cb2  = cb1 + 128;
  unsigned short* xbf = (unsigned short*)(cb2 + 128);  // NHWC (B,H,W,64)
  unsigned short* h1  = xbf + (size_t)BB * HWSZ * 64;  // NHWC (B,H,W,128)
  short* wbf1  = (short*)(h1 + (size_t)BB * HWSZ * COUT);  // frag 128x576
  short* wbf2  = wbf1 + (size_t)128 * 576;             // frag 128x1216
  short* woff1 = wbf2 + (size_t)128 * 1216;            // frag-order 18*1024
  short* woff2 = woff1 + (size_t)18 * 1024;            // frag-order 36*1024

  hipLaunchKernelGGL(prep_all_kernel, dim3((PA5 + 255) / 256), dim3(256), 0, stream,
                     dc1_w, dc2_w, id_w, dc1_offw, dc2_offw,
                     bn1_g, bn1_b, bn1_m, bn1_v, bn2_g, bn2_b, bn2_m, bn2_v,
                     bn3_g, bn3_b, bn3_m, bn3_v, id_b,
                     wbf1, wbf2, woff1, woff2, cb1, cb2);
  hipLaunchKernelGGL(xcast_kernel, dim3(BB * HWSZ / 64), dim3(256), 0, stream, x, xbf);

  // --- layer 1 (offset conv fused) ---
  hipLaunchKernelGGL((fused_layer_kernel<6, 576, 576, 0>), dim3(512), dim3(256), 0, stream,
                     xbf, woff1, dc1_offb, wbf1, cb1,
                     (const unsigned short*)nullptr, (float*)nullptr, h1);
  // --- layer 2 (offset conv + identity residual fused) ---
  hipLaunchKernelGGL((fused_layer_kernel<7, 1152, 1216, 1>), dim3(512), dim3(256), 0, stream,
                     h1, woff2, dc2_offb, wbf2, cb2,
                     xbf, (float*)d_out, (unsigned short*)nullptr);
}